// Round 1
// baseline (891.581 us; speedup 1.0000x reference)
//
#include <hip/hip_runtime.h>
#include <hip/hip_bf16.h>

// S4 (DPLR / annotated-S4) forward model, B=8 L=2048 IN=OUT=64 H=128 N=64, 4 layers.
// Strategy: LDS-resident radix-2 FFT convolution (DIF fwd / DIT inv, bit-reversal-free),
// two-for-one real FFT packing over channel pairs, fp32 VALU matmuls for enc/dec/MLP.

#define Bsz 8
#define Lseq 2048
#define Hdim 128
#define Npol 64
#define NLAYERS 4
#define L2FFT 4096

typedef float2 cplx;

__device__ inline cplx cmulf(cplx a, cplx b) {
    return make_float2(a.x * b.x - a.y * b.y, a.x * b.y + a.y * b.x);
}

__device__ inline float gelu_f(float v) {
    // jax.nn.gelu default: tanh approximation
    float v3 = v * v * v;
    return 0.5f * v * (1.0f + tanhf(0.7978845608028654f * (v + 0.044715f * v3)));
}

// ---------------- twiddle table: tw[k] = exp(-2*pi*i*k/4096), k<2048 ----------------
__global__ __launch_bounds__(256) void twiddle_init(float2* tw) {
    int k = blockIdx.x * blockDim.x + threadIdx.x;
    if (k < 2048) {
        double a = -6.283185307179586476925286766559 * (double)k / 4096.0;
        tw[k] = make_float2((float)cos(a), (float)sin(a));
    }
}

// ---------------- encoder: h[row,o] = enc_w[o,:] . x[row,:] + enc_b[o] ----------------
__global__ __launch_bounds__(128) void encoder_kernel(const float* __restrict__ x,
                                                      const float* __restrict__ w,
                                                      const float* __restrict__ b,
                                                      float* __restrict__ h) {
    int row = blockIdx.x;
    int o = threadIdx.x;  // 0..127
    __shared__ float xs[64];
    if (o < 64) xs[o] = x[row * 64 + o];
    __syncthreads();
    float acc = b[o];
    const float* wr = w + o * 64;
#pragma unroll 16
    for (int k = 0; k < 64; k++) acc += wr[k] * xs[k];
    h[row * Hdim + o] = acc;
}

// ---------------- layernorm over H ----------------
__global__ __launch_bounds__(128) void ln_kernel(const float* __restrict__ h,
                                                 float* __restrict__ hn,
                                                 const float* __restrict__ wb,
                                                 const float* __restrict__ bb) {
    int row = blockIdx.x;
    int t = threadIdx.x;  // 0..127
    float v = h[row * Hdim + t];
    __shared__ float s1[128];
    __shared__ float s2[128];
    s1[t] = v;
    s2[t] = v * v;
    __syncthreads();
    for (int s = 64; s > 0; s >>= 1) {
        if (t < s) { s1[t] += s1[t + s]; s2[t] += s2[t + s]; }
        __syncthreads();
    }
    float mu = s1[0] * (1.0f / 128.0f);
    float var = s2[0] * (1.0f / 128.0f) - mu * mu;
    float inv = 1.0f / sqrtf(var + 1e-5f);
    hn[row * Hdim + t] = (v - mu) * inv * wb[t] + bb[t];
}

// ---------------- DPLR generating function at L roots of unity ----------------
__global__ __launch_bounds__(256) void spectrum_kernel(const float* __restrict__ lam_re,
                                                       const float* __restrict__ lam_im,
                                                       const float* __restrict__ p_re,
                                                       const float* __restrict__ p_im,
                                                       const float* __restrict__ b_re,
                                                       const float* __restrict__ b_im,
                                                       const float* __restrict__ c_re,
                                                       const float* __restrict__ c_im,
                                                       const float* __restrict__ log_step,
                                                       float2* __restrict__ at_roots) {
    int h = blockIdx.x;
    int t = threadIdx.x;  // 0..255
    __shared__ float2 lamS[Npol], n00S[Npol], n01S[Npol], n10S[Npol];
    __shared__ float n11S[Npol];
    int baseP = h * Npol;
    if (t < Npol) {
        int n = t;
        float lr = lam_re[baseP + n], li = lam_im[baseP + n];
        float pr = p_re[baseP + n], pi = p_im[baseP + n];
        float br = b_re[baseP + n], bi = b_im[baseP + n];
        float cr = c_re[baseP + n], ci = c_im[baseP + n];
        lamS[n] = make_float2(lr, li);
        n00S[n] = make_float2(cr * br + ci * bi, cr * bi - ci * br);  // conj(C)*B
        n01S[n] = make_float2(cr * pr + ci * pi, cr * pi - ci * pr);  // conj(C)*P
        n10S[n] = make_float2(pr * br + pi * bi, pr * bi - pi * br);  // conj(P)*B
        n11S[n] = pr * pr + pi * pi;                                  // conj(P)*P (real)
    }
    __syncthreads();
    float step = expf(log_step[h]);
    float gs = 2.0f / step;
    for (int l = t; l < Lseq; l += 256) {
        float ang = -6.283185307179586f * (float)l / (float)Lseq;
        float wr = cosf(ang), wi = sinf(ang);  // omega (fp32 on purpose: keeps |g|^2 in range)
        float dr = 1.0f + wr, di = wi;         // 1+omega
        float invd2 = 1.0f / (dr * dr + di * di);
        float nr = 1.0f - wr, ni = -wi;        // 1-omega
        float gr = gs * (nr * dr + ni * di) * invd2;
        float gi = gs * (ni * dr - nr * di) * invd2;
        float cr2 = 2.0f * dr * invd2, ci2 = -2.0f * di * invd2;  // c = 2/(1+omega)
        float k00x = 0, k00y = 0, k01x = 0, k01y = 0, k10x = 0, k10y = 0, k11x = 0, k11y = 0;
#pragma unroll 8
        for (int n = 0; n < Npol; n++) {
            float er = gr - lamS[n].x, ei = gi - lamS[n].y;
            float inv2 = 1.0f / (er * er + ei * ei);
            float ir = er * inv2, ii = -ei * inv2;  // 1/(g - lam)
            k00x += n00S[n].x * ir - n00S[n].y * ii; k00y += n00S[n].x * ii + n00S[n].y * ir;
            k01x += n01S[n].x * ir - n01S[n].y * ii; k01y += n01S[n].x * ii + n01S[n].y * ir;
            k10x += n10S[n].x * ir - n10S[n].y * ii; k10y += n10S[n].x * ii + n10S[n].y * ir;
            k11x += n11S[n] * ir;                    k11y += n11S[n] * ii;
        }
        // at = c * (k00 - k01 * k10 / (1 + k11))
        float wr2 = 1.0f + k11x, wi2 = k11y;
        float w2inv = 1.0f / (wr2 * wr2 + wi2 * wi2);
        float vr = wr2 * w2inv, vi = -wi2 * w2inv;
        float t1x = k01x * k10x - k01y * k10y, t1y = k01x * k10y + k01y * k10x;
        float t2x = t1x * vr - t1y * vi, t2y = t1x * vi + t1y * vr;
        float ex = k00x - t2x, ey = k00y - t2y;
        at_roots[h * Lseq + l] = make_float2(cr2 * ex - ci2 * ey, cr2 * ey + ci2 * ex);
    }
}

// ---------------- in-place FFT helpers (blockDim = 256) ----------------
// DIF: natural-order in -> bit-reversed out.  inverse=true conjugates twiddles.
__device__ inline void dif_fft(float2* data, const float2* __restrict__ tw, int n_half,
                               int t, bool inverse) {
    for (int m = n_half; m >= 1; m >>= 1) {
        int tstride = 2048 / m;
        for (int j = t; j < n_half; j += 256) {
            int jm = j & (m - 1);
            int idx = ((j - jm) << 1) + jm;  // (j/m)*2m + jm
            float2 a = data[idx], b = data[idx + m];
            float2 w = tw[jm * tstride];
            if (inverse) w.y = -w.y;
            float2 d = make_float2(a.x - b.x, a.y - b.y);
            data[idx] = make_float2(a.x + b.x, a.y + b.y);
            data[idx + m] = cmulf(d, w);
        }
        __syncthreads();
    }
}

// DIT with conjugated twiddles: bit-reversed in -> natural out, unnormalized inverse.
__device__ inline void dit_ifft(float2* data, const float2* __restrict__ tw, int n_half, int t) {
    for (int m = 1; m <= n_half; m <<= 1) {
        int tstride = 2048 / m;
        for (int j = t; j < n_half; j += 256) {
            int jm = j & (m - 1);
            int idx = ((j - jm) << 1) + jm;
            float2 w = tw[jm * tstride];
            float2 a = data[idx];
            float2 bb = data[idx + m];
            float2 b = make_float2(bb.x * w.x + bb.y * w.y, bb.y * w.x - bb.x * w.y);  // bb*conj(w)
            data[idx] = make_float2(a.x + b.x, a.y + b.y);
            data[idx + m] = make_float2(a.x - b.x, a.y - b.y);
        }
        __syncthreads();
    }
}

// ---------------- per-channel kernel spectrum: ifft_2048 -> pad -> fft_4096 ----------------
// Kd stored in BIT-REVERSED order (consistent with conv kernel's pointwise phase).
__global__ __launch_bounds__(256) void kernelfft_kernel(const float2* __restrict__ at_roots,
                                                        float2* __restrict__ Kd,
                                                        const float2* __restrict__ tw) {
    int h = blockIdx.x;
    int t = threadIdx.x;
    __shared__ float2 data[L2FFT];
    __shared__ float ktmp[Lseq];
    const float2* src = at_roots + h * Lseq;
    for (int l = t; l < Lseq; l += 256) data[l] = src[l];
    __syncthreads();
    dif_fft(data, tw, 1024, t, true);  // inverse DIF, n=2048 -> bit-rev time domain
    for (int p = t; p < Lseq; p += 256) {
        int l = __brev((unsigned)p) >> 21;  // 11-bit reversal
        ktmp[l] = data[p].x * (1.0f / 2048.0f);  // K = Re(ifft(at_roots))
    }
    __syncthreads();
    for (int l = t; l < Lseq; l += 256) {
        data[l] = make_float2(ktmp[l], 0.0f);
        data[l + Lseq] = make_float2(0.0f, 0.0f);
    }
    __syncthreads();
    dif_fft(data, tw, 2048, t, false);  // forward, n=4096 -> bit-rev spectrum
    float2* dst = Kd + h * L2FFT;
    for (int p = t; p < L2FFT; p += 256) dst[p] = data[p];
}

// ---------------- FFT convolution + D-skip + gelu, two channels per block ----------------
__global__ __launch_bounds__(256) void conv_kernel(float* __restrict__ hn,
                                                   const float2* __restrict__ Kd,
                                                   const float* __restrict__ dvec,
                                                   const float2* __restrict__ tw) {
    int hp = blockIdx.x;  // channel pair 0..63
    int b = blockIdx.y;   // batch 0..7
    int h0 = hp * 2;
    int t = threadIdx.x;
    __shared__ float2 data[L2FFT];
    __shared__ float2 uc[Lseq];
    float* base = hn + (size_t)b * Lseq * Hdim + h0;
    for (int l = t; l < Lseq; l += 256) {
        float2 u2 = *(const float2*)(base + (size_t)l * Hdim);
        uc[l] = u2;
        data[l] = u2;               // z = u_h + i*u_{h+1}
        data[l + Lseq] = make_float2(0.0f, 0.0f);
    }
    __syncthreads();
    dif_fft(data, tw, 2048, t, false);  // Z in bit-rev order
    // pointwise: separate two-for-one spectra, multiply by Kd, recombine. Bit-rev domain.
    const float2* K0 = Kd + (size_t)h0 * L2FFT;
    const float2* K1 = Kd + (size_t)(h0 + 1) * L2FFT;
    const float scale = 1.0f / 4096.0f;
    for (int f = t; f <= 2048; f += 256) {  // t=0 also covers f=2048
        int fm = (4096 - f) & 4095;
        int p = __brev((unsigned)f) >> 20;
        int pm = __brev((unsigned)fm) >> 20;
        float2 Zf = data[p], Zm = data[pm];
        float2 U0 = make_float2(0.5f * (Zf.x + Zm.x), 0.5f * (Zf.y - Zm.y));
        float2 Dm = make_float2(Zf.x - Zm.x, Zf.y + Zm.y);
        float2 U1 = make_float2(0.5f * Dm.y, -0.5f * Dm.x);  // -i/2 * Dm
        float2 S0 = cmulf(U0, K0[p]);
        float2 S1 = cmulf(U1, K1[p]);
        float2 Wf = make_float2((S0.x - S1.y) * scale, (S0.y + S1.x) * scale);
        float2 U0m = make_float2(U0.x, -U0.y);
        float2 U1m = make_float2(U1.x, -U1.y);
        float2 S0m = cmulf(U0m, K0[pm]);
        float2 S1m = cmulf(U1m, K1[pm]);
        float2 Wm = make_float2((S0m.x - S1m.y) * scale, (S0m.y + S1m.x) * scale);
        data[p] = Wf;
        if (pm != p) data[pm] = Wm;
    }
    __syncthreads();
    dit_ifft(data, tw, 2048, t);  // natural-order y0 + i*y1
    float d0 = dvec[h0], d1 = dvec[h0 + 1];
    for (int l = t; l < Lseq; l += 256) {
        float2 wv = data[l];
        float y0 = gelu_f(wv.x + uc[l].x * d0);
        float y1 = gelu_f(wv.y + uc[l].y * d1);
        *(float2*)(base + (size_t)l * Hdim) = make_float2(y0, y1);
    }
}

// ---------------- gated MLP + residual: h += (y@w1.T+b1) * sigmoid(y@w2.T+b2) ----------------
__global__ __launch_bounds__(256) void mlp_kernel(const float* __restrict__ y,
                                                  float* __restrict__ h,
                                                  const float* __restrict__ w1,
                                                  const float* __restrict__ b1,
                                                  const float* __restrict__ w2,
                                                  const float* __restrict__ b2) {
    const int ROWS = 16;
    int r0 = blockIdx.x * ROWS;
    int t = threadIdx.x;  // 0..255
    __shared__ __align__(16) float ys[ROWS][Hdim];
    __shared__ float dots[ROWS][256];
    for (int i = t; i < ROWS * Hdim; i += 256)
        ys[i >> 7][i & 127] = y[(size_t)(r0 + (i >> 7)) * Hdim + (i & 127)];
    __syncthreads();
    int o = t;
    const float* Wrow = (o < 128) ? (w1 + (size_t)o * Hdim) : (w2 + (size_t)(o - 128) * Hdim);
    float bias = (o < 128) ? b1[o] : b2[o - 128];
    float acc[ROWS];
#pragma unroll
    for (int r = 0; r < ROWS; r++) acc[r] = bias;
    for (int k4 = 0; k4 < Hdim; k4 += 4) {
        float4 wv = *(const float4*)(Wrow + k4);
#pragma unroll
        for (int r = 0; r < ROWS; r++) {
            float4 yv = *(const float4*)(&ys[r][k4]);  // wave-uniform addr -> LDS broadcast
            acc[r] += wv.x * yv.x + wv.y * yv.y + wv.z * yv.z + wv.w * yv.w;
        }
    }
#pragma unroll
    for (int r = 0; r < ROWS; r++) dots[r][o] = acc[r];
    __syncthreads();
    for (int e = t; e < ROWS * Hdim; e += 256) {
        int r = e >> 7, c = e & 127;
        float v1 = dots[r][c], v2 = dots[r][c + 128];
        float sg = 1.0f / (1.0f + expf(-v2));
        size_t idx = (size_t)(r0 + r) * Hdim + c;
        h[idx] += v1 * sg;
    }
}

// ---------------- decoder ----------------
__global__ __launch_bounds__(64) void decoder_kernel(const float* __restrict__ h,
                                                     const float* __restrict__ w,
                                                     const float* __restrict__ b,
                                                     float* __restrict__ out) {
    int row = blockIdx.x;
    int o = threadIdx.x;  // 0..63
    __shared__ float hs[Hdim];
    hs[o] = h[row * Hdim + o];
    hs[o + 64] = h[row * Hdim + o + 64];
    __syncthreads();
    float acc = b[o];
    const float* wr = w + o * Hdim;
#pragma unroll 16
    for (int k = 0; k < Hdim; k++) acc += wr[k] * hs[k];
    out[row * 64 + o] = acc;
}

extern "C" void kernel_launch(void* const* d_in, const int* in_sizes, int n_in,
                              void* d_out, int out_size, void* d_ws, size_t ws_size,
                              hipStream_t stream) {
    const float* x      = (const float*)d_in[0];
    // d_in[1] = convolve flag (static 1), unused
    const float* enc_w  = (const float*)d_in[2];
    const float* enc_b  = (const float*)d_in[3];
    const float* dec_w  = (const float*)d_in[4];
    const float* dec_b  = (const float*)d_in[5];
    const float* lam_re = (const float*)d_in[6];
    const float* lam_im = (const float*)d_in[7];
    const float* p_re   = (const float*)d_in[8];
    const float* p_im   = (const float*)d_in[9];
    const float* b_re   = (const float*)d_in[10];
    const float* b_im   = (const float*)d_in[11];
    const float* c_re   = (const float*)d_in[12];
    const float* c_im   = (const float*)d_in[13];
    const float* dvec   = (const float*)d_in[14];
    const float* lstep  = (const float*)d_in[15];
    const float* norm_w = (const float*)d_in[16];
    const float* norm_b = (const float*)d_in[17];
    const float* w1     = (const float*)d_in[18];
    const float* b1     = (const float*)d_in[19];
    const float* w2     = (const float*)d_in[20];
    const float* b2     = (const float*)d_in[21];
    float* out = (float*)d_out;

    char* ws = (char*)d_ws;
    float2* tw  = (float2*)ws;  ws += 2048 * sizeof(float2);
    float*  h   = (float*)ws;   ws += (size_t)Bsz * Lseq * Hdim * sizeof(float);
    float*  hn  = (float*)ws;   ws += (size_t)Bsz * Lseq * Hdim * sizeof(float);
    float2* atr = (float2*)ws;  ws += (size_t)Hdim * Lseq * sizeof(float2);
    float2* Kd  = (float2*)ws;  ws += (size_t)Hdim * L2FFT * sizeof(float2);

    const int nrows = Bsz * Lseq;  // 16384

    twiddle_init<<<8, 256, 0, stream>>>(tw);
    encoder_kernel<<<nrows, 128, 0, stream>>>(x, enc_w, enc_b, h);
    for (int L = 0; L < NLAYERS; L++) {
        ln_kernel<<<nrows, 128, 0, stream>>>(h, hn, norm_w + L * Hdim, norm_b + L * Hdim);
        int po = L * Hdim * Npol;
        spectrum_kernel<<<Hdim, 256, 0, stream>>>(lam_re + po, lam_im + po, p_re + po, p_im + po,
                                                  b_re + po, b_im + po, c_re + po, c_im + po,
                                                  lstep + L * Hdim, atr);
        kernelfft_kernel<<<Hdim, 256, 0, stream>>>(atr, Kd, tw);
        conv_kernel<<<dim3(Hdim / 2, Bsz), 256, 0, stream>>>(hn, Kd, dvec + L * Hdim, tw);
        mlp_kernel<<<nrows / 16, 256, 0, stream>>>(hn, h, w1 + (size_t)L * Hdim * Hdim,
                                                   b1 + L * Hdim, w2 + (size_t)L * Hdim * Hdim,
                                                   b2 + L * Hdim);
    }
    decoder_kernel<<<nrows, 64, 0, stream>>>(h, dec_w, dec_b, out);
}

// Round 2
// 675.175 us; speedup vs baseline: 1.3205x; 1.3205x over previous
//
#include <hip/hip_runtime.h>
#include <hip/hip_bf16.h>

// S4 (DPLR) forward, B=8 L=2048 IN=OUT=64 H=128 N=64, 4 layers.
// R2: register-resident radix-16^3 FFT (Stockham-style), XOR bank swizzle,
// u kept in registers, pair-interleaved Kd (float4), spectrum 4x parallelism.

#define Bsz 8
#define Lseq 2048
#define Hdim 128
#define Npol 64
#define NLAYERS 4

__device__ __forceinline__ float2 cmulf(float2 a, float2 b) {
    return make_float2(a.x * b.x - a.y * b.y, a.x * b.y + a.y * b.x);
}
__device__ __forceinline__ float2 cmulc(float2 a, float2 b) {  // a * conj(b)
    return make_float2(a.x * b.x + a.y * b.y, a.y * b.x - a.x * b.y);
}

__device__ __forceinline__ float gelu_f(float v) {
    float v3 = v * v * v;
    return 0.5f * v * (1.0f + tanhf(0.7978845608028654f * (v + 0.044715f * v3)));
}

// XOR swizzle: mixes digit1 into the bank digit so strides 1/16/256 are all conflict-uniform.
__device__ __forceinline__ int sw(int i) { return (i & ~15) | ((i ^ (i >> 4)) & 15); }

static __device__ const float W16R[8] = {1.f, 0.9238795325f, 0.7071067812f, 0.3826834324f,
                                         0.f, -0.3826834324f, -0.7071067812f, -0.9238795325f};
static __device__ const float W16I[8] = {0.f, -0.3826834324f, -0.7071067812f, -0.9238795325f,
                                         -1.f, -0.9238795325f, -0.7071067812f, -0.3826834324f};
static __device__ const int BR4[16] = {0, 8, 4, 12, 2, 10, 6, 14, 1, 9, 5, 13, 3, 11, 7, 15};
static __device__ const int BR3[8] = {0, 4, 2, 6, 1, 5, 3, 7};

// tw[k] = exp(-2*pi*i*k/4096), k<2048; twget handles e in [0,4096)
__device__ __forceinline__ float2 twget(const float2* __restrict__ tw, int e) {
    float2 w = tw[e & 2047];
    if (e & 2048) { w.x = -w.x; w.y = -w.y; }
    return w;
}

// 16-pt DIF: natural in -> bit-reversed out (slot i holds digit BR4[i]). INV = conj twiddles.
template <bool INV>
__device__ __forceinline__ void fft16_dif(float2 v[16]) {
#pragma unroll
    for (int mi = 0; mi < 4; mi++) {
        const int m = 8 >> mi;
#pragma unroll
        for (int g = 0; g < 16; g += 2 * m) {
#pragma unroll
            for (int j = 0; j < m; j++) {
                float wr = W16R[j << mi];
                float wi = INV ? -W16I[j << mi] : W16I[j << mi];
                float2 a = v[g + j], b = v[g + j + m];
                float dx = a.x - b.x, dy = a.y - b.y;
                v[g + j] = make_float2(a.x + b.x, a.y + b.y);
                v[g + j + m] = make_float2(dx * wr - dy * wi, dx * wi + dy * wr);
            }
        }
    }
}

// 16-pt DIT: bit-reversed in (slot i = digit BR4[i]) -> natural out. INV = conj twiddles.
template <bool INV>
__device__ __forceinline__ void fft16_dit(float2 v[16]) {
#pragma unroll
    for (int mi = 3; mi >= 0; mi--) {
        const int m = 8 >> mi;
#pragma unroll
        for (int g = 0; g < 16; g += 2 * m) {
#pragma unroll
            for (int j = 0; j < m; j++) {
                float wr = W16R[j << mi];
                float wi = INV ? -W16I[j << mi] : W16I[j << mi];
                float2 a = v[g + j], b = v[g + j + m];
                float bx = b.x * wr - b.y * wi, by = b.x * wi + b.y * wr;
                v[g + j] = make_float2(a.x + bx, a.y + by);
                v[g + j + m] = make_float2(a.x - bx, a.y - by);
            }
        }
    }
}

// 8-pt DIF (for the 2048-pt transform's last pass). W8^j = W16^(2j).
template <bool INV>
__device__ __forceinline__ void fft8_dif(float2 v[8]) {
#pragma unroll
    for (int mi = 0; mi < 3; mi++) {
        const int m = 4 >> mi;
#pragma unroll
        for (int g = 0; g < 8; g += 2 * m) {
#pragma unroll
            for (int j = 0; j < m; j++) {
                float wr = W16R[j << (mi + 1)];
                float wi = INV ? -W16I[j << (mi + 1)] : W16I[j << (mi + 1)];
                float2 a = v[g + j], b = v[g + j + m];
                float dx = a.x - b.x, dy = a.y - b.y;
                v[g + j] = make_float2(a.x + b.x, a.y + b.y);
                v[g + j + m] = make_float2(dx * wr - dy * wi, dx * wi + dy * wr);
            }
        }
    }
}

// Forward 4096-pt FFT in LDS, 256 threads, output in full 12-bit bit-reversed positions.
// No leading barrier needed IF the caller's fill writes exactly {t+256k} per thread.
__device__ __forceinline__ void fft4096_fwd(float2* data, const float2* __restrict__ tw, int t) {
    {  // pass A: stride 256, twiddle W4096^{j*r}
        float2 v[16];
#pragma unroll
        for (int k = 0; k < 16; k++) v[k] = data[sw(t + 256 * k)];
        fft16_dif<false>(v);
#pragma unroll
        for (int i = 1; i < 16; i++) v[i] = cmulf(v[i], twget(tw, t * BR4[i]));
#pragma unroll
        for (int i = 0; i < 16; i++) data[sw(i * 256 + t)] = v[i];
    }
    __syncthreads();
    {  // pass B: stride 16, twiddle W256^{j0*s}
        int j0 = t & 15;
        int base = (t >> 4) * 256 + j0;
        float2 v[16];
#pragma unroll
        for (int k = 0; k < 16; k++) v[k] = data[sw(base + 16 * k)];
        fft16_dif<false>(v);
#pragma unroll
        for (int i = 1; i < 16; i++) v[i] = cmulf(v[i], twget(tw, 16 * j0 * BR4[i]));
#pragma unroll
        for (int i = 0; i < 16; i++) data[sw(base + 16 * i)] = v[i];
    }
    __syncthreads();
    {  // pass C: stride 1, no extra twiddle
        float2 v[16];
#pragma unroll
        for (int k = 0; k < 16; k++) v[k] = data[sw(t * 16 + k)];
        fft16_dif<false>(v);
#pragma unroll
        for (int i = 0; i < 16; i++) data[sw(t * 16 + i)] = v[i];
    }
    __syncthreads();
}

// ---------------- twiddle table ----------------
__global__ __launch_bounds__(256) void twiddle_init(float2* tw) {
    int k = blockIdx.x * blockDim.x + threadIdx.x;
    if (k < 2048) {
        double a = -6.283185307179586476925286766559 * (double)k / 4096.0;
        tw[k] = make_float2((float)cos(a), (float)sin(a));
    }
}

// ---------------- encoder ----------------
__global__ __launch_bounds__(128) void encoder_kernel(const float* __restrict__ x,
                                                      const float* __restrict__ w,
                                                      const float* __restrict__ b,
                                                      float* __restrict__ h) {
    int row = blockIdx.x;
    int o = threadIdx.x;
    __shared__ float xs[64];
    if (o < 64) xs[o] = x[row * 64 + o];
    __syncthreads();
    float acc = b[o];
    const float* wr = w + o * 64;
#pragma unroll 16
    for (int k = 0; k < 64; k++) acc += wr[k] * xs[k];
    h[row * Hdim + o] = acc;
}

// ---------------- layernorm ----------------
__global__ __launch_bounds__(128) void ln_kernel(const float* __restrict__ h,
                                                 float* __restrict__ hn,
                                                 const float* __restrict__ wb,
                                                 const float* __restrict__ bb) {
    int row = blockIdx.x;
    int t = threadIdx.x;
    float v = h[row * Hdim + t];
    __shared__ float s1[128];
    __shared__ float s2[128];
    s1[t] = v;
    s2[t] = v * v;
    __syncthreads();
    for (int s = 64; s > 0; s >>= 1) {
        if (t < s) { s1[t] += s1[t + s]; s2[t] += s2[t + s]; }
        __syncthreads();
    }
    float mu = s1[0] * (1.0f / 128.0f);
    float var = s2[0] * (1.0f / 128.0f) - mu * mu;
    float inv = 1.0f / sqrtf(var + 1e-5f);
    hn[row * Hdim + t] = (v - mu) * inv * wb[t] + bb[t];
}

// ---------------- DPLR generating function ----------------
__global__ __launch_bounds__(256) void spectrum_kernel(const float* __restrict__ lam_re,
                                                       const float* __restrict__ lam_im,
                                                       const float* __restrict__ p_re,
                                                       const float* __restrict__ p_im,
                                                       const float* __restrict__ b_re,
                                                       const float* __restrict__ b_im,
                                                       const float* __restrict__ c_re,
                                                       const float* __restrict__ c_im,
                                                       const float* __restrict__ log_step,
                                                       float2* __restrict__ at_roots) {
    int h = blockIdx.x;
    int t = threadIdx.x;
    __shared__ float2 lamS[Npol], n00S[Npol], n01S[Npol], n10S[Npol];
    __shared__ float n11S[Npol];
    int baseP = h * Npol;
    if (t < Npol) {
        int n = t;
        float lr = lam_re[baseP + n], li = lam_im[baseP + n];
        float pr = p_re[baseP + n], pi = p_im[baseP + n];
        float br = b_re[baseP + n], bi = b_im[baseP + n];
        float cr = c_re[baseP + n], ci = c_im[baseP + n];
        lamS[n] = make_float2(lr, li);
        n00S[n] = make_float2(cr * br + ci * bi, cr * bi - ci * br);
        n01S[n] = make_float2(cr * pr + ci * pi, cr * pi - ci * pr);
        n10S[n] = make_float2(pr * br + pi * bi, pr * bi - pi * br);
        n11S[n] = pr * pr + pi * pi;
    }
    __syncthreads();
    float step = expf(log_step[h]);
    float gs = 2.0f / step;
    int l0 = 512 * blockIdx.y;
    for (int l = l0 + t; l < l0 + 512; l += 256) {
        float ang = -6.283185307179586f * (float)l / (float)Lseq;
        float wr = cosf(ang), wi = sinf(ang);  // fp32 omega on purpose: keeps |g|^2 in range
        float dr = 1.0f + wr, di = wi;
        float invd2 = 1.0f / (dr * dr + di * di);
        float nr = 1.0f - wr, ni = -wi;
        float gr = gs * (nr * dr + ni * di) * invd2;
        float gi = gs * (ni * dr - nr * di) * invd2;
        float cr2 = 2.0f * dr * invd2, ci2 = -2.0f * di * invd2;
        float k00x = 0, k00y = 0, k01x = 0, k01y = 0, k10x = 0, k10y = 0, k11x = 0, k11y = 0;
#pragma unroll 8
        for (int n = 0; n < Npol; n++) {
            float er = gr - lamS[n].x, ei = gi - lamS[n].y;
            float inv2 = 1.0f / (er * er + ei * ei);
            float ir = er * inv2, ii = -ei * inv2;
            k00x += n00S[n].x * ir - n00S[n].y * ii; k00y += n00S[n].x * ii + n00S[n].y * ir;
            k01x += n01S[n].x * ir - n01S[n].y * ii; k01y += n01S[n].x * ii + n01S[n].y * ir;
            k10x += n10S[n].x * ir - n10S[n].y * ii; k10y += n10S[n].x * ii + n10S[n].y * ir;
            k11x += n11S[n] * ir;                    k11y += n11S[n] * ii;
        }
        float wr2 = 1.0f + k11x, wi2 = k11y;
        float w2inv = 1.0f / (wr2 * wr2 + wi2 * wi2);
        float vr = wr2 * w2inv, vi = -wi2 * w2inv;
        float t1x = k01x * k10x - k01y * k10y, t1y = k01x * k10y + k01y * k10x;
        float t2x = t1x * vr - t1y * vi, t2y = t1x * vi + t1y * vr;
        float ex = k00x - t2x, ey = k00y - t2y;
        at_roots[h * Lseq + l] = make_float2(cr2 * ex - ci2 * ey, cr2 * ey + ci2 * ex);
    }
}

// ---------------- kernel spectrum: ifft2048 (16x16x8) -> pad -> fft4096 ----------------
// Kd2 layout: [hp][p] float4 = (K_{2hp}[p].re, .im, K_{2hp+1}[p].re, .im), p bit-reversed.
__global__ __launch_bounds__(256) void kernelfft_kernel(const float2* __restrict__ at_roots,
                                                        float4* __restrict__ Kd2,
                                                        const float2* __restrict__ tw) {
    int h = blockIdx.x, t = threadIdx.x;
    __shared__ float2 data[4096];
    __shared__ float ktmp[2048];
    const float2* src = at_roots + (size_t)h * Lseq;
#pragma unroll
    for (int k = 0; k < 8; k++) data[sw(t + 256 * k)] = src[t + 256 * k];
    __syncthreads();
    // inverse 2048-pt (conjugated DIF), digits 16(A) x 16(B) x 8(C)
    if (t < 128) {  // pass A2: stride 128, twiddle conj(W2048^{j*r}) = conj(W4096^{2jr})
        float2 v[16];
#pragma unroll
        for (int k = 0; k < 16; k++) v[k] = data[sw(t + 128 * k)];
        fft16_dif<true>(v);
#pragma unroll
        for (int i = 1; i < 16; i++) v[i] = cmulc(v[i], twget(tw, 2 * t * BR4[i]));
#pragma unroll
        for (int i = 0; i < 16; i++) data[sw(i * 128 + t)] = v[i];
    }
    __syncthreads();
    if (t < 128) {  // pass B2: stride 8, twiddle conj(W128^{j0*s}) = conj(W4096^{32*j0*s})
        int i2 = t >> 3, j0 = t & 7;
        int base2 = i2 * 128 + j0;
        float2 v[16];
#pragma unroll
        for (int k = 0; k < 16; k++) v[k] = data[sw(base2 + 8 * k)];
        fft16_dif<true>(v);
#pragma unroll
        for (int i = 1; i < 16; i++) v[i] = cmulc(v[i], twget(tw, 32 * j0 * BR4[i]));
#pragma unroll
        for (int i = 0; i < 16; i++) data[sw(base2 + 8 * i)] = v[i];
    }
    __syncthreads();
    {  // pass C2: radix-8 stride 1; scatter real part directly to natural-order ktmp
        float2 v8[8];
#pragma unroll
        for (int k = 0; k < 8; k++) v8[k] = data[sw(t * 8 + k)];
        fft8_dif<true>(v8);
        int r = BR4[t >> 4], s = BR4[t & 15];
#pragma unroll
        for (int i = 0; i < 8; i++) {
            int l = r + 16 * s + 256 * BR3[i];
            ktmp[l] = v8[i].x * (1.0f / 2048.0f);
        }
    }
    __syncthreads();
    // forward 4096 of zero-padded K (fill set == pass A read set per thread: no barrier)
#pragma unroll
    for (int k = 0; k < 8; k++) {
        int l = t + 256 * k;
        data[sw(l)] = make_float2(ktmp[l], 0.f);
        data[sw(l + 2048)] = make_float2(0.f, 0.f);
    }
    fft4096_fwd(data, tw, t);
    float2* dst = (float2*)(Kd2 + (size_t)(h >> 1) * 4096);
    int half = h & 1;
#pragma unroll
    for (int k = 0; k < 16; k++) {
        int p = t + 256 * k;
        dst[2 * p + half] = data[sw(p)];
    }
}

// ---------------- FFT convolution + D-skip + gelu, channel pair per block ----------------
__global__ __launch_bounds__(256) void conv_kernel(float* __restrict__ hn,
                                                   const float4* __restrict__ Kd2,
                                                   const float* __restrict__ dvec,
                                                   const float2* __restrict__ tw) {
    int hp = blockIdx.x, b = blockIdx.y, h0 = hp * 2, t = threadIdx.x;
    __shared__ float2 data[4096];
    float* base = hn + (size_t)b * Lseq * Hdim + h0;
    float2 ureg[8];
#pragma unroll
    for (int k = 0; k < 8; k++) {
        int l = t + 256 * k;
        float2 u2 = *(const float2*)(base + (size_t)l * Hdim);
        ureg[k] = u2;
        data[sw(l)] = u2;                       // z = u_h + i*u_{h+1}
        data[sw(l + 2048)] = make_float2(0.f, 0.f);
    }
    // fill set == pass A read set per thread: no barrier needed
    fft4096_fwd(data, tw, t);
    // pointwise two-for-one multiply in bit-reversed freq domain
    const float4* Kp = Kd2 + (size_t)hp * 4096;
    const float scale = 1.0f / 4096.0f;
    for (int f = t; f <= 2048; f += 256) {
        int fm = (4096 - f) & 4095;
        int p = __brev((unsigned)f) >> 20;
        int pm = __brev((unsigned)fm) >> 20;
        float2 Zf = data[sw(p)], Zm = data[sw(pm)];
        float2 U0 = make_float2(0.5f * (Zf.x + Zm.x), 0.5f * (Zf.y - Zm.y));
        float2 Dm = make_float2(Zf.x - Zm.x, Zf.y + Zm.y);
        float2 U1 = make_float2(0.5f * Dm.y, -0.5f * Dm.x);
        float4 Ka = Kp[p];
        float2 S0 = cmulf(U0, make_float2(Ka.x, Ka.y));
        float2 S1 = cmulf(U1, make_float2(Ka.z, Ka.w));
        float2 Wf = make_float2((S0.x - S1.y) * scale, (S0.y + S1.x) * scale);
        float4 Kb = Kp[pm];
        float2 U0m = make_float2(U0.x, -U0.y);
        float2 U1m = make_float2(U1.x, -U1.y);
        float2 S0m = cmulf(U0m, make_float2(Kb.x, Kb.y));
        float2 S1m = cmulf(U1m, make_float2(Kb.z, Kb.w));
        float2 Wm = make_float2((S0m.x - S1m.y) * scale, (S0m.y + S1m.x) * scale);
        data[sw(p)] = Wf;
        if (pm != p) data[sw(pm)] = Wm;
    }
    __syncthreads();
    {  // inverse pass C'
        float2 v[16];
#pragma unroll
        for (int i = 0; i < 16; i++) v[i] = data[sw(t * 16 + i)];
        fft16_dit<true>(v);
#pragma unroll
        for (int i = 0; i < 16; i++) data[sw(t * 16 + i)] = v[i];
    }
    __syncthreads();
    {  // inverse pass B' (pre-twiddle conj, then DIT)
        int j0 = t & 15;
        int base2 = (t >> 4) * 256 + j0;
        float2 v[16];
        v[0] = data[sw(base2)];
#pragma unroll
        for (int i = 1; i < 16; i++)
            v[i] = cmulc(data[sw(base2 + 16 * i)], twget(tw, 16 * j0 * BR4[i]));
        fft16_dit<true>(v);
#pragma unroll
        for (int i = 0; i < 16; i++) data[sw(base2 + 16 * i)] = v[i];
    }
    __syncthreads();
    {  // inverse pass A' + epilogue (thread t ends holding y[t + 256k] -> direct store)
        float2 v[16];
        v[0] = data[sw(t)];
#pragma unroll
        for (int i = 1; i < 16; i++)
            v[i] = cmulc(data[sw(i * 256 + t)], twget(tw, t * BR4[i]));
        fft16_dit<true>(v);
        float d0 = dvec[h0], d1 = dvec[h0 + 1];
#pragma unroll
        for (int k = 0; k < 8; k++) {
            float y0 = gelu_f(v[k].x + ureg[k].x * d0);
            float y1 = gelu_f(v[k].y + ureg[k].y * d1);
            *(float2*)(base + (size_t)(t + 256 * k) * Hdim) = make_float2(y0, y1);
        }
    }
}

// ---------------- gated MLP + residual ----------------
__global__ __launch_bounds__(256) void mlp_kernel(const float* __restrict__ y,
                                                  float* __restrict__ h,
                                                  const float* __restrict__ w1,
                                                  const float* __restrict__ b1,
                                                  const float* __restrict__ w2,
                                                  const float* __restrict__ b2) {
    const int ROWS = 16;
    int r0 = blockIdx.x * ROWS;
    int t = threadIdx.x;
    __shared__ __align__(16) float ys[ROWS][Hdim];
    __shared__ float dots[ROWS][256];
    for (int i = t; i < ROWS * Hdim; i += 256)
        ys[i >> 7][i & 127] = y[(size_t)(r0 + (i >> 7)) * Hdim + (i & 127)];
    __syncthreads();
    int o = t;
    const float* Wrow = (o < 128) ? (w1 + (size_t)o * Hdim) : (w2 + (size_t)(o - 128) * Hdim);
    float bias = (o < 128) ? b1[o] : b2[o - 128];
    float acc[ROWS];
#pragma unroll
    for (int r = 0; r < ROWS; r++) acc[r] = bias;
    for (int k4 = 0; k4 < Hdim; k4 += 4) {
        float4 wv = *(const float4*)(Wrow + k4);
#pragma unroll
        for (int r = 0; r < ROWS; r++) {
            float4 yv = *(const float4*)(&ys[r][k4]);
            acc[r] += wv.x * yv.x + wv.y * yv.y + wv.z * yv.z + wv.w * yv.w;
        }
    }
#pragma unroll
    for (int r = 0; r < ROWS; r++) dots[r][o] = acc[r];
    __syncthreads();
    for (int e = t; e < ROWS * Hdim; e += 256) {
        int r = e >> 7, c = e & 127;
        float v1 = dots[r][c], v2 = dots[r][c + 128];
        float sg = 1.0f / (1.0f + expf(-v2));
        size_t idx = (size_t)(r0 + r) * Hdim + c;
        h[idx] += v1 * sg;
    }
}

// ---------------- decoder ----------------
__global__ __launch_bounds__(64) void decoder_kernel(const float* __restrict__ h,
                                                     const float* __restrict__ w,
                                                     const float* __restrict__ b,
                                                     float* __restrict__ out) {
    int row = blockIdx.x;
    int o = threadIdx.x;
    __shared__ float hs[Hdim];
    hs[o] = h[row * Hdim + o];
    hs[o + 64] = h[row * Hdim + o + 64];
    __syncthreads();
    float acc = b[o];
    const float* wr = w + o * Hdim;
#pragma unroll 16
    for (int k = 0; k < Hdim; k++) acc += wr[k] * hs[k];
    out[row * 64 + o] = acc;
}

extern "C" void kernel_launch(void* const* d_in, const int* in_sizes, int n_in,
                              void* d_out, int out_size, void* d_ws, size_t ws_size,
                              hipStream_t stream) {
    const float* x      = (const float*)d_in[0];
    const float* enc_w  = (const float*)d_in[2];
    const float* enc_b  = (const float*)d_in[3];
    const float* dec_w  = (const float*)d_in[4];
    const float* dec_b  = (const float*)d_in[5];
    const float* lam_re = (const float*)d_in[6];
    const float* lam_im = (const float*)d_in[7];
    const float* p_re   = (const float*)d_in[8];
    const float* p_im   = (const float*)d_in[9];
    const float* b_re   = (const float*)d_in[10];
    const float* b_im   = (const float*)d_in[11];
    const float* c_re   = (const float*)d_in[12];
    const float* c_im   = (const float*)d_in[13];
    const float* dvec   = (const float*)d_in[14];
    const float* lstep  = (const float*)d_in[15];
    const float* norm_w = (const float*)d_in[16];
    const float* norm_b = (const float*)d_in[17];
    const float* w1     = (const float*)d_in[18];
    const float* b1     = (const float*)d_in[19];
    const float* w2     = (const float*)d_in[20];
    const float* b2     = (const float*)d_in[21];
    float* out = (float*)d_out;

    char* ws = (char*)d_ws;
    float2* tw  = (float2*)ws;  ws += 2048 * sizeof(float2);
    float*  h   = (float*)ws;   ws += (size_t)Bsz * Lseq * Hdim * sizeof(float);
    float*  hn  = (float*)ws;   ws += (size_t)Bsz * Lseq * Hdim * sizeof(float);
    float2* atr = (float2*)ws;  ws += (size_t)Hdim * Lseq * sizeof(float2);
    float4* Kd2 = (float4*)ws;  ws += (size_t)(Hdim / 2) * 4096 * sizeof(float4);

    const int nrows = Bsz * Lseq;  // 16384

    twiddle_init<<<8, 256, 0, stream>>>(tw);
    encoder_kernel<<<nrows, 128, 0, stream>>>(x, enc_w, enc_b, h);
    for (int L = 0; L < NLAYERS; L++) {
        ln_kernel<<<nrows, 128, 0, stream>>>(h, hn, norm_w + L * Hdim, norm_b + L * Hdim);
        int po = L * Hdim * Npol;
        spectrum_kernel<<<dim3(Hdim, 4), 256, 0, stream>>>(
            lam_re + po, lam_im + po, p_re + po, p_im + po, b_re + po, b_im + po,
            c_re + po, c_im + po, lstep + L * Hdim, atr);
        kernelfft_kernel<<<Hdim, 256, 0, stream>>>(atr, Kd2, tw);
        conv_kernel<<<dim3(Hdim / 2, Bsz), 256, 0, stream>>>(hn, Kd2, dvec + L * Hdim, tw);
        mlp_kernel<<<nrows / 16, 256, 0, stream>>>(hn, h, w1 + (size_t)L * Hdim * Hdim,
                                                   b1 + L * Hdim, w2 + (size_t)L * Hdim * Hdim,
                                                   b2 + L * Hdim);
    }
    decoder_kernel<<<nrows, 64, 0, stream>>>(h, dec_w, dec_b, out);
}

// Round 3
// 535.478 us; speedup vs baseline: 1.6650x; 1.2609x over previous
//
#include <hip/hip_runtime.h>
#include <hip/hip_bf16.h>

// S4 (DPLR) forward, B=8 L=2048 IN=OUT=64 H=128 N=64, 4 layers.
// R3: LDS-staged coalesced matmuls (enc/dec/mlp), LN fused into producers,
// spectrum+kernelFFT fused into one all-layer launch. Conv unchanged from R2.

#define Bsz 8
#define Lseq 2048
#define Hdim 128
#define Npol 64
#define NLAYERS 4

__device__ __forceinline__ float2 cmulf(float2 a, float2 b) {
    return make_float2(a.x * b.x - a.y * b.y, a.x * b.y + a.y * b.x);
}
__device__ __forceinline__ float2 cmulc(float2 a, float2 b) {  // a * conj(b)
    return make_float2(a.x * b.x + a.y * b.y, a.y * b.x - a.x * b.y);
}

__device__ __forceinline__ float gelu_f(float v) {
    float v3 = v * v * v;
    return 0.5f * v * (1.0f + tanhf(0.7978845608028654f * (v + 0.044715f * v3)));
}

// XOR swizzle: mixes digit1 into the bank digit so strides 1/16/256 are all conflict-uniform.
__device__ __forceinline__ int sw(int i) { return (i & ~15) | ((i ^ (i >> 4)) & 15); }

static __device__ const float W16R[8] = {1.f, 0.9238795325f, 0.7071067812f, 0.3826834324f,
                                         0.f, -0.3826834324f, -0.7071067812f, -0.9238795325f};
static __device__ const float W16I[8] = {0.f, -0.3826834324f, -0.7071067812f, -0.9238795325f,
                                         -1.f, -0.9238795325f, -0.7071067812f, -0.3826834324f};
static __device__ const int BR4[16] = {0, 8, 4, 12, 2, 10, 6, 14, 1, 9, 5, 13, 3, 11, 7, 15};
static __device__ const int BR3[8] = {0, 4, 2, 6, 1, 5, 3, 7};

__device__ __forceinline__ float2 twget(const float2* __restrict__ tw, int e) {
    float2 w = tw[e & 2047];
    if (e & 2048) { w.x = -w.x; w.y = -w.y; }
    return w;
}

template <bool INV>
__device__ __forceinline__ void fft16_dif(float2 v[16]) {
#pragma unroll
    for (int mi = 0; mi < 4; mi++) {
        const int m = 8 >> mi;
#pragma unroll
        for (int g = 0; g < 16; g += 2 * m) {
#pragma unroll
            for (int j = 0; j < m; j++) {
                float wr = W16R[j << mi];
                float wi = INV ? -W16I[j << mi] : W16I[j << mi];
                float2 a = v[g + j], b = v[g + j + m];
                float dx = a.x - b.x, dy = a.y - b.y;
                v[g + j] = make_float2(a.x + b.x, a.y + b.y);
                v[g + j + m] = make_float2(dx * wr - dy * wi, dx * wi + dy * wr);
            }
        }
    }
}

template <bool INV>
__device__ __forceinline__ void fft16_dit(float2 v[16]) {
#pragma unroll
    for (int mi = 3; mi >= 0; mi--) {
        const int m = 8 >> mi;
#pragma unroll
        for (int g = 0; g < 16; g += 2 * m) {
#pragma unroll
            for (int j = 0; j < m; j++) {
                float wr = W16R[j << mi];
                float wi = INV ? -W16I[j << mi] : W16I[j << mi];
                float2 a = v[g + j], b = v[g + j + m];
                float bx = b.x * wr - b.y * wi, by = b.x * wi + b.y * wr;
                v[g + j] = make_float2(a.x + bx, a.y + by);
                v[g + j + m] = make_float2(a.x - bx, a.y - by);
            }
        }
    }
}

template <bool INV>
__device__ __forceinline__ void fft8_dif(float2 v[8]) {
#pragma unroll
    for (int mi = 0; mi < 3; mi++) {
        const int m = 4 >> mi;
#pragma unroll
        for (int g = 0; g < 8; g += 2 * m) {
#pragma unroll
            for (int j = 0; j < m; j++) {
                float wr = W16R[j << (mi + 1)];
                float wi = INV ? -W16I[j << (mi + 1)] : W16I[j << (mi + 1)];
                float2 a = v[g + j], b = v[g + j + m];
                float dx = a.x - b.x, dy = a.y - b.y;
                v[g + j] = make_float2(a.x + b.x, a.y + b.y);
                v[g + j + m] = make_float2(dx * wr - dy * wi, dx * wi + dy * wr);
            }
        }
    }
}

// Forward 4096-pt FFT in LDS, 256 threads, result in 12-bit bit-reversed positions.
// No leading barrier IF caller's fill writes exactly {t+256k, k<16} per thread.
__device__ __forceinline__ void fft4096_fwd(float2* data, const float2* __restrict__ tw, int t) {
    {
        float2 v[16];
#pragma unroll
        for (int k = 0; k < 16; k++) v[k] = data[sw(t + 256 * k)];
        fft16_dif<false>(v);
#pragma unroll
        for (int i = 1; i < 16; i++) v[i] = cmulf(v[i], twget(tw, t * BR4[i]));
#pragma unroll
        for (int i = 0; i < 16; i++) data[sw(i * 256 + t)] = v[i];
    }
    __syncthreads();
    {
        int j0 = t & 15;
        int base = (t >> 4) * 256 + j0;
        float2 v[16];
#pragma unroll
        for (int k = 0; k < 16; k++) v[k] = data[sw(base + 16 * k)];
        fft16_dif<false>(v);
#pragma unroll
        for (int i = 1; i < 16; i++) v[i] = cmulf(v[i], twget(tw, 16 * j0 * BR4[i]));
#pragma unroll
        for (int i = 0; i < 16; i++) data[sw(base + 16 * i)] = v[i];
    }
    __syncthreads();
    {
        float2 v[16];
#pragma unroll
        for (int k = 0; k < 16; k++) v[k] = data[sw(t * 16 + k)];
        fft16_dif<false>(v);
#pragma unroll
        for (int i = 0; i < 16; i++) data[sw(t * 16 + i)] = v[i];
    }
    __syncthreads();
}

// ---------------- twiddle table ----------------
__global__ __launch_bounds__(256) void twiddle_init(float2* tw) {
    int k = blockIdx.x * blockDim.x + threadIdx.x;
    if (k < 2048) {
        double a = -6.283185307179586476925286766559 * (double)k / 4096.0;
        tw[k] = make_float2((float)cos(a), (float)sin(a));
    }
}

// ---------------- encoder + fused LN: 16 rows/block ----------------
__global__ __launch_bounds__(256) void encoder_kernel(const float* __restrict__ x,
                                                      const float* __restrict__ w,
                                                      const float* __restrict__ b,
                                                      const float* __restrict__ nw,
                                                      const float* __restrict__ nb,
                                                      float* __restrict__ h,
                                                      float* __restrict__ hn) {
    int r0 = blockIdx.x * 16;
    int t = threadIdx.x;
    __shared__ float ws[128 * 65];                 // w[o][k], pad 65 -> bank (o+k)%32
    __shared__ __align__(16) float xst[64 * 20];   // x transposed [k][r], pad 20 (b128-aligned)
    __shared__ float dots[16 * 128];
    __shared__ float2 mv[16];
    for (int i = t; i < 128 * 64; i += 256) ws[(i >> 6) * 65 + (i & 63)] = w[i];
    for (int i = t; i < 16 * 64; i += 256) {
        int r = i >> 6, k = i & 63;
        xst[k * 20 + r] = x[(size_t)(r0 + r) * 64 + k];
    }
    __syncthreads();
    int o = t & 127, half = t >> 7;
    float acc[8];
    float bo = b[o];
#pragma unroll
    for (int j = 0; j < 8; j++) acc[j] = bo;
    for (int k = 0; k < 64; k++) {
        float wv = ws[o * 65 + k];
        float4 xa = *(const float4*)&xst[k * 20 + half * 8];
        float4 xb = *(const float4*)&xst[k * 20 + half * 8 + 4];
        acc[0] += wv * xa.x; acc[1] += wv * xa.y; acc[2] += wv * xa.z; acc[3] += wv * xa.w;
        acc[4] += wv * xb.x; acc[5] += wv * xb.y; acc[6] += wv * xb.z; acc[7] += wv * xb.w;
    }
#pragma unroll
    for (int j = 0; j < 8; j++) dots[(half * 8 + j) * 128 + o] = acc[j];
    __syncthreads();
    {  // LN stats: 16 threads per row
        int row = t >> 4, lane = t & 15;
        float s1 = 0.f, s2 = 0.f;
#pragma unroll
        for (int i = 0; i < 8; i++) {
            float v = dots[row * 128 + lane * 8 + i];
            s1 += v; s2 += v * v;
        }
#pragma unroll
        for (int m = 1; m < 16; m <<= 1) { s1 += __shfl_xor(s1, m); s2 += __shfl_xor(s2, m); }
        if (lane == 0) {
            float mu = s1 * (1.0f / 128.0f);
            float var = s2 * (1.0f / 128.0f) - mu * mu;
            mv[row] = make_float2(mu, rsqrtf(var + 1e-5f));
        }
    }
    __syncthreads();
    int c = t & 127;
    float nwc = nw[c], nbc = nb[c];
#pragma unroll
    for (int j = 0; j < 8; j++) {
        int r = (t >> 7) + 2 * j;
        float v = dots[r * 128 + c];
        size_t idx = (size_t)(r0 + r) * Hdim + c;
        h[idx] = v;
        float2 m = mv[r];
        hn[idx] = (v - m.x) * m.y * nwc + nbc;
    }
}

// ---------------- fused spectrum + kernel FFT, all layers, one launch ----------------
// Kd2 layout: [layer][hp][p] float4 = (K_{2hp}[p].re,.im, K_{2hp+1}[p].re,.im), p bit-rev.
__global__ __launch_bounds__(256) void specfft_kernel(const float* __restrict__ lam_re,
                                                      const float* __restrict__ lam_im,
                                                      const float* __restrict__ p_re,
                                                      const float* __restrict__ p_im,
                                                      const float* __restrict__ b_re,
                                                      const float* __restrict__ b_im,
                                                      const float* __restrict__ c_re,
                                                      const float* __restrict__ c_im,
                                                      const float* __restrict__ log_step,
                                                      float4* __restrict__ Kd2,
                                                      const float2* __restrict__ tw) {
    int h = blockIdx.x, layer = blockIdx.y, t = threadIdx.x;
    __shared__ float2 data[4096];
    __shared__ float ktmp[2048];
    __shared__ float2 lamS[Npol], n00S[Npol], n01S[Npol], n10S[Npol];
    __shared__ float n11S[Npol];
    int baseP = (layer * Hdim + h) * Npol;
    if (t < Npol) {
        int n = t;
        float lr = lam_re[baseP + n], li = lam_im[baseP + n];
        float pr = p_re[baseP + n], pi = p_im[baseP + n];
        float br = b_re[baseP + n], bi = b_im[baseP + n];
        float cr = c_re[baseP + n], ci = c_im[baseP + n];
        lamS[n] = make_float2(lr, li);
        n00S[n] = make_float2(cr * br + ci * bi, cr * bi - ci * br);
        n01S[n] = make_float2(cr * pr + ci * pi, cr * pi - ci * pr);
        n10S[n] = make_float2(pr * br + pi * bi, pr * bi - pi * br);
        n11S[n] = pr * pr + pi * pi;
    }
    __syncthreads();
    float step = expf(log_step[layer * Hdim + h]);
    float gs = 2.0f / step;
    for (int l = t; l < Lseq; l += 256) {
        float ang = -6.283185307179586f * (float)l / (float)Lseq;
        float wr = cosf(ang), wi = sinf(ang);  // fp32 omega on purpose: keeps |g|^2 in range
        float dr = 1.0f + wr, di = wi;
        float invd2 = 1.0f / (dr * dr + di * di);
        float nr = 1.0f - wr, ni = -wi;
        float gr = gs * (nr * dr + ni * di) * invd2;
        float gi = gs * (ni * dr - nr * di) * invd2;
        float cr2 = 2.0f * dr * invd2, ci2 = -2.0f * di * invd2;
        float k00x = 0, k00y = 0, k01x = 0, k01y = 0, k10x = 0, k10y = 0, k11x = 0, k11y = 0;
#pragma unroll 8
        for (int n = 0; n < Npol; n++) {
            float er = gr - lamS[n].x, ei = gi - lamS[n].y;
            float inv2 = 1.0f / (er * er + ei * ei);
            float ir = er * inv2, ii = -ei * inv2;
            k00x += n00S[n].x * ir - n00S[n].y * ii; k00y += n00S[n].x * ii + n00S[n].y * ir;
            k01x += n01S[n].x * ir - n01S[n].y * ii; k01y += n01S[n].x * ii + n01S[n].y * ir;
            k10x += n10S[n].x * ir - n10S[n].y * ii; k10y += n10S[n].x * ii + n10S[n].y * ir;
            k11x += n11S[n] * ir;                    k11y += n11S[n] * ii;
        }
        float wr2 = 1.0f + k11x, wi2 = k11y;
        float w2inv = 1.0f / (wr2 * wr2 + wi2 * wi2);
        float vr = wr2 * w2inv, vi = -wi2 * w2inv;
        float t1x = k01x * k10x - k01y * k10y, t1y = k01x * k10y + k01y * k10x;
        float t2x = t1x * vr - t1y * vi, t2y = t1x * vi + t1y * vr;
        float ex = k00x - t2x, ey = k00y - t2y;
        data[sw(l)] = make_float2(cr2 * ex - ci2 * ey, cr2 * ey + ci2 * ex);
    }
    __syncthreads();
    // inverse 2048-pt (conjugated DIF), digits 16 x 16 x 8
    if (t < 128) {
        float2 v[16];
#pragma unroll
        for (int k = 0; k < 16; k++) v[k] = data[sw(t + 128 * k)];
        fft16_dif<true>(v);
#pragma unroll
        for (int i = 1; i < 16; i++) v[i] = cmulc(v[i], twget(tw, 2 * t * BR4[i]));
#pragma unroll
        for (int i = 0; i < 16; i++) data[sw(i * 128 + t)] = v[i];
    }
    __syncthreads();
    if (t < 128) {
        int i2 = t >> 3, j0 = t & 7;
        int base2 = i2 * 128 + j0;
        float2 v[16];
#pragma unroll
        for (int k = 0; k < 16; k++) v[k] = data[sw(base2 + 8 * k)];
        fft16_dif<true>(v);
#pragma unroll
        for (int i = 1; i < 16; i++) v[i] = cmulc(v[i], twget(tw, 32 * j0 * BR4[i]));
#pragma unroll
        for (int i = 0; i < 16; i++) data[sw(base2 + 8 * i)] = v[i];
    }
    __syncthreads();
    {
        float2 v8[8];
#pragma unroll
        for (int k = 0; k < 8; k++) v8[k] = data[sw(t * 8 + k)];
        fft8_dif<true>(v8);
        int r = BR4[t >> 4], s = BR4[t & 15];
#pragma unroll
        for (int i = 0; i < 8; i++) {
            int l = r + 16 * s + 256 * BR3[i];
            ktmp[l] = v8[i].x * (1.0f / 2048.0f);
        }
    }
    __syncthreads();
#pragma unroll
    for (int k = 0; k < 8; k++) {
        int l = t + 256 * k;
        data[sw(l)] = make_float2(ktmp[l], 0.f);
        data[sw(l + 2048)] = make_float2(0.f, 0.f);
    }
    fft4096_fwd(data, tw, t);
    float2* dst = (float2*)(Kd2 + ((size_t)layer * 64 + (h >> 1)) * 4096);
    int half = h & 1;
#pragma unroll
    for (int k = 0; k < 16; k++) {
        int p = t + 256 * k;
        dst[2 * p + half] = data[sw(p)];
    }
}

// ---------------- FFT convolution + D-skip + gelu, channel pair per block ----------------
__global__ __launch_bounds__(256) void conv_kernel(float* __restrict__ hn,
                                                   const float4* __restrict__ Kd2,
                                                   const float* __restrict__ dvec,
                                                   const float2* __restrict__ tw) {
    int hp = blockIdx.x, b = blockIdx.y, h0 = hp * 2, t = threadIdx.x;
    __shared__ float2 data[4096];
    float* base = hn + (size_t)b * Lseq * Hdim + h0;
    float2 ureg[8];
#pragma unroll
    for (int k = 0; k < 8; k++) {
        int l = t + 256 * k;
        float2 u2 = *(const float2*)(base + (size_t)l * Hdim);
        ureg[k] = u2;
        data[sw(l)] = u2;
        data[sw(l + 2048)] = make_float2(0.f, 0.f);
    }
    fft4096_fwd(data, tw, t);
    const float4* Kp = Kd2 + (size_t)hp * 4096;
    const float scale = 1.0f / 4096.0f;
    for (int f = t; f <= 2048; f += 256) {
        int fm = (4096 - f) & 4095;
        int p = __brev((unsigned)f) >> 20;
        int pm = __brev((unsigned)fm) >> 20;
        float2 Zf = data[sw(p)], Zm = data[sw(pm)];
        float2 U0 = make_float2(0.5f * (Zf.x + Zm.x), 0.5f * (Zf.y - Zm.y));
        float2 Dm = make_float2(Zf.x - Zm.x, Zf.y + Zm.y);
        float2 U1 = make_float2(0.5f * Dm.y, -0.5f * Dm.x);
        float4 Ka = Kp[p];
        float2 S0 = cmulf(U0, make_float2(Ka.x, Ka.y));
        float2 S1 = cmulf(U1, make_float2(Ka.z, Ka.w));
        float2 Wf = make_float2((S0.x - S1.y) * scale, (S0.y + S1.x) * scale);
        float4 Kb = Kp[pm];
        float2 U0m = make_float2(U0.x, -U0.y);
        float2 U1m = make_float2(U1.x, -U1.y);
        float2 S0m = cmulf(U0m, make_float2(Kb.x, Kb.y));
        float2 S1m = cmulf(U1m, make_float2(Kb.z, Kb.w));
        float2 Wm = make_float2((S0m.x - S1m.y) * scale, (S0m.y + S1m.x) * scale);
        data[sw(p)] = Wf;
        if (pm != p) data[sw(pm)] = Wm;
    }
    __syncthreads();
    {
        float2 v[16];
#pragma unroll
        for (int i = 0; i < 16; i++) v[i] = data[sw(t * 16 + i)];
        fft16_dit<true>(v);
#pragma unroll
        for (int i = 0; i < 16; i++) data[sw(t * 16 + i)] = v[i];
    }
    __syncthreads();
    {
        int j0 = t & 15;
        int base2 = (t >> 4) * 256 + j0;
        float2 v[16];
        v[0] = data[sw(base2)];
#pragma unroll
        for (int i = 1; i < 16; i++)
            v[i] = cmulc(data[sw(base2 + 16 * i)], twget(tw, 16 * j0 * BR4[i]));
        fft16_dit<true>(v);
#pragma unroll
        for (int i = 0; i < 16; i++) data[sw(base2 + 16 * i)] = v[i];
    }
    __syncthreads();
    {
        float2 v[16];
        v[0] = data[sw(t)];
#pragma unroll
        for (int i = 1; i < 16; i++)
            v[i] = cmulc(data[sw(i * 256 + t)], twget(tw, t * BR4[i]));
        fft16_dit<true>(v);
        float d0 = dvec[h0], d1 = dvec[h0 + 1];
#pragma unroll
        for (int k = 0; k < 8; k++) {
            float y0 = gelu_f(v[k].x + ureg[k].x * d0);
            float y1 = gelu_f(v[k].y + ureg[k].y * d1);
            *(float2*)(base + (size_t)(t + 256 * k) * Hdim) = make_float2(y0, y1);
        }
    }
}

// ---------------- gated MLP + residual + fused next-layer LN: 16 rows/block ----------------
__global__ __launch_bounds__(256) void mlp_kernel(const float* __restrict__ y,
                                                  float* __restrict__ h,
                                                  float* __restrict__ hn,
                                                  const float* __restrict__ w1,
                                                  const float* __restrict__ b1,
                                                  const float* __restrict__ w2,
                                                  const float* __restrict__ b2,
                                                  const float* __restrict__ nw,
                                                  const float* __restrict__ nb,
                                                  int do_ln) {
    int r0 = blockIdx.x * 16;
    int t = threadIdx.x;
    __shared__ float ws[2 * 128 * 17];             // KC=16 chunk of w1|w2, pad 17
    __shared__ __align__(16) float yst[128 * 20];  // y transposed [k][r], pad 20
    __shared__ float dots[16 * 256];
    __shared__ float2 mv[16];
    for (int i = t; i < 16 * 128; i += 256) {
        int r = i >> 7, k = i & 127;
        yst[k * 20 + r] = y[(size_t)(r0 + r) * Hdim + k];
    }
    int oo = t & 127, sel = t >> 7;
    float acc[16];
    float bias = sel ? b2[oo] : b1[oo];
#pragma unroll
    for (int r = 0; r < 16; r++) acc[r] = bias;
    for (int kc0 = 0; kc0 < 128; kc0 += 16) {
        __syncthreads();  // protect previous chunk reads (and yst fill on first iter)
        for (int i = t; i < 4096; i += 256) {
            int s = i >> 11, rem = i & 2047, o = rem >> 4, k = rem & 15;
            ws[s * 2176 + o * 17 + k] = (s ? w2 : w1)[(size_t)o * Hdim + kc0 + k];
        }
        __syncthreads();
#pragma unroll
        for (int k = 0; k < 16; k++) {
            float wv = ws[sel * 2176 + oo * 17 + k];
            int kk = (kc0 + k) * 20;
            float4 ya = *(const float4*)&yst[kk];
            float4 yb = *(const float4*)&yst[kk + 4];
            float4 yc = *(const float4*)&yst[kk + 8];
            float4 yd = *(const float4*)&yst[kk + 12];
            acc[0] += wv * ya.x;  acc[1] += wv * ya.y;  acc[2] += wv * ya.z;  acc[3] += wv * ya.w;
            acc[4] += wv * yb.x;  acc[5] += wv * yb.y;  acc[6] += wv * yb.z;  acc[7] += wv * yb.w;
            acc[8] += wv * yc.x;  acc[9] += wv * yc.y;  acc[10] += wv * yc.z; acc[11] += wv * yc.w;
            acc[12] += wv * yd.x; acc[13] += wv * yd.y; acc[14] += wv * yd.z; acc[15] += wv * yd.w;
        }
    }
#pragma unroll
    for (int r = 0; r < 16; r++) dots[r * 256 + t] = acc[r];
    __syncthreads();
    int c = t & 127;
    // h_new = h_old + v1 * sigmoid(v2); stash in dots (each slot read+written by same thread)
#pragma unroll
    for (int j = 0; j < 8; j++) {
        int r = (t >> 7) + 2 * j;
        float v1 = dots[r * 256 + c], v2 = dots[r * 256 + c + 128];
        float hN = h[(size_t)(r0 + r) * Hdim + c] + v1 * (1.0f / (1.0f + expf(-v2)));
        dots[r * 256 + c] = hN;
    }
    __syncthreads();
    if (do_ln) {
        int row = t >> 4, lane = t & 15;
        float s1 = 0.f, s2 = 0.f;
#pragma unroll
        for (int i = 0; i < 8; i++) {
            float v = dots[row * 256 + lane * 8 + i];
            s1 += v; s2 += v * v;
        }
#pragma unroll
        for (int m = 1; m < 16; m <<= 1) { s1 += __shfl_xor(s1, m); s2 += __shfl_xor(s2, m); }
        if (lane == 0) {
            float mu = s1 * (1.0f / 128.0f);
            float var = s2 * (1.0f / 128.0f) - mu * mu;
            mv[row] = make_float2(mu, rsqrtf(var + 1e-5f));
        }
        __syncthreads();
        float nwc = nw[c], nbc = nb[c];
#pragma unroll
        for (int j = 0; j < 8; j++) {
            int r = (t >> 7) + 2 * j;
            float v = dots[r * 256 + c];
            size_t idx = (size_t)(r0 + r) * Hdim + c;
            h[idx] = v;
            float2 m = mv[r];
            hn[idx] = (v - m.x) * m.y * nwc + nbc;
        }
    } else {
#pragma unroll
        for (int j = 0; j < 8; j++) {
            int r = (t >> 7) + 2 * j;
            h[(size_t)(r0 + r) * Hdim + c] = dots[r * 256 + c];
        }
    }
}

// ---------------- decoder: 32 rows/block ----------------
__global__ __launch_bounds__(256) void decoder_kernel(const float* __restrict__ h,
                                                      const float* __restrict__ w,
                                                      const float* __restrict__ b,
                                                      float* __restrict__ out) {
    int r0 = blockIdx.x * 32;
    int t = threadIdx.x;
    __shared__ float ws[64 * 129];                 // w[o][k], pad 129
    __shared__ __align__(16) float hst[128 * 36];  // h transposed [k][r], pad 36
    for (int i = t; i < 64 * 128; i += 256) ws[(i >> 7) * 129 + (i & 127)] = w[i];
    for (int i = t; i < 32 * 128; i += 256) {
        int r = i >> 7, k = i & 127;
        hst[k * 36 + r] = h[(size_t)(r0 + r) * Hdim + k];
    }
    __syncthreads();
    int o = t & 63, q = t >> 6;  // q: 4 row-groups of 8
    float acc[8];
    float bo = b[o];
#pragma unroll
    for (int j = 0; j < 8; j++) acc[j] = bo;
    for (int k = 0; k < 128; k++) {
        float wv = ws[o * 129 + k];
        float4 ha = *(const float4*)&hst[k * 36 + q * 8];
        float4 hb = *(const float4*)&hst[k * 36 + q * 8 + 4];
        acc[0] += wv * ha.x; acc[1] += wv * ha.y; acc[2] += wv * ha.z; acc[3] += wv * ha.w;
        acc[4] += wv * hb.x; acc[5] += wv * hb.y; acc[6] += wv * hb.z; acc[7] += wv * hb.w;
    }
#pragma unroll
    for (int j = 0; j < 8; j++) out[(size_t)(r0 + q * 8 + j) * 64 + o] = acc[j];
}

extern "C" void kernel_launch(void* const* d_in, const int* in_sizes, int n_in,
                              void* d_out, int out_size, void* d_ws, size_t ws_size,
                              hipStream_t stream) {
    const float* x      = (const float*)d_in[0];
    const float* enc_w  = (const float*)d_in[2];
    const float* enc_b  = (const float*)d_in[3];
    const float* dec_w  = (const float*)d_in[4];
    const float* dec_b  = (const float*)d_in[5];
    const float* lam_re = (const float*)d_in[6];
    const float* lam_im = (const float*)d_in[7];
    const float* p_re   = (const float*)d_in[8];
    const float* p_im   = (const float*)d_in[9];
    const float* b_re   = (const float*)d_in[10];
    const float* b_im   = (const float*)d_in[11];
    const float* c_re   = (const float*)d_in[12];
    const float* c_im   = (const float*)d_in[13];
    const float* dvec   = (const float*)d_in[14];
    const float* lstep  = (const float*)d_in[15];
    const float* norm_w = (const float*)d_in[16];
    const float* norm_b = (const float*)d_in[17];
    const float* w1     = (const float*)d_in[18];
    const float* b1     = (const float*)d_in[19];
    const float* w2     = (const float*)d_in[20];
    const float* b2     = (const float*)d_in[21];
    float* out = (float*)d_out;

    char* ws = (char*)d_ws;
    float2* tw  = (float2*)ws;  ws += 2048 * sizeof(float2);
    float*  h   = (float*)ws;   ws += (size_t)Bsz * Lseq * Hdim * sizeof(float);
    float*  hn  = (float*)ws;   ws += (size_t)Bsz * Lseq * Hdim * sizeof(float);
    float4* Kd2 = (float4*)ws;  ws += (size_t)NLAYERS * (Hdim / 2) * 4096 * sizeof(float4);

    const int nrows = Bsz * Lseq;  // 16384

    twiddle_init<<<8, 256, 0, stream>>>(tw);
    specfft_kernel<<<dim3(Hdim, NLAYERS), 256, 0, stream>>>(
        lam_re, lam_im, p_re, p_im, b_re, b_im, c_re, c_im, lstep, Kd2, tw);
    encoder_kernel<<<nrows / 16, 256, 0, stream>>>(x, enc_w, enc_b, norm_w, norm_b, h, hn);
    for (int L = 0; L < NLAYERS; L++) {
        conv_kernel<<<dim3(Hdim / 2, Bsz), 256, 0, stream>>>(
            hn, Kd2 + (size_t)L * (Hdim / 2) * 4096, dvec + L * Hdim, tw);
        int do_ln = (L < NLAYERS - 1) ? 1 : 0;
        const float* nwn = norm_w + ((L + 1) % NLAYERS) * Hdim;
        const float* nbn = norm_b + ((L + 1) % NLAYERS) * Hdim;
        mlp_kernel<<<nrows / 16, 256, 0, stream>>>(hn, h, hn,
                                                   w1 + (size_t)L * Hdim * Hdim, b1 + L * Hdim,
                                                   w2 + (size_t)L * Hdim * Hdim, b2 + L * Hdim,
                                                   nwn, nbn, do_ln);
    }
    decoder_kernel<<<nrows / 32, 256, 0, stream>>>(h, dec_w, dec_b, out);
}

// Round 4
// 516.639 us; speedup vs baseline: 1.7257x; 1.0365x over previous
//
#include <hip/hip_runtime.h>
#include <hip/hip_bf16.h>

// S4 (DPLR) forward, B=8 L=2048 IN=OUT=64 H=128 N=64, 4 layers.
// R4: specfft split into high-occupancy spectrum (2048 blocks) + kfft (512 blocks);
// IEEE div/rsqrt sequences replaced with v_rcp/v_rsq/fast-exp intrinsics
// (no -ffast-math in harness, so 1/x was a ~10-inst div sequence).

#define Bsz 8
#define Lseq 2048
#define Hdim 128
#define Npol 64
#define NLAYERS 4

__device__ __forceinline__ float fast_rcp(float x) { return __builtin_amdgcn_rcpf(x); }
__device__ __forceinline__ float fast_rsq(float x) { return __builtin_amdgcn_rsqf(x); }

__device__ __forceinline__ float2 cmulf(float2 a, float2 b) {
    return make_float2(a.x * b.x - a.y * b.y, a.x * b.y + a.y * b.x);
}
__device__ __forceinline__ float2 cmulc(float2 a, float2 b) {  // a * conj(b)
    return make_float2(a.x * b.x + a.y * b.y, a.y * b.x - a.x * b.y);
}

__device__ __forceinline__ float gelu_f(float v) {
    // 0.5v(1+tanh(z)) = v*sigmoid(2z) = v - v*rcp(exp(2z)+1)
    float z = 0.7978845608028654f * (v + 0.044715f * v * v * v);
    float e = __expf(2.0f * z);
    return v - v * fast_rcp(e + 1.0f);
}

// XOR swizzle: mixes digit1 into the bank digit so strides 1/16/256 are all conflict-uniform.
__device__ __forceinline__ int sw(int i) { return (i & ~15) | ((i ^ (i >> 4)) & 15); }

static __device__ const float W16R[8] = {1.f, 0.9238795325f, 0.7071067812f, 0.3826834324f,
                                         0.f, -0.3826834324f, -0.7071067812f, -0.9238795325f};
static __device__ const float W16I[8] = {0.f, -0.3826834324f, -0.7071067812f, -0.9238795325f,
                                         -1.f, -0.9238795325f, -0.7071067812f, -0.3826834324f};
static __device__ const int BR4[16] = {0, 8, 4, 12, 2, 10, 6, 14, 1, 9, 5, 13, 3, 11, 7, 15};
static __device__ const int BR3[8] = {0, 4, 2, 6, 1, 5, 3, 7};

__device__ __forceinline__ float2 twget(const float2* __restrict__ tw, int e) {
    float2 w = tw[e & 2047];
    if (e & 2048) { w.x = -w.x; w.y = -w.y; }
    return w;
}

template <bool INV>
__device__ __forceinline__ void fft16_dif(float2 v[16]) {
#pragma unroll
    for (int mi = 0; mi < 4; mi++) {
        const int m = 8 >> mi;
#pragma unroll
        for (int g = 0; g < 16; g += 2 * m) {
#pragma unroll
            for (int j = 0; j < m; j++) {
                float wr = W16R[j << mi];
                float wi = INV ? -W16I[j << mi] : W16I[j << mi];
                float2 a = v[g + j], b = v[g + j + m];
                float dx = a.x - b.x, dy = a.y - b.y;
                v[g + j] = make_float2(a.x + b.x, a.y + b.y);
                v[g + j + m] = make_float2(dx * wr - dy * wi, dx * wi + dy * wr);
            }
        }
    }
}

template <bool INV>
__device__ __forceinline__ void fft16_dit(float2 v[16]) {
#pragma unroll
    for (int mi = 3; mi >= 0; mi--) {
        const int m = 8 >> mi;
#pragma unroll
        for (int g = 0; g < 16; g += 2 * m) {
#pragma unroll
            for (int j = 0; j < m; j++) {
                float wr = W16R[j << mi];
                float wi = INV ? -W16I[j << mi] : W16I[j << mi];
                float2 a = v[g + j], b = v[g + j + m];
                float bx = b.x * wr - b.y * wi, by = b.x * wi + b.y * wr;
                v[g + j] = make_float2(a.x + bx, a.y + by);
                v[g + j + m] = make_float2(a.x - bx, a.y - by);
            }
        }
    }
}

template <bool INV>
__device__ __forceinline__ void fft8_dif(float2 v[8]) {
#pragma unroll
    for (int mi = 0; mi < 3; mi++) {
        const int m = 4 >> mi;
#pragma unroll
        for (int g = 0; g < 8; g += 2 * m) {
#pragma unroll
            for (int j = 0; j < m; j++) {
                float wr = W16R[j << (mi + 1)];
                float wi = INV ? -W16I[j << (mi + 1)] : W16I[j << (mi + 1)];
                float2 a = v[g + j], b = v[g + j + m];
                float dx = a.x - b.x, dy = a.y - b.y;
                v[g + j] = make_float2(a.x + b.x, a.y + b.y);
                v[g + j + m] = make_float2(dx * wr - dy * wi, dx * wi + dy * wr);
            }
        }
    }
}

// Forward 4096-pt FFT in LDS, 256 threads, result in 12-bit bit-reversed positions.
// No leading barrier IF caller's fill writes exactly {t+256k, k<16} per thread.
__device__ __forceinline__ void fft4096_fwd(float2* data, const float2* __restrict__ tw, int t) {
    {
        float2 v[16];
#pragma unroll
        for (int k = 0; k < 16; k++) v[k] = data[sw(t + 256 * k)];
        fft16_dif<false>(v);
#pragma unroll
        for (int i = 1; i < 16; i++) v[i] = cmulf(v[i], twget(tw, t * BR4[i]));
#pragma unroll
        for (int i = 0; i < 16; i++) data[sw(i * 256 + t)] = v[i];
    }
    __syncthreads();
    {
        int j0 = t & 15;
        int base = (t >> 4) * 256 + j0;
        float2 v[16];
#pragma unroll
        for (int k = 0; k < 16; k++) v[k] = data[sw(base + 16 * k)];
        fft16_dif<false>(v);
#pragma unroll
        for (int i = 1; i < 16; i++) v[i] = cmulf(v[i], twget(tw, 16 * j0 * BR4[i]));
#pragma unroll
        for (int i = 0; i < 16; i++) data[sw(base + 16 * i)] = v[i];
    }
    __syncthreads();
    {
        float2 v[16];
#pragma unroll
        for (int k = 0; k < 16; k++) v[k] = data[sw(t * 16 + k)];
        fft16_dif<false>(v);
#pragma unroll
        for (int i = 0; i < 16; i++) data[sw(t * 16 + i)] = v[i];
    }
    __syncthreads();
}

// ---------------- twiddle table ----------------
__global__ __launch_bounds__(256) void twiddle_init(float2* tw) {
    int k = blockIdx.x * blockDim.x + threadIdx.x;
    if (k < 2048) {
        double a = -6.283185307179586476925286766559 * (double)k / 4096.0;
        tw[k] = make_float2((float)cos(a), (float)sin(a));
    }
}

// ---------------- encoder + fused LN: 16 rows/block ----------------
__global__ __launch_bounds__(256) void encoder_kernel(const float* __restrict__ x,
                                                      const float* __restrict__ w,
                                                      const float* __restrict__ b,
                                                      const float* __restrict__ nw,
                                                      const float* __restrict__ nb,
                                                      float* __restrict__ h,
                                                      float* __restrict__ hn) {
    int r0 = blockIdx.x * 16;
    int t = threadIdx.x;
    __shared__ float ws[128 * 65];
    __shared__ __align__(16) float xst[64 * 20];
    __shared__ float dots[16 * 128];
    __shared__ float2 mv[16];
    for (int i = t; i < 128 * 64; i += 256) ws[(i >> 6) * 65 + (i & 63)] = w[i];
    for (int i = t; i < 16 * 64; i += 256) {
        int r = i >> 6, k = i & 63;
        xst[k * 20 + r] = x[(size_t)(r0 + r) * 64 + k];
    }
    __syncthreads();
    int o = t & 127, half = t >> 7;
    float acc[8];
    float bo = b[o];
#pragma unroll
    for (int j = 0; j < 8; j++) acc[j] = bo;
    for (int k = 0; k < 64; k++) {
        float wv = ws[o * 65 + k];
        float4 xa = *(const float4*)&xst[k * 20 + half * 8];
        float4 xb = *(const float4*)&xst[k * 20 + half * 8 + 4];
        acc[0] += wv * xa.x; acc[1] += wv * xa.y; acc[2] += wv * xa.z; acc[3] += wv * xa.w;
        acc[4] += wv * xb.x; acc[5] += wv * xb.y; acc[6] += wv * xb.z; acc[7] += wv * xb.w;
    }
#pragma unroll
    for (int j = 0; j < 8; j++) dots[(half * 8 + j) * 128 + o] = acc[j];
    __syncthreads();
    {
        int row = t >> 4, lane = t & 15;
        float s1 = 0.f, s2 = 0.f;
#pragma unroll
        for (int i = 0; i < 8; i++) {
            float v = dots[row * 128 + lane * 8 + i];
            s1 += v; s2 += v * v;
        }
#pragma unroll
        for (int m = 1; m < 16; m <<= 1) { s1 += __shfl_xor(s1, m); s2 += __shfl_xor(s2, m); }
        if (lane == 0) {
            float mu = s1 * (1.0f / 128.0f);
            float var = s2 * (1.0f / 128.0f) - mu * mu;
            mv[row] = make_float2(mu, fast_rsq(var + 1e-5f));
        }
    }
    __syncthreads();
    int c = t & 127;
    float nwc = nw[c], nbc = nb[c];
#pragma unroll
    for (int j = 0; j < 8; j++) {
        int r = (t >> 7) + 2 * j;
        float v = dots[r * 128 + c];
        size_t idx = (size_t)(r0 + r) * Hdim + c;
        h[idx] = v;
        float2 m = mv[r];
        hn[idx] = (v - m.x) * m.y * nwc + nbc;
    }
}

// ---------------- DPLR generating function: 2048 blocks, 512 l's each ----------------
__global__ __launch_bounds__(256) void spectrum_kernel(const float* __restrict__ lam_re,
                                                       const float* __restrict__ lam_im,
                                                       const float* __restrict__ p_re,
                                                       const float* __restrict__ p_im,
                                                       const float* __restrict__ b_re,
                                                       const float* __restrict__ b_im,
                                                       const float* __restrict__ c_re,
                                                       const float* __restrict__ c_im,
                                                       const float* __restrict__ log_step,
                                                       float2* __restrict__ at_roots) {
    int h = blockIdx.x, layer = blockIdx.y, t = threadIdx.x;
    __shared__ float2 lamS[Npol], n00S[Npol], n01S[Npol], n10S[Npol];
    __shared__ float n11S[Npol];
    int baseP = (layer * Hdim + h) * Npol;
    if (t < Npol) {
        int n = t;
        float lr = lam_re[baseP + n], li = lam_im[baseP + n];
        float pr = p_re[baseP + n], pi = p_im[baseP + n];
        float br = b_re[baseP + n], bi = b_im[baseP + n];
        float cr = c_re[baseP + n], ci = c_im[baseP + n];
        lamS[n] = make_float2(lr, li);
        n00S[n] = make_float2(cr * br + ci * bi, cr * bi - ci * br);
        n01S[n] = make_float2(cr * pr + ci * pi, cr * pi - ci * pr);
        n10S[n] = make_float2(pr * br + pi * bi, pr * bi - pi * br);
        n11S[n] = pr * pr + pi * pi;
    }
    __syncthreads();
    float step = expf(log_step[layer * Hdim + h]);
    float gs = 2.0f / step;
    int l0 = 512 * blockIdx.z;
    for (int l = l0 + t; l < l0 + 512; l += 256) {
        float ang = -6.283185307179586f * (float)l / (float)Lseq;
        float wr = cosf(ang), wi = sinf(ang);  // fp32 omega on purpose: keeps |g|^2 in range
        float dr = 1.0f + wr, di = wi;
        float invd2 = fast_rcp(dr * dr + di * di);
        float nr = 1.0f - wr, ni = -wi;
        float gr = gs * (nr * dr + ni * di) * invd2;
        float gi = gs * (ni * dr - nr * di) * invd2;
        float cr2 = 2.0f * dr * invd2, ci2 = -2.0f * di * invd2;
        float k00x = 0, k00y = 0, k01x = 0, k01y = 0, k10x = 0, k10y = 0, k11x = 0, k11y = 0;
#pragma unroll 8
        for (int n = 0; n < Npol; n++) {
            float er = gr - lamS[n].x, ei = gi - lamS[n].y;
            float inv2 = fast_rcp(fmaf(er, er, ei * ei));
            float ir = er * inv2, ii = -ei * inv2;
            k00x += n00S[n].x * ir - n00S[n].y * ii; k00y += n00S[n].x * ii + n00S[n].y * ir;
            k01x += n01S[n].x * ir - n01S[n].y * ii; k01y += n01S[n].x * ii + n01S[n].y * ir;
            k10x += n10S[n].x * ir - n10S[n].y * ii; k10y += n10S[n].x * ii + n10S[n].y * ir;
            k11x += n11S[n] * ir;                    k11y += n11S[n] * ii;
        }
        float wr2 = 1.0f + k11x, wi2 = k11y;
        float w2inv = fast_rcp(wr2 * wr2 + wi2 * wi2);
        float vr = wr2 * w2inv, vi = -wi2 * w2inv;
        float t1x = k01x * k10x - k01y * k10y, t1y = k01x * k10y + k01y * k10x;
        float t2x = t1x * vr - t1y * vi, t2y = t1x * vi + t1y * vr;
        float ex = k00x - t2x, ey = k00y - t2y;
        at_roots[((size_t)layer * Hdim + h) * Lseq + l] =
            make_float2(cr2 * ex - ci2 * ey, cr2 * ey + ci2 * ex);
    }
}

// ---------------- kernel FFT: ifft2048 -> pad -> fft4096, all layers ----------------
// Kd2 layout: [layer][hp][p] float4 = (K_{2hp}[p].re,.im, K_{2hp+1}[p].re,.im), p bit-rev.
__global__ __launch_bounds__(256) void kfft_kernel(const float2* __restrict__ at_roots,
                                                   float4* __restrict__ Kd2,
                                                   const float2* __restrict__ tw) {
    int h = blockIdx.x, layer = blockIdx.y, t = threadIdx.x;
    __shared__ float2 data[4096];
    __shared__ float ktmp[2048];
    const float2* src = at_roots + ((size_t)layer * Hdim + h) * Lseq;
#pragma unroll
    for (int k = 0; k < 8; k++) {
        int l = t + 256 * k;
        data[sw(l)] = src[l];
    }
    __syncthreads();
    // inverse 2048-pt (conjugated DIF), digits 16 x 16 x 8
    if (t < 128) {
        float2 v[16];
#pragma unroll
        for (int k = 0; k < 16; k++) v[k] = data[sw(t + 128 * k)];
        fft16_dif<true>(v);
#pragma unroll
        for (int i = 1; i < 16; i++) v[i] = cmulc(v[i], twget(tw, 2 * t * BR4[i]));
#pragma unroll
        for (int i = 0; i < 16; i++) data[sw(i * 128 + t)] = v[i];
    }
    __syncthreads();
    if (t < 128) {
        int i2 = t >> 3, j0 = t & 7;
        int base2 = i2 * 128 + j0;
        float2 v[16];
#pragma unroll
        for (int k = 0; k < 16; k++) v[k] = data[sw(base2 + 8 * k)];
        fft16_dif<true>(v);
#pragma unroll
        for (int i = 1; i < 16; i++) v[i] = cmulc(v[i], twget(tw, 32 * j0 * BR4[i]));
#pragma unroll
        for (int i = 0; i < 16; i++) data[sw(base2 + 8 * i)] = v[i];
    }
    __syncthreads();
    {
        float2 v8[8];
#pragma unroll
        for (int k = 0; k < 8; k++) v8[k] = data[sw(t * 8 + k)];
        fft8_dif<true>(v8);
        int r = BR4[t >> 4], s = BR4[t & 15];
#pragma unroll
        for (int i = 0; i < 8; i++) {
            int l = r + 16 * s + 256 * BR3[i];
            ktmp[l] = v8[i].x * (1.0f / 2048.0f);
        }
    }
    __syncthreads();
#pragma unroll
    for (int k = 0; k < 8; k++) {
        int l = t + 256 * k;
        data[sw(l)] = make_float2(ktmp[l], 0.f);
        data[sw(l + 2048)] = make_float2(0.f, 0.f);
    }
    fft4096_fwd(data, tw, t);
    float2* dst = (float2*)(Kd2 + ((size_t)layer * 64 + (h >> 1)) * 4096);
    int half = h & 1;
#pragma unroll
    for (int k = 0; k < 16; k++) {
        int p = t + 256 * k;
        dst[2 * p + half] = data[sw(p)];
    }
}

// ---------------- FFT convolution + D-skip + gelu, channel pair per block ----------------
__global__ __launch_bounds__(256) void conv_kernel(float* __restrict__ hn,
                                                   const float4* __restrict__ Kd2,
                                                   const float* __restrict__ dvec,
                                                   const float2* __restrict__ tw) {
    int hp = blockIdx.x, b = blockIdx.y, h0 = hp * 2, t = threadIdx.x;
    __shared__ float2 data[4096];
    float* base = hn + (size_t)b * Lseq * Hdim + h0;
    float2 ureg[8];
#pragma unroll
    for (int k = 0; k < 8; k++) {
        int l = t + 256 * k;
        float2 u2 = *(const float2*)(base + (size_t)l * Hdim);
        ureg[k] = u2;
        data[sw(l)] = u2;
        data[sw(l + 2048)] = make_float2(0.f, 0.f);
    }
    fft4096_fwd(data, tw, t);
    const float4* Kp = Kd2 + (size_t)hp * 4096;
    const float scale = 1.0f / 4096.0f;
    for (int f = t; f <= 2048; f += 256) {
        int fm = (4096 - f) & 4095;
        int p = __brev((unsigned)f) >> 20;
        int pm = __brev((unsigned)fm) >> 20;
        float2 Zf = data[sw(p)], Zm = data[sw(pm)];
        float2 U0 = make_float2(0.5f * (Zf.x + Zm.x), 0.5f * (Zf.y - Zm.y));
        float2 Dm = make_float2(Zf.x - Zm.x, Zf.y + Zm.y);
        float2 U1 = make_float2(0.5f * Dm.y, -0.5f * Dm.x);
        float4 Ka = Kp[p];
        float2 S0 = cmulf(U0, make_float2(Ka.x, Ka.y));
        float2 S1 = cmulf(U1, make_float2(Ka.z, Ka.w));
        float2 Wf = make_float2((S0.x - S1.y) * scale, (S0.y + S1.x) * scale);
        float4 Kb = Kp[pm];
        float2 U0m = make_float2(U0.x, -U0.y);
        float2 U1m = make_float2(U1.x, -U1.y);
        float2 S0m = cmulf(U0m, make_float2(Kb.x, Kb.y));
        float2 S1m = cmulf(U1m, make_float2(Kb.z, Kb.w));
        float2 Wm = make_float2((S0m.x - S1m.y) * scale, (S0m.y + S1m.x) * scale);
        data[sw(p)] = Wf;
        if (pm != p) data[sw(pm)] = Wm;
    }
    __syncthreads();
    {
        float2 v[16];
#pragma unroll
        for (int i = 0; i < 16; i++) v[i] = data[sw(t * 16 + i)];
        fft16_dit<true>(v);
#pragma unroll
        for (int i = 0; i < 16; i++) data[sw(t * 16 + i)] = v[i];
    }
    __syncthreads();
    {
        int j0 = t & 15;
        int base2 = (t >> 4) * 256 + j0;
        float2 v[16];
        v[0] = data[sw(base2)];
#pragma unroll
        for (int i = 1; i < 16; i++)
            v[i] = cmulc(data[sw(base2 + 16 * i)], twget(tw, 16 * j0 * BR4[i]));
        fft16_dit<true>(v);
#pragma unroll
        for (int i = 0; i < 16; i++) data[sw(base2 + 16 * i)] = v[i];
    }
    __syncthreads();
    {
        float2 v[16];
        v[0] = data[sw(t)];
#pragma unroll
        for (int i = 1; i < 16; i++)
            v[i] = cmulc(data[sw(i * 256 + t)], twget(tw, t * BR4[i]));
        fft16_dit<true>(v);
        float d0 = dvec[h0], d1 = dvec[h0 + 1];
#pragma unroll
        for (int k = 0; k < 8; k++) {
            float y0 = gelu_f(v[k].x + ureg[k].x * d0);
            float y1 = gelu_f(v[k].y + ureg[k].y * d1);
            *(float2*)(base + (size_t)(t + 256 * k) * Hdim) = make_float2(y0, y1);
        }
    }
}

// ---------------- gated MLP + residual + fused next-layer LN: 16 rows/block ----------------
__global__ __launch_bounds__(256) void mlp_kernel(const float* __restrict__ y,
                                                  float* __restrict__ h,
                                                  float* __restrict__ hn,
                                                  const float* __restrict__ w1,
                                                  const float* __restrict__ b1,
                                                  const float* __restrict__ w2,
                                                  const float* __restrict__ b2,
                                                  const float* __restrict__ nw,
                                                  const float* __restrict__ nb,
                                                  int do_ln) {
    int r0 = blockIdx.x * 16;
    int t = threadIdx.x;
    __shared__ float ws[2 * 128 * 17];
    __shared__ __align__(16) float yst[128 * 20];
    __shared__ float dots[16 * 256];
    __shared__ float2 mv[16];
    for (int i = t; i < 16 * 128; i += 256) {
        int r = i >> 7, k = i & 127;
        yst[k * 20 + r] = y[(size_t)(r0 + r) * Hdim + k];
    }
    int oo = t & 127, sel = t >> 7;
    float acc[16];
    float bias = sel ? b2[oo] : b1[oo];
#pragma unroll
    for (int r = 0; r < 16; r++) acc[r] = bias;
    for (int kc0 = 0; kc0 < 128; kc0 += 16) {
        __syncthreads();
        for (int i = t; i < 4096; i += 256) {
            int s = i >> 11, rem = i & 2047, o = rem >> 4, k = rem & 15;
            ws[s * 2176 + o * 17 + k] = (s ? w2 : w1)[(size_t)o * Hdim + kc0 + k];
        }
        __syncthreads();
#pragma unroll
        for (int k = 0; k < 16; k++) {
            float wv = ws[sel * 2176 + oo * 17 + k];
            int kk = (kc0 + k) * 20;
            float4 ya = *(const float4*)&yst[kk];
            float4 yb = *(const float4*)&yst[kk + 4];
            float4 yc = *(const float4*)&yst[kk + 8];
            float4 yd = *(const float4*)&yst[kk + 12];
            acc[0] += wv * ya.x;  acc[1] += wv * ya.y;  acc[2] += wv * ya.z;  acc[3] += wv * ya.w;
            acc[4] += wv * yb.x;  acc[5] += wv * yb.y;  acc[6] += wv * yb.z;  acc[7] += wv * yb.w;
            acc[8] += wv * yc.x;  acc[9] += wv * yc.y;  acc[10] += wv * yc.z; acc[11] += wv * yc.w;
            acc[12] += wv * yd.x; acc[13] += wv * yd.y; acc[14] += wv * yd.z; acc[15] += wv * yd.w;
        }
    }
#pragma unroll
    for (int r = 0; r < 16; r++) dots[r * 256 + t] = acc[r];
    __syncthreads();
    int c = t & 127;
#pragma unroll
    for (int j = 0; j < 8; j++) {
        int r = (t >> 7) + 2 * j;
        float v1 = dots[r * 256 + c], v2 = dots[r * 256 + c + 128];
        float hN = h[(size_t)(r0 + r) * Hdim + c] + v1 * fast_rcp(1.0f + __expf(-v2));
        dots[r * 256 + c] = hN;
    }
    __syncthreads();
    if (do_ln) {
        int row = t >> 4, lane = t & 15;
        float s1 = 0.f, s2 = 0.f;
#pragma unroll
        for (int i = 0; i < 8; i++) {
            float v = dots[row * 256 + lane * 8 + i];
            s1 += v; s2 += v * v;
        }
#pragma unroll
        for (int m = 1; m < 16; m <<= 1) { s1 += __shfl_xor(s1, m); s2 += __shfl_xor(s2, m); }
        if (lane == 0) {
            float mu = s1 * (1.0f / 128.0f);
            float var = s2 * (1.0f / 128.0f) - mu * mu;
            mv[row] = make_float2(mu, fast_rsq(var + 1e-5f));
        }
        __syncthreads();
        float nwc = nw[c], nbc = nb[c];
#pragma unroll
        for (int j = 0; j < 8; j++) {
            int r = (t >> 7) + 2 * j;
            float v = dots[r * 256 + c];
            size_t idx = (size_t)(r0 + r) * Hdim + c;
            h[idx] = v;
            float2 m = mv[r];
            hn[idx] = (v - m.x) * m.y * nwc + nbc;
        }
    } else {
#pragma unroll
        for (int j = 0; j < 8; j++) {
            int r = (t >> 7) + 2 * j;
            h[(size_t)(r0 + r) * Hdim + c] = dots[r * 256 + c];
        }
    }
}

// ---------------- decoder: 32 rows/block ----------------
__global__ __launch_bounds__(256) void decoder_kernel(const float* __restrict__ h,
                                                      const float* __restrict__ w,
                                                      const float* __restrict__ b,
                                                      float* __restrict__ out) {
    int r0 = blockIdx.x * 32;
    int t = threadIdx.x;
    __shared__ float ws[64 * 129];
    __shared__ __align__(16) float hst[128 * 36];
    for (int i = t; i < 64 * 128; i += 256) ws[(i >> 7) * 129 + (i & 127)] = w[i];
    for (int i = t; i < 32 * 128; i += 256) {
        int r = i >> 7, k = i & 127;
        hst[k * 36 + r] = h[(size_t)(r0 + r) * Hdim + k];
    }
    __syncthreads();
    int o = t & 63, q = t >> 6;
    float acc[8];
    float bo = b[o];
#pragma unroll
    for (int j = 0; j < 8; j++) acc[j] = bo;
    for (int k = 0; k < 128; k++) {
        float wv = ws[o * 129 + k];
        float4 ha = *(const float4*)&hst[k * 36 + q * 8];
        float4 hb = *(const float4*)&hst[k * 36 + q * 8 + 4];
        acc[0] += wv * ha.x; acc[1] += wv * ha.y; acc[2] += wv * ha.z; acc[3] += wv * ha.w;
        acc[4] += wv * hb.x; acc[5] += wv * hb.y; acc[6] += wv * hb.z; acc[7] += wv * hb.w;
    }
#pragma unroll
    for (int j = 0; j < 8; j++) out[(size_t)(r0 + q * 8 + j) * 64 + o] = acc[j];
}

extern "C" void kernel_launch(void* const* d_in, const int* in_sizes, int n_in,
                              void* d_out, int out_size, void* d_ws, size_t ws_size,
                              hipStream_t stream) {
    const float* x      = (const float*)d_in[0];
    const float* enc_w  = (const float*)d_in[2];
    const float* enc_b  = (const float*)d_in[3];
    const float* dec_w  = (const float*)d_in[4];
    const float* dec_b  = (const float*)d_in[5];
    const float* lam_re = (const float*)d_in[6];
    const float* lam_im = (const float*)d_in[7];
    const float* p_re   = (const float*)d_in[8];
    const float* p_im   = (const float*)d_in[9];
    const float* b_re   = (const float*)d_in[10];
    const float* b_im   = (const float*)d_in[11];
    const float* c_re   = (const float*)d_in[12];
    const float* c_im   = (const float*)d_in[13];
    const float* dvec   = (const float*)d_in[14];
    const float* lstep  = (const float*)d_in[15];
    const float* norm_w = (const float*)d_in[16];
    const float* norm_b = (const float*)d_in[17];
    const float* w1     = (const float*)d_in[18];
    const float* b1     = (const float*)d_in[19];
    const float* w2     = (const float*)d_in[20];
    const float* b2     = (const float*)d_in[21];
    float* out = (float*)d_out;

    char* ws = (char*)d_ws;
    float2* tw  = (float2*)ws;  ws += 2048 * sizeof(float2);
    float*  h   = (float*)ws;   ws += (size_t)Bsz * Lseq * Hdim * sizeof(float);
    float*  hn  = (float*)ws;   ws += (size_t)Bsz * Lseq * Hdim * sizeof(float);
    float2* atr = (float2*)ws;  ws += (size_t)NLAYERS * Hdim * Lseq * sizeof(float2);
    float4* Kd2 = (float4*)ws;  ws += (size_t)NLAYERS * (Hdim / 2) * 4096 * sizeof(float4);

    const int nrows = Bsz * Lseq;  // 16384

    twiddle_init<<<8, 256, 0, stream>>>(tw);
    spectrum_kernel<<<dim3(Hdim, NLAYERS, 4), 256, 0, stream>>>(
        lam_re, lam_im, p_re, p_im, b_re, b_im, c_re, c_im, lstep, atr);
    kfft_kernel<<<dim3(Hdim, NLAYERS), 256, 0, stream>>>(atr, Kd2, tw);
    encoder_kernel<<<nrows / 16, 256, 0, stream>>>(x, enc_w, enc_b, norm_w, norm_b, h, hn);
    for (int L = 0; L < NLAYERS; L++) {
        conv_kernel<<<dim3(Hdim / 2, Bsz), 256, 0, stream>>>(
            hn, Kd2 + (size_t)L * (Hdim / 2) * 4096, dvec + L * Hdim, tw);
        int do_ln = (L < NLAYERS - 1) ? 1 : 0;
        const float* nwn = norm_w + ((L + 1) % NLAYERS) * Hdim;
        const float* nbn = norm_b + ((L + 1) % NLAYERS) * Hdim;
        mlp_kernel<<<nrows / 16, 256, 0, stream>>>(hn, h, hn,
                                                   w1 + (size_t)L * Hdim * Hdim, b1 + L * Hdim,
                                                   w2 + (size_t)L * Hdim * Hdim, b2 + L * Hdim,
                                                   nwn, nbn, do_ln);
    }
    decoder_kernel<<<nrows / 32, 256, 0, stream>>>(h, dec_w, dec_b, out);
}

// Round 5
// 493.357 us; speedup vs baseline: 1.8072x; 1.0472x over previous
//
#include <hip/hip_runtime.h>
#include <hip/hip_bf16.h>

// S4 (DPLR) forward, B=8 L=2048 IN=OUT=64 H=128 N=64, 4 layers.
// R5: spectrum restructured — 4 l-values per thread (amortize pole loads 4x),
// float4-packed pole data (b128 LDS reads), explicit fmaf accumulation chains.

#define Bsz 8
#define Lseq 2048
#define Hdim 128
#define Npol 64
#define NLAYERS 4

__device__ __forceinline__ float fast_rcp(float x) { return __builtin_amdgcn_rcpf(x); }
__device__ __forceinline__ float fast_rsq(float x) { return __builtin_amdgcn_rsqf(x); }

__device__ __forceinline__ float2 cmulf(float2 a, float2 b) {
    return make_float2(a.x * b.x - a.y * b.y, a.x * b.y + a.y * b.x);
}
__device__ __forceinline__ float2 cmulc(float2 a, float2 b) {  // a * conj(b)
    return make_float2(a.x * b.x + a.y * b.y, a.y * b.x - a.x * b.y);
}

__device__ __forceinline__ float gelu_f(float v) {
    float z = 0.7978845608028654f * (v + 0.044715f * v * v * v);
    float e = __expf(2.0f * z);
    return v - v * fast_rcp(e + 1.0f);
}

// XOR swizzle: mixes digit1 into the bank digit so strides 1/16/256 are all conflict-uniform.
__device__ __forceinline__ int sw(int i) { return (i & ~15) | ((i ^ (i >> 4)) & 15); }

static __device__ const float W16R[8] = {1.f, 0.9238795325f, 0.7071067812f, 0.3826834324f,
                                         0.f, -0.3826834324f, -0.7071067812f, -0.9238795325f};
static __device__ const float W16I[8] = {0.f, -0.3826834324f, -0.7071067812f, -0.9238795325f,
                                         -1.f, -0.9238795325f, -0.7071067812f, -0.3826834324f};
static __device__ const int BR4[16] = {0, 8, 4, 12, 2, 10, 6, 14, 1, 9, 5, 13, 3, 11, 7, 15};
static __device__ const int BR3[8] = {0, 4, 2, 6, 1, 5, 3, 7};

__device__ __forceinline__ float2 twget(const float2* __restrict__ tw, int e) {
    float2 w = tw[e & 2047];
    if (e & 2048) { w.x = -w.x; w.y = -w.y; }
    return w;
}

template <bool INV>
__device__ __forceinline__ void fft16_dif(float2 v[16]) {
#pragma unroll
    for (int mi = 0; mi < 4; mi++) {
        const int m = 8 >> mi;
#pragma unroll
        for (int g = 0; g < 16; g += 2 * m) {
#pragma unroll
            for (int j = 0; j < m; j++) {
                float wr = W16R[j << mi];
                float wi = INV ? -W16I[j << mi] : W16I[j << mi];
                float2 a = v[g + j], b = v[g + j + m];
                float dx = a.x - b.x, dy = a.y - b.y;
                v[g + j] = make_float2(a.x + b.x, a.y + b.y);
                v[g + j + m] = make_float2(dx * wr - dy * wi, dx * wi + dy * wr);
            }
        }
    }
}

template <bool INV>
__device__ __forceinline__ void fft16_dit(float2 v[16]) {
#pragma unroll
    for (int mi = 3; mi >= 0; mi--) {
        const int m = 8 >> mi;
#pragma unroll
        for (int g = 0; g < 16; g += 2 * m) {
#pragma unroll
            for (int j = 0; j < m; j++) {
                float wr = W16R[j << mi];
                float wi = INV ? -W16I[j << mi] : W16I[j << mi];
                float2 a = v[g + j], b = v[g + j + m];
                float bx = b.x * wr - b.y * wi, by = b.x * wi + b.y * wr;
                v[g + j] = make_float2(a.x + bx, a.y + by);
                v[g + j + m] = make_float2(a.x - bx, a.y - by);
            }
        }
    }
}

template <bool INV>
__device__ __forceinline__ void fft8_dif(float2 v[8]) {
#pragma unroll
    for (int mi = 0; mi < 3; mi++) {
        const int m = 4 >> mi;
#pragma unroll
        for (int g = 0; g < 8; g += 2 * m) {
#pragma unroll
            for (int j = 0; j < m; j++) {
                float wr = W16R[j << (mi + 1)];
                float wi = INV ? -W16I[j << (mi + 1)] : W16I[j << (mi + 1)];
                float2 a = v[g + j], b = v[g + j + m];
                float dx = a.x - b.x, dy = a.y - b.y;
                v[g + j] = make_float2(a.x + b.x, a.y + b.y);
                v[g + j + m] = make_float2(dx * wr - dy * wi, dx * wi + dy * wr);
            }
        }
    }
}

// Forward 4096-pt FFT in LDS, 256 threads, result in 12-bit bit-reversed positions.
// No leading barrier IF caller's fill writes exactly {t+256k, k<16} per thread.
__device__ __forceinline__ void fft4096_fwd(float2* data, const float2* __restrict__ tw, int t) {
    {
        float2 v[16];
#pragma unroll
        for (int k = 0; k < 16; k++) v[k] = data[sw(t + 256 * k)];
        fft16_dif<false>(v);
#pragma unroll
        for (int i = 1; i < 16; i++) v[i] = cmulf(v[i], twget(tw, t * BR4[i]));
#pragma unroll
        for (int i = 0; i < 16; i++) data[sw(i * 256 + t)] = v[i];
    }
    __syncthreads();
    {
        int j0 = t & 15;
        int base = (t >> 4) * 256 + j0;
        float2 v[16];
#pragma unroll
        for (int k = 0; k < 16; k++) v[k] = data[sw(base + 16 * k)];
        fft16_dif<false>(v);
#pragma unroll
        for (int i = 1; i < 16; i++) v[i] = cmulf(v[i], twget(tw, 16 * j0 * BR4[i]));
#pragma unroll
        for (int i = 0; i < 16; i++) data[sw(base + 16 * i)] = v[i];
    }
    __syncthreads();
    {
        float2 v[16];
#pragma unroll
        for (int k = 0; k < 16; k++) v[k] = data[sw(t * 16 + k)];
        fft16_dif<false>(v);
#pragma unroll
        for (int i = 0; i < 16; i++) data[sw(t * 16 + i)] = v[i];
    }
    __syncthreads();
}

// ---------------- twiddle table ----------------
__global__ __launch_bounds__(256) void twiddle_init(float2* tw) {
    int k = blockIdx.x * blockDim.x + threadIdx.x;
    if (k < 2048) {
        double a = -6.283185307179586476925286766559 * (double)k / 4096.0;
        tw[k] = make_float2((float)cos(a), (float)sin(a));
    }
}

// ---------------- encoder + fused LN: 16 rows/block ----------------
__global__ __launch_bounds__(256) void encoder_kernel(const float* __restrict__ x,
                                                      const float* __restrict__ w,
                                                      const float* __restrict__ b,
                                                      const float* __restrict__ nw,
                                                      const float* __restrict__ nb,
                                                      float* __restrict__ h,
                                                      float* __restrict__ hn) {
    int r0 = blockIdx.x * 16;
    int t = threadIdx.x;
    __shared__ float ws[128 * 65];
    __shared__ __align__(16) float xst[64 * 20];
    __shared__ float dots[16 * 128];
    __shared__ float2 mv[16];
    for (int i = t; i < 128 * 64; i += 256) ws[(i >> 6) * 65 + (i & 63)] = w[i];
    for (int i = t; i < 16 * 64; i += 256) {
        int r = i >> 6, k = i & 63;
        xst[k * 20 + r] = x[(size_t)(r0 + r) * 64 + k];
    }
    __syncthreads();
    int o = t & 127, half = t >> 7;
    float acc[8];
    float bo = b[o];
#pragma unroll
    for (int j = 0; j < 8; j++) acc[j] = bo;
    for (int k = 0; k < 64; k++) {
        float wv = ws[o * 65 + k];
        float4 xa = *(const float4*)&xst[k * 20 + half * 8];
        float4 xb = *(const float4*)&xst[k * 20 + half * 8 + 4];
        acc[0] += wv * xa.x; acc[1] += wv * xa.y; acc[2] += wv * xa.z; acc[3] += wv * xa.w;
        acc[4] += wv * xb.x; acc[5] += wv * xb.y; acc[6] += wv * xb.z; acc[7] += wv * xb.w;
    }
#pragma unroll
    for (int j = 0; j < 8; j++) dots[(half * 8 + j) * 128 + o] = acc[j];
    __syncthreads();
    {
        int row = t >> 4, lane = t & 15;
        float s1 = 0.f, s2 = 0.f;
#pragma unroll
        for (int i = 0; i < 8; i++) {
            float v = dots[row * 128 + lane * 8 + i];
            s1 += v; s2 += v * v;
        }
#pragma unroll
        for (int m = 1; m < 16; m <<= 1) { s1 += __shfl_xor(s1, m); s2 += __shfl_xor(s2, m); }
        if (lane == 0) {
            float mu = s1 * (1.0f / 128.0f);
            float var = s2 * (1.0f / 128.0f) - mu * mu;
            mv[row] = make_float2(mu, fast_rsq(var + 1e-5f));
        }
    }
    __syncthreads();
    int c = t & 127;
    float nwc = nw[c], nbc = nb[c];
#pragma unroll
    for (int j = 0; j < 8; j++) {
        int r = (t >> 7) + 2 * j;
        float v = dots[r * 128 + c];
        size_t idx = (size_t)(r0 + r) * Hdim + c;
        h[idx] = v;
        float2 m = mv[r];
        hn[idx] = (v - m.x) * m.y * nwc + nbc;
    }
}

// ---------------- DPLR generating function: 4 l's per thread, fmaf chains ----------------
__global__ __launch_bounds__(256, 4) void spectrum_kernel(const float* __restrict__ lam_re,
                                                          const float* __restrict__ lam_im,
                                                          const float* __restrict__ p_re,
                                                          const float* __restrict__ p_im,
                                                          const float* __restrict__ b_re,
                                                          const float* __restrict__ b_im,
                                                          const float* __restrict__ c_re,
                                                          const float* __restrict__ c_im,
                                                          const float* __restrict__ log_step,
                                                          float2* __restrict__ at_roots) {
    int h = blockIdx.x, layer = blockIdx.y, t = threadIdx.x;
    __shared__ __align__(16) float4 polA[Npol];  // (lam.re, lam.im, n00.re, n00.im)
    __shared__ __align__(16) float4 polB[Npol];  // (n01.re, n01.im, n10.re, n10.im)
    __shared__ float n11S[Npol];
    int baseP = (layer * Hdim + h) * Npol;
    if (t < Npol) {
        int n = t;
        float lr = lam_re[baseP + n], li = lam_im[baseP + n];
        float pr = p_re[baseP + n], pi = p_im[baseP + n];
        float br = b_re[baseP + n], bi = b_im[baseP + n];
        float cr = c_re[baseP + n], ci = c_im[baseP + n];
        polA[n] = make_float4(lr, li, cr * br + ci * bi, cr * bi - ci * br);
        polB[n] = make_float4(cr * pr + ci * pi, cr * pi - ci * pr,
                              pr * br + pi * bi, pr * bi - pi * br);
        n11S[n] = pr * pr + pi * pi;
    }
    __syncthreads();
    float step = expf(log_step[layer * Hdim + h]);
    float gs = 2.0f / step;
    int l0 = 1024 * blockIdx.z;

    float gr[4], gi[4], cr2[4], ci2[4];
#pragma unroll
    for (int j = 0; j < 4; j++) {
        int l = l0 + t + 256 * j;
        float ang = -6.283185307179586f * (float)l / (float)Lseq;
        float wr = cosf(ang), wi = sinf(ang);  // fp32 omega on purpose: keeps |g|^2 in range
        float dr = 1.0f + wr, di = wi;
        float invd2 = fast_rcp(dr * dr + di * di);
        float nr = 1.0f - wr, ni = -wi;
        gr[j] = gs * (nr * dr + ni * di) * invd2;
        gi[j] = gs * (ni * dr - nr * di) * invd2;
        cr2[j] = 2.0f * dr * invd2;
        ci2[j] = -2.0f * di * invd2;
    }
    float k00x[4] = {0, 0, 0, 0}, k00y[4] = {0, 0, 0, 0};
    float k01x[4] = {0, 0, 0, 0}, k01y[4] = {0, 0, 0, 0};
    float k10x[4] = {0, 0, 0, 0}, k10y[4] = {0, 0, 0, 0};
    float k11x[4] = {0, 0, 0, 0}, k11y[4] = {0, 0, 0, 0};
#pragma unroll 2
    for (int n = 0; n < Npol; n++) {
        float4 A = polA[n];  // b128 broadcast
        float4 B = polB[n];
        float n11 = n11S[n];
#pragma unroll
        for (int j = 0; j < 4; j++) {
            float er = gr[j] - A.x, ei = gi[j] - A.y;
            float inv2 = fast_rcp(fmaf(er, er, ei * ei));
            float ir = er * inv2;
            float mi = ei * inv2;  // = -Im(1/(g-lam))
            k00x[j] = fmaf(A.z, ir, fmaf(A.w, mi, k00x[j]));
            k00y[j] = fmaf(A.w, ir, fmaf(-A.z, mi, k00y[j]));
            k01x[j] = fmaf(B.x, ir, fmaf(B.y, mi, k01x[j]));
            k01y[j] = fmaf(B.y, ir, fmaf(-B.x, mi, k01y[j]));
            k10x[j] = fmaf(B.z, ir, fmaf(B.w, mi, k10x[j]));
            k10y[j] = fmaf(B.w, ir, fmaf(-B.z, mi, k10y[j]));
            k11x[j] = fmaf(n11, ir, k11x[j]);
            k11y[j] = fmaf(-n11, mi, k11y[j]);
        }
    }
#pragma unroll
    for (int j = 0; j < 4; j++) {
        float wr2 = 1.0f + k11x[j], wi2 = k11y[j];
        float w2inv = fast_rcp(fmaf(wr2, wr2, wi2 * wi2));
        float vr = wr2 * w2inv, vi = -wi2 * w2inv;
        float t1x = k01x[j] * k10x[j] - k01y[j] * k10y[j];
        float t1y = k01x[j] * k10y[j] + k01y[j] * k10x[j];
        float t2x = t1x * vr - t1y * vi, t2y = t1x * vi + t1y * vr;
        float ex = k00x[j] - t2x, ey = k00y[j] - t2y;
        int l = l0 + t + 256 * j;
        at_roots[((size_t)layer * Hdim + h) * Lseq + l] =
            make_float2(cr2[j] * ex - ci2[j] * ey, cr2[j] * ey + ci2[j] * ex);
    }
}

// ---------------- kernel FFT: ifft2048 -> pad -> fft4096, all layers ----------------
// Kd2 layout: [layer][hp][p] float4 = (K_{2hp}[p].re,.im, K_{2hp+1}[p].re,.im), p bit-rev.
__global__ __launch_bounds__(256) void kfft_kernel(const float2* __restrict__ at_roots,
                                                   float4* __restrict__ Kd2,
                                                   const float2* __restrict__ tw) {
    int h = blockIdx.x, layer = blockIdx.y, t = threadIdx.x;
    __shared__ float2 data[4096];
    __shared__ float ktmp[2048];
    const float2* src = at_roots + ((size_t)layer * Hdim + h) * Lseq;
#pragma unroll
    for (int k = 0; k < 8; k++) {
        int l = t + 256 * k;
        data[sw(l)] = src[l];
    }
    __syncthreads();
    // inverse 2048-pt (conjugated DIF), digits 16 x 16 x 8
    if (t < 128) {
        float2 v[16];
#pragma unroll
        for (int k = 0; k < 16; k++) v[k] = data[sw(t + 128 * k)];
        fft16_dif<true>(v);
#pragma unroll
        for (int i = 1; i < 16; i++) v[i] = cmulc(v[i], twget(tw, 2 * t * BR4[i]));
#pragma unroll
        for (int i = 0; i < 16; i++) data[sw(i * 128 + t)] = v[i];
    }
    __syncthreads();
    if (t < 128) {
        int i2 = t >> 3, j0 = t & 7;
        int base2 = i2 * 128 + j0;
        float2 v[16];
#pragma unroll
        for (int k = 0; k < 16; k++) v[k] = data[sw(base2 + 8 * k)];
        fft16_dif<true>(v);
#pragma unroll
        for (int i = 1; i < 16; i++) v[i] = cmulc(v[i], twget(tw, 32 * j0 * BR4[i]));
#pragma unroll
        for (int i = 0; i < 16; i++) data[sw(base2 + 8 * i)] = v[i];
    }
    __syncthreads();
    {
        float2 v8[8];
#pragma unroll
        for (int k = 0; k < 8; k++) v8[k] = data[sw(t * 8 + k)];
        fft8_dif<true>(v8);
        int r = BR4[t >> 4], s = BR4[t & 15];
#pragma unroll
        for (int i = 0; i < 8; i++) {
            int l = r + 16 * s + 256 * BR3[i];
            ktmp[l] = v8[i].x * (1.0f / 2048.0f);
        }
    }
    __syncthreads();
#pragma unroll
    for (int k = 0; k < 8; k++) {
        int l = t + 256 * k;
        data[sw(l)] = make_float2(ktmp[l], 0.f);
        data[sw(l + 2048)] = make_float2(0.f, 0.f);
    }
    fft4096_fwd(data, tw, t);
    float2* dst = (float2*)(Kd2 + ((size_t)layer * 64 + (h >> 1)) * 4096);
    int half = h & 1;
#pragma unroll
    for (int k = 0; k < 16; k++) {
        int p = t + 256 * k;
        dst[2 * p + half] = data[sw(p)];
    }
}

// ---------------- FFT convolution + D-skip + gelu, channel pair per block ----------------
__global__ __launch_bounds__(256) void conv_kernel(float* __restrict__ hn,
                                                   const float4* __restrict__ Kd2,
                                                   const float* __restrict__ dvec,
                                                   const float2* __restrict__ tw) {
    int hp = blockIdx.x, b = blockIdx.y, h0 = hp * 2, t = threadIdx.x;
    __shared__ float2 data[4096];
    float* base = hn + (size_t)b * Lseq * Hdim + h0;
    float2 ureg[8];
#pragma unroll
    for (int k = 0; k < 8; k++) {
        int l = t + 256 * k;
        float2 u2 = *(const float2*)(base + (size_t)l * Hdim);
        ureg[k] = u2;
        data[sw(l)] = u2;
        data[sw(l + 2048)] = make_float2(0.f, 0.f);
    }
    fft4096_fwd(data, tw, t);
    const float4* Kp = Kd2 + (size_t)hp * 4096;
    const float scale = 1.0f / 4096.0f;
    for (int f = t; f <= 2048; f += 256) {
        int fm = (4096 - f) & 4095;
        int p = __brev((unsigned)f) >> 20;
        int pm = __brev((unsigned)fm) >> 20;
        float2 Zf = data[sw(p)], Zm = data[sw(pm)];
        float2 U0 = make_float2(0.5f * (Zf.x + Zm.x), 0.5f * (Zf.y - Zm.y));
        float2 Dm = make_float2(Zf.x - Zm.x, Zf.y + Zm.y);
        float2 U1 = make_float2(0.5f * Dm.y, -0.5f * Dm.x);
        float4 Ka = Kp[p];
        float2 S0 = cmulf(U0, make_float2(Ka.x, Ka.y));
        float2 S1 = cmulf(U1, make_float2(Ka.z, Ka.w));
        float2 Wf = make_float2((S0.x - S1.y) * scale, (S0.y + S1.x) * scale);
        float4 Kb = Kp[pm];
        float2 U0m = make_float2(U0.x, -U0.y);
        float2 U1m = make_float2(U1.x, -U1.y);
        float2 S0m = cmulf(U0m, make_float2(Kb.x, Kb.y));
        float2 S1m = cmulf(U1m, make_float2(Kb.z, Kb.w));
        float2 Wm = make_float2((S0m.x - S1m.y) * scale, (S0m.y + S1m.x) * scale);
        data[sw(p)] = Wf;
        if (pm != p) data[sw(pm)] = Wm;
    }
    __syncthreads();
    {
        float2 v[16];
#pragma unroll
        for (int i = 0; i < 16; i++) v[i] = data[sw(t * 16 + i)];
        fft16_dit<true>(v);
#pragma unroll
        for (int i = 0; i < 16; i++) data[sw(t * 16 + i)] = v[i];
    }
    __syncthreads();
    {
        int j0 = t & 15;
        int base2 = (t >> 4) * 256 + j0;
        float2 v[16];
        v[0] = data[sw(base2)];
#pragma unroll
        for (int i = 1; i < 16; i++)
            v[i] = cmulc(data[sw(base2 + 16 * i)], twget(tw, 16 * j0 * BR4[i]));
        fft16_dit<true>(v);
#pragma unroll
        for (int i = 0; i < 16; i++) data[sw(base2 + 16 * i)] = v[i];
    }
    __syncthreads();
    {
        float2 v[16];
        v[0] = data[sw(t)];
#pragma unroll
        for (int i = 1; i < 16; i++)
            v[i] = cmulc(data[sw(i * 256 + t)], twget(tw, t * BR4[i]));
        fft16_dit<true>(v);
        float d0 = dvec[h0], d1 = dvec[h0 + 1];
#pragma unroll
        for (int k = 0; k < 8; k++) {
            float y0 = gelu_f(v[k].x + ureg[k].x * d0);
            float y1 = gelu_f(v[k].y + ureg[k].y * d1);
            *(float2*)(base + (size_t)(t + 256 * k) * Hdim) = make_float2(y0, y1);
        }
    }
}

// ---------------- gated MLP + residual + fused next-layer LN: 16 rows/block ----------------
__global__ __launch_bounds__(256) void mlp_kernel(const float* __restrict__ y,
                                                  float* __restrict__ h,
                                                  float* __restrict__ hn,
                                                  const float* __restrict__ w1,
                                                  const float* __restrict__ b1,
                                                  const float* __restrict__ w2,
                                                  const float* __restrict__ b2,
                                                  const float* __restrict__ nw,
                                                  const float* __restrict__ nb,
                                                  int do_ln) {
    int r0 = blockIdx.x * 16;
    int t = threadIdx.x;
    __shared__ float ws[2 * 128 * 17];
    __shared__ __align__(16) float yst[128 * 20];
    __shared__ float dots[16 * 256];
    __shared__ float2 mv[16];
    for (int i = t; i < 16 * 128; i += 256) {
        int r = i >> 7, k = i & 127;
        yst[k * 20 + r] = y[(size_t)(r0 + r) * Hdim + k];
    }
    int oo = t & 127, sel = t >> 7;
    float acc[16];
    float bias = sel ? b2[oo] : b1[oo];
#pragma unroll
    for (int r = 0; r < 16; r++) acc[r] = bias;
    for (int kc0 = 0; kc0 < 128; kc0 += 16) {
        __syncthreads();
        for (int i = t; i < 4096; i += 256) {
            int s = i >> 11, rem = i & 2047, o = rem >> 4, k = rem & 15;
            ws[s * 2176 + o * 17 + k] = (s ? w2 : w1)[(size_t)o * Hdim + kc0 + k];
        }
        __syncthreads();
#pragma unroll
        for (int k = 0; k < 16; k++) {
            float wv = ws[sel * 2176 + oo * 17 + k];
            int kk = (kc0 + k) * 20;
            float4 ya = *(const float4*)&yst[kk];
            float4 yb = *(const float4*)&yst[kk + 4];
            float4 yc = *(const float4*)&yst[kk + 8];
            float4 yd = *(const float4*)&yst[kk + 12];
            acc[0] += wv * ya.x;  acc[1] += wv * ya.y;  acc[2] += wv * ya.z;  acc[3] += wv * ya.w;
            acc[4] += wv * yb.x;  acc[5] += wv * yb.y;  acc[6] += wv * yb.z;  acc[7] += wv * yb.w;
            acc[8] += wv * yc.x;  acc[9] += wv * yc.y;  acc[10] += wv * yc.z; acc[11] += wv * yc.w;
            acc[12] += wv * yd.x; acc[13] += wv * yd.y; acc[14] += wv * yd.z; acc[15] += wv * yd.w;
        }
    }
#pragma unroll
    for (int r = 0; r < 16; r++) dots[r * 256 + t] = acc[r];
    __syncthreads();
    int c = t & 127;
#pragma unroll
    for (int j = 0; j < 8; j++) {
        int r = (t >> 7) + 2 * j;
        float v1 = dots[r * 256 + c], v2 = dots[r * 256 + c + 128];
        float hN = h[(size_t)(r0 + r) * Hdim + c] + v1 * fast_rcp(1.0f + __expf(-v2));
        dots[r * 256 + c] = hN;
    }
    __syncthreads();
    if (do_ln) {
        int row = t >> 4, lane = t & 15;
        float s1 = 0.f, s2 = 0.f;
#pragma unroll
        for (int i = 0; i < 8; i++) {
            float v = dots[row * 256 + lane * 8 + i];
            s1 += v; s2 += v * v;
        }
#pragma unroll
        for (int m = 1; m < 16; m <<= 1) { s1 += __shfl_xor(s1, m); s2 += __shfl_xor(s2, m); }
        if (lane == 0) {
            float mu = s1 * (1.0f / 128.0f);
            float var = s2 * (1.0f / 128.0f) - mu * mu;
            mv[row] = make_float2(mu, fast_rsq(var + 1e-5f));
        }
        __syncthreads();
        float nwc = nw[c], nbc = nb[c];
#pragma unroll
        for (int j = 0; j < 8; j++) {
            int r = (t >> 7) + 2 * j;
            float v = dots[r * 256 + c];
            size_t idx = (size_t)(r0 + r) * Hdim + c;
            h[idx] = v;
            float2 m = mv[r];
            hn[idx] = (v - m.x) * m.y * nwc + nbc;
        }
    } else {
#pragma unroll
        for (int j = 0; j < 8; j++) {
            int r = (t >> 7) + 2 * j;
            h[(size_t)(r0 + r) * Hdim + c] = dots[r * 256 + c];
        }
    }
}

// ---------------- decoder: 32 rows/block ----------------
__global__ __launch_bounds__(256) void decoder_kernel(const float* __restrict__ h,
                                                      const float* __restrict__ w,
                                                      const float* __restrict__ b,
                                                      float* __restrict__ out) {
    int r0 = blockIdx.x * 32;
    int t = threadIdx.x;
    __shared__ float ws[64 * 129];
    __shared__ __align__(16) float hst[128 * 36];
    for (int i = t; i < 64 * 128; i += 256) ws[(i >> 7) * 129 + (i & 127)] = w[i];
    for (int i = t; i < 32 * 128; i += 256) {
        int r = i >> 7, k = i & 127;
        hst[k * 36 + r] = h[(size_t)(r0 + r) * Hdim + k];
    }
    __syncthreads();
    int o = t & 63, q = t >> 6;
    float acc[8];
    float bo = b[o];
#pragma unroll
    for (int j = 0; j < 8; j++) acc[j] = bo;
    for (int k = 0; k < 128; k++) {
        float wv = ws[o * 129 + k];
        float4 ha = *(const float4*)&hst[k * 36 + q * 8];
        float4 hb = *(const float4*)&hst[k * 36 + q * 8 + 4];
        acc[0] += wv * ha.x; acc[1] += wv * ha.y; acc[2] += wv * ha.z; acc[3] += wv * ha.w;
        acc[4] += wv * hb.x; acc[5] += wv * hb.y; acc[6] += wv * hb.z; acc[7] += wv * hb.w;
    }
#pragma unroll
    for (int j = 0; j < 8; j++) out[(size_t)(r0 + q * 8 + j) * 64 + o] = acc[j];
}

extern "C" void kernel_launch(void* const* d_in, const int* in_sizes, int n_in,
                              void* d_out, int out_size, void* d_ws, size_t ws_size,
                              hipStream_t stream) {
    const float* x      = (const float*)d_in[0];
    const float* enc_w  = (const float*)d_in[2];
    const float* enc_b  = (const float*)d_in[3];
    const float* dec_w  = (const float*)d_in[4];
    const float* dec_b  = (const float*)d_in[5];
    const float* lam_re = (const float*)d_in[6];
    const float* lam_im = (const float*)d_in[7];
    const float* p_re   = (const float*)d_in[8];
    const float* p_im   = (const float*)d_in[9];
    const float* b_re   = (const float*)d_in[10];
    const float* b_im   = (const float*)d_in[11];
    const float* c_re   = (const float*)d_in[12];
    const float* c_im   = (const float*)d_in[13];
    const float* dvec   = (const float*)d_in[14];
    const float* lstep  = (const float*)d_in[15];
    const float* norm_w = (const float*)d_in[16];
    const float* norm_b = (const float*)d_in[17];
    const float* w1     = (const float*)d_in[18];
    const float* b1     = (const float*)d_in[19];
    const float* w2     = (const float*)d_in[20];
    const float* b2     = (const float*)d_in[21];
    float* out = (float*)d_out;

    char* ws = (char*)d_ws;
    float2* tw  = (float2*)ws;  ws += 2048 * sizeof(float2);
    float*  h   = (float*)ws;   ws += (size_t)Bsz * Lseq * Hdim * sizeof(float);
    float*  hn  = (float*)ws;   ws += (size_t)Bsz * Lseq * Hdim * sizeof(float);
    float2* atr = (float2*)ws;  ws += (size_t)NLAYERS * Hdim * Lseq * sizeof(float2);
    float4* Kd2 = (float4*)ws;  ws += (size_t)NLAYERS * (Hdim / 2) * 4096 * sizeof(float4);

    const int nrows = Bsz * Lseq;  // 16384

    twiddle_init<<<8, 256, 0, stream>>>(tw);
    spectrum_kernel<<<dim3(Hdim, NLAYERS, 2), 256, 0, stream>>>(
        lam_re, lam_im, p_re, p_im, b_re, b_im, c_re, c_im, lstep, atr);
    kfft_kernel<<<dim3(Hdim, NLAYERS), 256, 0, stream>>>(atr, Kd2, tw);
    encoder_kernel<<<nrows / 16, 256, 0, stream>>>(x, enc_w, enc_b, norm_w, norm_b, h, hn);
    for (int L = 0; L < NLAYERS; L++) {
        conv_kernel<<<dim3(Hdim / 2, Bsz), 256, 0, stream>>>(
            hn, Kd2 + (size_t)L * (Hdim / 2) * 4096, dvec + L * Hdim, tw);
        int do_ln = (L < NLAYERS - 1) ? 1 : 0;
        const float* nwn = norm_w + ((L + 1) % NLAYERS) * Hdim;
        const float* nbn = norm_b + ((L + 1) % NLAYERS) * Hdim;
        mlp_kernel<<<nrows / 16, 256, 0, stream>>>(hn, h, hn,
                                                   w1 + (size_t)L * Hdim * Hdim, b1 + L * Hdim,
                                                   w2 + (size_t)L * Hdim * Hdim, b2 + L * Hdim,
                                                   nwn, nbn, do_ln);
    }
    decoder_kernel<<<nrows / 32, 256, 0, stream>>>(h, dec_w, dec_b, out);
}

// Round 6
// 421.336 us; speedup vs baseline: 2.1161x; 1.1709x over previous
//
#include <hip/hip_runtime.h>
#include <hip/hip_bf16.h>

// S4 (DPLR) forward, B=8 L=2048 IN=OUT=64 H=128 N=64, 4 layers.
// R6: mlp restructured — 32 rows/block, thread owns col o for BOTH w1,w2
// (32 FMA per 6 LDS, gate in-thread), register-prefetched w chunks, LDS alias.

#define Bsz 8
#define Lseq 2048
#define Hdim 128
#define Npol 64
#define NLAYERS 4

__device__ __forceinline__ float fast_rcp(float x) { return __builtin_amdgcn_rcpf(x); }
__device__ __forceinline__ float fast_rsq(float x) { return __builtin_amdgcn_rsqf(x); }

__device__ __forceinline__ float2 cmulf(float2 a, float2 b) {
    return make_float2(a.x * b.x - a.y * b.y, a.x * b.y + a.y * b.x);
}
__device__ __forceinline__ float2 cmulc(float2 a, float2 b) {  // a * conj(b)
    return make_float2(a.x * b.x + a.y * b.y, a.y * b.x - a.x * b.y);
}

__device__ __forceinline__ float gelu_f(float v) {
    float z = 0.7978845608028654f * (v + 0.044715f * v * v * v);
    float e = __expf(2.0f * z);
    return v - v * fast_rcp(e + 1.0f);
}

// XOR swizzle: mixes digit1 into the bank digit so strides 1/16/256 are all conflict-uniform.
__device__ __forceinline__ int sw(int i) { return (i & ~15) | ((i ^ (i >> 4)) & 15); }

static __device__ const float W16R[8] = {1.f, 0.9238795325f, 0.7071067812f, 0.3826834324f,
                                         0.f, -0.3826834324f, -0.7071067812f, -0.9238795325f};
static __device__ const float W16I[8] = {0.f, -0.3826834324f, -0.7071067812f, -0.9238795325f,
                                         -1.f, -0.9238795325f, -0.7071067812f, -0.3826834324f};
static __device__ const int BR4[16] = {0, 8, 4, 12, 2, 10, 6, 14, 1, 9, 5, 13, 3, 11, 7, 15};
static __device__ const int BR3[8] = {0, 4, 2, 6, 1, 5, 3, 7};

__device__ __forceinline__ float2 twget(const float2* __restrict__ tw, int e) {
    float2 w = tw[e & 2047];
    if (e & 2048) { w.x = -w.x; w.y = -w.y; }
    return w;
}

template <bool INV>
__device__ __forceinline__ void fft16_dif(float2 v[16]) {
#pragma unroll
    for (int mi = 0; mi < 4; mi++) {
        const int m = 8 >> mi;
#pragma unroll
        for (int g = 0; g < 16; g += 2 * m) {
#pragma unroll
            for (int j = 0; j < m; j++) {
                float wr = W16R[j << mi];
                float wi = INV ? -W16I[j << mi] : W16I[j << mi];
                float2 a = v[g + j], b = v[g + j + m];
                float dx = a.x - b.x, dy = a.y - b.y;
                v[g + j] = make_float2(a.x + b.x, a.y + b.y);
                v[g + j + m] = make_float2(dx * wr - dy * wi, dx * wi + dy * wr);
            }
        }
    }
}

template <bool INV>
__device__ __forceinline__ void fft16_dit(float2 v[16]) {
#pragma unroll
    for (int mi = 3; mi >= 0; mi--) {
        const int m = 8 >> mi;
#pragma unroll
        for (int g = 0; g < 16; g += 2 * m) {
#pragma unroll
            for (int j = 0; j < m; j++) {
                float wr = W16R[j << mi];
                float wi = INV ? -W16I[j << mi] : W16I[j << mi];
                float2 a = v[g + j], b = v[g + j + m];
                float bx = b.x * wr - b.y * wi, by = b.x * wi + b.y * wr;
                v[g + j] = make_float2(a.x + bx, a.y + by);
                v[g + j + m] = make_float2(a.x - bx, a.y - by);
            }
        }
    }
}

template <bool INV>
__device__ __forceinline__ void fft8_dif(float2 v[8]) {
#pragma unroll
    for (int mi = 0; mi < 3; mi++) {
        const int m = 4 >> mi;
#pragma unroll
        for (int g = 0; g < 8; g += 2 * m) {
#pragma unroll
            for (int j = 0; j < m; j++) {
                float wr = W16R[j << (mi + 1)];
                float wi = INV ? -W16I[j << (mi + 1)] : W16I[j << (mi + 1)];
                float2 a = v[g + j], b = v[g + j + m];
                float dx = a.x - b.x, dy = a.y - b.y;
                v[g + j] = make_float2(a.x + b.x, a.y + b.y);
                v[g + j + m] = make_float2(dx * wr - dy * wi, dx * wi + dy * wr);
            }
        }
    }
}

// Forward 4096-pt FFT in LDS, 256 threads, result in 12-bit bit-reversed positions.
// No leading barrier IF caller's fill writes exactly {t+256k, k<16} per thread.
__device__ __forceinline__ void fft4096_fwd(float2* data, const float2* __restrict__ tw, int t) {
    {
        float2 v[16];
#pragma unroll
        for (int k = 0; k < 16; k++) v[k] = data[sw(t + 256 * k)];
        fft16_dif<false>(v);
#pragma unroll
        for (int i = 1; i < 16; i++) v[i] = cmulf(v[i], twget(tw, t * BR4[i]));
#pragma unroll
        for (int i = 0; i < 16; i++) data[sw(i * 256 + t)] = v[i];
    }
    __syncthreads();
    {
        int j0 = t & 15;
        int base = (t >> 4) * 256 + j0;
        float2 v[16];
#pragma unroll
        for (int k = 0; k < 16; k++) v[k] = data[sw(base + 16 * k)];
        fft16_dif<false>(v);
#pragma unroll
        for (int i = 1; i < 16; i++) v[i] = cmulf(v[i], twget(tw, 16 * j0 * BR4[i]));
#pragma unroll
        for (int i = 0; i < 16; i++) data[sw(base + 16 * i)] = v[i];
    }
    __syncthreads();
    {
        float2 v[16];
#pragma unroll
        for (int k = 0; k < 16; k++) v[k] = data[sw(t * 16 + k)];
        fft16_dif<false>(v);
#pragma unroll
        for (int i = 0; i < 16; i++) data[sw(t * 16 + i)] = v[i];
    }
    __syncthreads();
}

// ---------------- twiddle table ----------------
__global__ __launch_bounds__(256) void twiddle_init(float2* tw) {
    int k = blockIdx.x * blockDim.x + threadIdx.x;
    if (k < 2048) {
        double a = -6.283185307179586476925286766559 * (double)k / 4096.0;
        tw[k] = make_float2((float)cos(a), (float)sin(a));
    }
}

// ---------------- encoder + fused LN: 16 rows/block ----------------
__global__ __launch_bounds__(256) void encoder_kernel(const float* __restrict__ x,
                                                      const float* __restrict__ w,
                                                      const float* __restrict__ b,
                                                      const float* __restrict__ nw,
                                                      const float* __restrict__ nb,
                                                      float* __restrict__ h,
                                                      float* __restrict__ hn) {
    int r0 = blockIdx.x * 16;
    int t = threadIdx.x;
    __shared__ float ws[128 * 65];
    __shared__ __align__(16) float xst[64 * 20];
    __shared__ float dots[16 * 128];
    __shared__ float2 mv[16];
    for (int i = t; i < 128 * 64; i += 256) ws[(i >> 6) * 65 + (i & 63)] = w[i];
    for (int i = t; i < 16 * 64; i += 256) {
        int r = i >> 6, k = i & 63;
        xst[k * 20 + r] = x[(size_t)(r0 + r) * 64 + k];
    }
    __syncthreads();
    int o = t & 127, half = t >> 7;
    float acc[8];
    float bo = b[o];
#pragma unroll
    for (int j = 0; j < 8; j++) acc[j] = bo;
    for (int k = 0; k < 64; k++) {
        float wv = ws[o * 65 + k];
        float4 xa = *(const float4*)&xst[k * 20 + half * 8];
        float4 xb = *(const float4*)&xst[k * 20 + half * 8 + 4];
        acc[0] += wv * xa.x; acc[1] += wv * xa.y; acc[2] += wv * xa.z; acc[3] += wv * xa.w;
        acc[4] += wv * xb.x; acc[5] += wv * xb.y; acc[6] += wv * xb.z; acc[7] += wv * xb.w;
    }
#pragma unroll
    for (int j = 0; j < 8; j++) dots[(half * 8 + j) * 128 + o] = acc[j];
    __syncthreads();
    {
        int row = t >> 4, lane = t & 15;
        float s1 = 0.f, s2 = 0.f;
#pragma unroll
        for (int i = 0; i < 8; i++) {
            float v = dots[row * 128 + lane * 8 + i];
            s1 += v; s2 += v * v;
        }
#pragma unroll
        for (int m = 1; m < 16; m <<= 1) { s1 += __shfl_xor(s1, m); s2 += __shfl_xor(s2, m); }
        if (lane == 0) {
            float mu = s1 * (1.0f / 128.0f);
            float var = s2 * (1.0f / 128.0f) - mu * mu;
            mv[row] = make_float2(mu, fast_rsq(var + 1e-5f));
        }
    }
    __syncthreads();
    int c = t & 127;
    float nwc = nw[c], nbc = nb[c];
#pragma unroll
    for (int j = 0; j < 8; j++) {
        int r = (t >> 7) + 2 * j;
        float v = dots[r * 128 + c];
        size_t idx = (size_t)(r0 + r) * Hdim + c;
        h[idx] = v;
        float2 m = mv[r];
        hn[idx] = (v - m.x) * m.y * nwc + nbc;
    }
}

// ---------------- DPLR generating function: 4 l's per thread, fmaf chains ----------------
__global__ __launch_bounds__(256, 4) void spectrum_kernel(const float* __restrict__ lam_re,
                                                          const float* __restrict__ lam_im,
                                                          const float* __restrict__ p_re,
                                                          const float* __restrict__ p_im,
                                                          const float* __restrict__ b_re,
                                                          const float* __restrict__ b_im,
                                                          const float* __restrict__ c_re,
                                                          const float* __restrict__ c_im,
                                                          const float* __restrict__ log_step,
                                                          float2* __restrict__ at_roots) {
    int h = blockIdx.x, layer = blockIdx.y, t = threadIdx.x;
    __shared__ __align__(16) float4 polA[Npol];  // (lam.re, lam.im, n00.re, n00.im)
    __shared__ __align__(16) float4 polB[Npol];  // (n01.re, n01.im, n10.re, n10.im)
    __shared__ float n11S[Npol];
    int baseP = (layer * Hdim + h) * Npol;
    if (t < Npol) {
        int n = t;
        float lr = lam_re[baseP + n], li = lam_im[baseP + n];
        float pr = p_re[baseP + n], pi = p_im[baseP + n];
        float br = b_re[baseP + n], bi = b_im[baseP + n];
        float cr = c_re[baseP + n], ci = c_im[baseP + n];
        polA[n] = make_float4(lr, li, cr * br + ci * bi, cr * bi - ci * br);
        polB[n] = make_float4(cr * pr + ci * pi, cr * pi - ci * pr,
                              pr * br + pi * bi, pr * bi - pi * br);
        n11S[n] = pr * pr + pi * pi;
    }
    __syncthreads();
    float step = expf(log_step[layer * Hdim + h]);
    float gs = 2.0f / step;
    int l0 = 1024 * blockIdx.z;

    float gr[4], gi[4], cr2[4], ci2[4];
#pragma unroll
    for (int j = 0; j < 4; j++) {
        int l = l0 + t + 256 * j;
        float ang = -6.283185307179586f * (float)l / (float)Lseq;
        float wr = cosf(ang), wi = sinf(ang);  // fp32 omega on purpose: keeps |g|^2 in range
        float dr = 1.0f + wr, di = wi;
        float invd2 = fast_rcp(dr * dr + di * di);
        float nr = 1.0f - wr, ni = -wi;
        gr[j] = gs * (nr * dr + ni * di) * invd2;
        gi[j] = gs * (ni * dr - nr * di) * invd2;
        cr2[j] = 2.0f * dr * invd2;
        ci2[j] = -2.0f * di * invd2;
    }
    float k00x[4] = {0, 0, 0, 0}, k00y[4] = {0, 0, 0, 0};
    float k01x[4] = {0, 0, 0, 0}, k01y[4] = {0, 0, 0, 0};
    float k10x[4] = {0, 0, 0, 0}, k10y[4] = {0, 0, 0, 0};
    float k11x[4] = {0, 0, 0, 0}, k11y[4] = {0, 0, 0, 0};
#pragma unroll 2
    for (int n = 0; n < Npol; n++) {
        float4 A = polA[n];  // b128 broadcast
        float4 B = polB[n];
        float n11 = n11S[n];
#pragma unroll
        for (int j = 0; j < 4; j++) {
            float er = gr[j] - A.x, ei = gi[j] - A.y;
            float inv2 = fast_rcp(fmaf(er, er, ei * ei));
            float ir = er * inv2;
            float mi = ei * inv2;  // = -Im(1/(g-lam))
            k00x[j] = fmaf(A.z, ir, fmaf(A.w, mi, k00x[j]));
            k00y[j] = fmaf(A.w, ir, fmaf(-A.z, mi, k00y[j]));
            k01x[j] = fmaf(B.x, ir, fmaf(B.y, mi, k01x[j]));
            k01y[j] = fmaf(B.y, ir, fmaf(-B.x, mi, k01y[j]));
            k10x[j] = fmaf(B.z, ir, fmaf(B.w, mi, k10x[j]));
            k10y[j] = fmaf(B.w, ir, fmaf(-B.z, mi, k10y[j]));
            k11x[j] = fmaf(n11, ir, k11x[j]);
            k11y[j] = fmaf(-n11, mi, k11y[j]);
        }
    }
#pragma unroll
    for (int j = 0; j < 4; j++) {
        float wr2 = 1.0f + k11x[j], wi2 = k11y[j];
        float w2inv = fast_rcp(fmaf(wr2, wr2, wi2 * wi2));
        float vr = wr2 * w2inv, vi = -wi2 * w2inv;
        float t1x = k01x[j] * k10x[j] - k01y[j] * k10y[j];
        float t1y = k01x[j] * k10y[j] + k01y[j] * k10x[j];
        float t2x = t1x * vr - t1y * vi, t2y = t1x * vi + t1y * vr;
        float ex = k00x[j] - t2x, ey = k00y[j] - t2y;
        int l = l0 + t + 256 * j;
        at_roots[((size_t)layer * Hdim + h) * Lseq + l] =
            make_float2(cr2[j] * ex - ci2[j] * ey, cr2[j] * ey + ci2[j] * ex);
    }
}

// ---------------- kernel FFT: ifft2048 -> pad -> fft4096, all layers ----------------
// Kd2 layout: [layer][hp][p] float4 = (K_{2hp}[p].re,.im, K_{2hp+1}[p].re,.im), p bit-rev.
__global__ __launch_bounds__(256) void kfft_kernel(const float2* __restrict__ at_roots,
                                                   float4* __restrict__ Kd2,
                                                   const float2* __restrict__ tw) {
    int h = blockIdx.x, layer = blockIdx.y, t = threadIdx.x;
    __shared__ float2 data[4096];
    __shared__ float ktmp[2048];
    const float2* src = at_roots + ((size_t)layer * Hdim + h) * Lseq;
#pragma unroll
    for (int k = 0; k < 8; k++) {
        int l = t + 256 * k;
        data[sw(l)] = src[l];
    }
    __syncthreads();
    // inverse 2048-pt (conjugated DIF), digits 16 x 16 x 8
    if (t < 128) {
        float2 v[16];
#pragma unroll
        for (int k = 0; k < 16; k++) v[k] = data[sw(t + 128 * k)];
        fft16_dif<true>(v);
#pragma unroll
        for (int i = 1; i < 16; i++) v[i] = cmulc(v[i], twget(tw, 2 * t * BR4[i]));
#pragma unroll
        for (int i = 0; i < 16; i++) data[sw(i * 128 + t)] = v[i];
    }
    __syncthreads();
    if (t < 128) {
        int i2 = t >> 3, j0 = t & 7;
        int base2 = i2 * 128 + j0;
        float2 v[16];
#pragma unroll
        for (int k = 0; k < 16; k++) v[k] = data[sw(base2 + 8 * k)];
        fft16_dif<true>(v);
#pragma unroll
        for (int i = 1; i < 16; i++) v[i] = cmulc(v[i], twget(tw, 32 * j0 * BR4[i]));
#pragma unroll
        for (int i = 0; i < 16; i++) data[sw(base2 + 8 * i)] = v[i];
    }
    __syncthreads();
    {
        float2 v8[8];
#pragma unroll
        for (int k = 0; k < 8; k++) v8[k] = data[sw(t * 8 + k)];
        fft8_dif<true>(v8);
        int r = BR4[t >> 4], s = BR4[t & 15];
#pragma unroll
        for (int i = 0; i < 8; i++) {
            int l = r + 16 * s + 256 * BR3[i];
            ktmp[l] = v8[i].x * (1.0f / 2048.0f);
        }
    }
    __syncthreads();
#pragma unroll
    for (int k = 0; k < 8; k++) {
        int l = t + 256 * k;
        data[sw(l)] = make_float2(ktmp[l], 0.f);
        data[sw(l + 2048)] = make_float2(0.f, 0.f);
    }
    fft4096_fwd(data, tw, t);
    float2* dst = (float2*)(Kd2 + ((size_t)layer * 64 + (h >> 1)) * 4096);
    int half = h & 1;
#pragma unroll
    for (int k = 0; k < 16; k++) {
        int p = t + 256 * k;
        dst[2 * p + half] = data[sw(p)];
    }
}

// ---------------- FFT convolution + D-skip + gelu, channel pair per block ----------------
__global__ __launch_bounds__(256) void conv_kernel(float* __restrict__ hn,
                                                   const float4* __restrict__ Kd2,
                                                   const float* __restrict__ dvec,
                                                   const float2* __restrict__ tw) {
    int hp = blockIdx.x, b = blockIdx.y, h0 = hp * 2, t = threadIdx.x;
    __shared__ float2 data[4096];
    float* base = hn + (size_t)b * Lseq * Hdim + h0;
    float2 ureg[8];
#pragma unroll
    for (int k = 0; k < 8; k++) {
        int l = t + 256 * k;
        float2 u2 = *(const float2*)(base + (size_t)l * Hdim);
        ureg[k] = u2;
        data[sw(l)] = u2;
        data[sw(l + 2048)] = make_float2(0.f, 0.f);
    }
    fft4096_fwd(data, tw, t);
    const float4* Kp = Kd2 + (size_t)hp * 4096;
    const float scale = 1.0f / 4096.0f;
    for (int f = t; f <= 2048; f += 256) {
        int fm = (4096 - f) & 4095;
        int p = __brev((unsigned)f) >> 20;
        int pm = __brev((unsigned)fm) >> 20;
        float2 Zf = data[sw(p)], Zm = data[sw(pm)];
        float2 U0 = make_float2(0.5f * (Zf.x + Zm.x), 0.5f * (Zf.y - Zm.y));
        float2 Dm = make_float2(Zf.x - Zm.x, Zf.y + Zm.y);
        float2 U1 = make_float2(0.5f * Dm.y, -0.5f * Dm.x);
        float4 Ka = Kp[p];
        float2 S0 = cmulf(U0, make_float2(Ka.x, Ka.y));
        float2 S1 = cmulf(U1, make_float2(Ka.z, Ka.w));
        float2 Wf = make_float2((S0.x - S1.y) * scale, (S0.y + S1.x) * scale);
        float4 Kb = Kp[pm];
        float2 U0m = make_float2(U0.x, -U0.y);
        float2 U1m = make_float2(U1.x, -U1.y);
        float2 S0m = cmulf(U0m, make_float2(Kb.x, Kb.y));
        float2 S1m = cmulf(U1m, make_float2(Kb.z, Kb.w));
        float2 Wm = make_float2((S0m.x - S1m.y) * scale, (S0m.y + S1m.x) * scale);
        data[sw(p)] = Wf;
        if (pm != p) data[sw(pm)] = Wm;
    }
    __syncthreads();
    {
        float2 v[16];
#pragma unroll
        for (int i = 0; i < 16; i++) v[i] = data[sw(t * 16 + i)];
        fft16_dit<true>(v);
#pragma unroll
        for (int i = 0; i < 16; i++) data[sw(t * 16 + i)] = v[i];
    }
    __syncthreads();
    {
        int j0 = t & 15;
        int base2 = (t >> 4) * 256 + j0;
        float2 v[16];
        v[0] = data[sw(base2)];
#pragma unroll
        for (int i = 1; i < 16; i++)
            v[i] = cmulc(data[sw(base2 + 16 * i)], twget(tw, 16 * j0 * BR4[i]));
        fft16_dit<true>(v);
#pragma unroll
        for (int i = 0; i < 16; i++) data[sw(base2 + 16 * i)] = v[i];
    }
    __syncthreads();
    {
        float2 v[16];
        v[0] = data[sw(t)];
#pragma unroll
        for (int i = 1; i < 16; i++)
            v[i] = cmulc(data[sw(i * 256 + t)], twget(tw, t * BR4[i]));
        fft16_dit<true>(v);
        float d0 = dvec[h0], d1 = dvec[h0 + 1];
#pragma unroll
        for (int k = 0; k < 8; k++) {
            float y0 = gelu_f(v[k].x + ureg[k].x * d0);
            float y1 = gelu_f(v[k].y + ureg[k].y * d1);
            *(float2*)(base + (size_t)(t + 256 * k) * Hdim) = make_float2(y0, y1);
        }
    }
}

// ---------------- gated MLP + residual + fused next-layer LN: 32 rows/block ----------------
// Thread t owns col o = t&127 for BOTH w1 and w2, rows rh*16..rh*16+15 (rh = t>>7).
// Gate v1*sigmoid(v2) is computed entirely in-thread.
__global__ __launch_bounds__(256) void mlp_kernel(const float* __restrict__ y,
                                                  float* __restrict__ h,
                                                  float* __restrict__ hn,
                                                  const float* __restrict__ w1,
                                                  const float* __restrict__ b1,
                                                  const float* __restrict__ w2,
                                                  const float* __restrict__ b2,
                                                  const float* __restrict__ nw,
                                                  const float* __restrict__ nb,
                                                  int do_ln) {
    const int ROWS = 32;
    int r0 = blockIdx.x * ROWS;
    int t = threadIdx.x;
    __shared__ __align__(16) float yst[128 * 36];  // y^T [k][r], pad 36 (18.4 KB)
    __shared__ float wst[2 * 128 * 17];            // w chunk [mat][o][k16]; aliased as dots later
    __shared__ float2 mv[32];
    float* dots = wst;                             // 32*132 = 4224 <= 4352 floats

    for (int i = t; i < ROWS * 128; i += 256) {
        int r = i >> 7, k = i & 127;
        yst[k * 36 + r] = y[(size_t)(r0 + r) * Hdim + k];
    }
    int o = t & 127, rh = t >> 7;
    float acc1[16], acc2[16];
    float bias1 = b1[o], bias2 = b2[o];
#pragma unroll
    for (int j = 0; j < 16; j++) { acc1[j] = bias1; acc2[j] = bias2; }

    // register prefetch of w chunk 0 (16 elems/thread of the 4096-elem chunk)
    float pf[16];
#pragma unroll
    for (int j = 0; j < 16; j++) {
        int e = t + 256 * j;
        int mat = e >> 11, rem = e & 2047, oo = rem >> 4, kk = rem & 15;
        pf[j] = (mat ? w2 : w1)[(size_t)oo * Hdim + kk];
    }
    for (int kc0 = 0; kc0 < 128; kc0 += 16) {
        __syncthreads();  // protect previous chunk's reads (and yst fill on first iter)
#pragma unroll
        for (int j = 0; j < 16; j++) {
            int e = t + 256 * j;
            int mat = e >> 11, rem = e & 2047, oo = rem >> 4, kk = rem & 15;
            wst[mat * 2176 + oo * 17 + kk] = pf[j];
        }
        __syncthreads();
        if (kc0 + 16 < 128) {  // prefetch next chunk (hides L2 latency under the FMAs)
#pragma unroll
            for (int j = 0; j < 16; j++) {
                int e = t + 256 * j;
                int mat = e >> 11, rem = e & 2047, oo = rem >> 4, kk = rem & 15;
                pf[j] = (mat ? w2 : w1)[(size_t)oo * Hdim + kc0 + 16 + kk];
            }
        }
#pragma unroll
        for (int k = 0; k < 16; k++) {
            float wv1 = wst[o * 17 + k];
            float wv2 = wst[2176 + o * 17 + k];
            int kk = (kc0 + k) * 36 + rh * 16;
            float4 ya = *(const float4*)&yst[kk];       // wave-uniform -> LDS broadcast
            float4 yb = *(const float4*)&yst[kk + 4];
            float4 yc = *(const float4*)&yst[kk + 8];
            float4 yd = *(const float4*)&yst[kk + 12];
            acc1[0]  = fmaf(wv1, ya.x, acc1[0]);  acc2[0]  = fmaf(wv2, ya.x, acc2[0]);
            acc1[1]  = fmaf(wv1, ya.y, acc1[1]);  acc2[1]  = fmaf(wv2, ya.y, acc2[1]);
            acc1[2]  = fmaf(wv1, ya.z, acc1[2]);  acc2[2]  = fmaf(wv2, ya.z, acc2[2]);
            acc1[3]  = fmaf(wv1, ya.w, acc1[3]);  acc2[3]  = fmaf(wv2, ya.w, acc2[3]);
            acc1[4]  = fmaf(wv1, yb.x, acc1[4]);  acc2[4]  = fmaf(wv2, yb.x, acc2[4]);
            acc1[5]  = fmaf(wv1, yb.y, acc1[5]);  acc2[5]  = fmaf(wv2, yb.y, acc2[5]);
            acc1[6]  = fmaf(wv1, yb.z, acc1[6]);  acc2[6]  = fmaf(wv2, yb.z, acc2[6]);
            acc1[7]  = fmaf(wv1, yb.w, acc1[7]);  acc2[7]  = fmaf(wv2, yb.w, acc2[7]);
            acc1[8]  = fmaf(wv1, yc.x, acc1[8]);  acc2[8]  = fmaf(wv2, yc.x, acc2[8]);
            acc1[9]  = fmaf(wv1, yc.y, acc1[9]);  acc2[9]  = fmaf(wv2, yc.y, acc2[9]);
            acc1[10] = fmaf(wv1, yc.z, acc1[10]); acc2[10] = fmaf(wv2, yc.z, acc2[10]);
            acc1[11] = fmaf(wv1, yc.w, acc1[11]); acc2[11] = fmaf(wv2, yc.w, acc2[11]);
            acc1[12] = fmaf(wv1, yd.x, acc1[12]); acc2[12] = fmaf(wv2, yd.x, acc2[12]);
            acc1[13] = fmaf(wv1, yd.y, acc1[13]); acc2[13] = fmaf(wv2, yd.y, acc2[13]);
            acc1[14] = fmaf(wv1, yd.z, acc1[14]); acc2[14] = fmaf(wv2, yd.z, acc2[14]);
            acc1[15] = fmaf(wv1, yd.w, acc1[15]); acc2[15] = fmaf(wv2, yd.w, acc2[15]);
        }
    }
    __syncthreads();  // wst dead -> reuse as dots
    // gate + residual, all in-thread
    float hv[16];
#pragma unroll
    for (int j = 0; j < 16; j++) {
        int r = rh * 16 + j;
        float g = fast_rcp(1.0f + __expf(-acc2[j]));
        hv[j] = h[(size_t)(r0 + r) * Hdim + o] + acc1[j] * g;
        dots[r * 132 + o] = hv[j];
    }
    __syncthreads();
    if (do_ln) {
        int row = t >> 3, lane = t & 7;  // 8 lanes per row, 16 vals each
        float s1 = 0.f, s2 = 0.f;
        int base = row * 132 + lane * 16;
#pragma unroll
        for (int q = 0; q < 4; q++) {
            float4 v4 = *(const float4*)&dots[base + 4 * q];
            s1 += v4.x + v4.y + v4.z + v4.w;
            s2 += v4.x * v4.x + v4.y * v4.y + v4.z * v4.z + v4.w * v4.w;
        }
#pragma unroll
        for (int m = 1; m < 8; m <<= 1) { s1 += __shfl_xor(s1, m); s2 += __shfl_xor(s2, m); }
        if (lane == 0) {
            float mu = s1 * (1.0f / 128.0f);
            float var = s2 * (1.0f / 128.0f) - mu * mu;
            mv[row] = make_float2(mu, fast_rsq(var + 1e-5f));
        }
        __syncthreads();
        float nwc = nw[o], nbc = nb[o];
#pragma unroll
        for (int j = 0; j < 16; j++) {
            int r = rh * 16 + j;
            size_t idx = (size_t)(r0 + r) * Hdim + o;
            h[idx] = hv[j];
            float2 m = mv[r];
            hn[idx] = (hv[j] - m.x) * m.y * nwc + nbc;
        }
    } else {
#pragma unroll
        for (int j = 0; j < 16; j++) {
            int r = rh * 16 + j;
            h[(size_t)(r0 + r) * Hdim + o] = hv[j];
        }
    }
}

// ---------------- decoder: 32 rows/block ----------------
__global__ __launch_bounds__(256) void decoder_kernel(const float* __restrict__ h,
                                                      const float* __restrict__ w,
                                                      const float* __restrict__ b,
                                                      float* __restrict__ out) {
    int r0 = blockIdx.x * 32;
    int t = threadIdx.x;
    __shared__ float ws[64 * 129];
    __shared__ __align__(16) float hst[128 * 36];
    for (int i = t; i < 64 * 128; i += 256) ws[(i >> 7) * 129 + (i & 127)] = w[i];
    for (int i = t; i < 32 * 128; i += 256) {
        int r = i >> 7, k = i & 127;
        hst[k * 36 + r] = h[(size_t)(r0 + r) * Hdim + k];
    }
    __syncthreads();
    int o = t & 63, q = t >> 6;
    float acc[8];
    float bo = b[o];
#pragma unroll
    for (int j = 0; j < 8; j++) acc[j] = bo;
    for (int k = 0; k < 128; k++) {
        float wv = ws[o * 129 + k];
        float4 ha = *(const float4*)&hst[k * 36 + q * 8];
        float4 hb = *(const float4*)&hst[k * 36 + q * 8 + 4];
        acc[0] += wv * ha.x; acc[1] += wv * ha.y; acc[2] += wv * ha.z; acc[3] += wv * ha.w;
        acc[4] += wv * hb.x; acc[5] += wv * hb.y; acc[6] += wv * hb.z; acc[7] += wv * hb.w;
    }
#pragma unroll
    for (int j = 0; j < 8; j++) out[(size_t)(r0 + q * 8 + j) * 64 + o] = acc[j];
}

extern "C" void kernel_launch(void* const* d_in, const int* in_sizes, int n_in,
                              void* d_out, int out_size, void* d_ws, size_t ws_size,
                              hipStream_t stream) {
    const float* x      = (const float*)d_in[0];
    const float* enc_w  = (const float*)d_in[2];
    const float* enc_b  = (const float*)d_in[3];
    const float* dec_w  = (const float*)d_in[4];
    const float* dec_b  = (const float*)d_in[5];
    const float* lam_re = (const float*)d_in[6];
    const float* lam_im = (const float*)d_in[7];
    const float* p_re   = (const float*)d_in[8];
    const float* p_im   = (const float*)d_in[9];
    const float* b_re   = (const float*)d_in[10];
    const float* b_im   = (const float*)d_in[11];
    const float* c_re   = (const float*)d_in[12];
    const float* c_im   = (const float*)d_in[13];
    const float* dvec   = (const float*)d_in[14];
    const float* lstep  = (const float*)d_in[15];
    const float* norm_w = (const float*)d_in[16];
    const float* norm_b = (const float*)d_in[17];
    const float* w1     = (const float*)d_in[18];
    const float* b1     = (const float*)d_in[19];
    const float* w2     = (const float*)d_in[20];
    const float* b2     = (const float*)d_in[21];
    float* out = (float*)d_out;

    char* ws = (char*)d_ws;
    float2* tw  = (float2*)ws;  ws += 2048 * sizeof(float2);
    float*  h   = (float*)ws;   ws += (size_t)Bsz * Lseq * Hdim * sizeof(float);
    float*  hn  = (float*)ws;   ws += (size_t)Bsz * Lseq * Hdim * sizeof(float);
    float2* atr = (float2*)ws;  ws += (size_t)NLAYERS * Hdim * Lseq * sizeof(float2);
    float4* Kd2 = (float4*)ws;  ws += (size_t)NLAYERS * (Hdim / 2) * 4096 * sizeof(float4);

    const int nrows = Bsz * Lseq;  // 16384

    twiddle_init<<<8, 256, 0, stream>>>(tw);
    spectrum_kernel<<<dim3(Hdim, NLAYERS, 2), 256, 0, stream>>>(
        lam_re, lam_im, p_re, p_im, b_re, b_im, c_re, c_im, lstep, atr);
    kfft_kernel<<<dim3(Hdim, NLAYERS), 256, 0, stream>>>(atr, Kd2, tw);
    encoder_kernel<<<nrows / 16, 256, 0, stream>>>(x, enc_w, enc_b, norm_w, norm_b, h, hn);
    for (int L = 0; L < NLAYERS; L++) {
        conv_kernel<<<dim3(Hdim / 2, Bsz), 256, 0, stream>>>(
            hn, Kd2 + (size_t)L * (Hdim / 2) * 4096, dvec + L * Hdim, tw);
        int do_ln = (L < NLAYERS - 1) ? 1 : 0;
        const float* nwn = norm_w + ((L + 1) % NLAYERS) * Hdim;
        const float* nbn = norm_b + ((L + 1) % NLAYERS) * Hdim;
        mlp_kernel<<<nrows / 32, 256, 0, stream>>>(hn, h, hn,
                                                   w1 + (size_t)L * Hdim * Hdim, b1 + L * Hdim,
                                                   w2 + (size_t)L * Hdim * Hdim, b2 + L * Hdim,
                                                   nwn, nbn, do_ln);
    }
    decoder_kernel<<<nrows / 32, 256, 0, stream>>>(h, dec_w, dec_b, out);
}

// Round 7
// 369.174 us; speedup vs baseline: 2.4151x; 1.1413x over previous
//
#include <hip/hip_runtime.h>
#include <hip/hip_bf16.h>

// S4 (DPLR) forward, B=8 L=2048 IN=OUT=64 H=128 N=64, 4 layers.
// R7: hn stored TRANSPOSED as hnT[b][h][l] so conv_kernel's global loads/stores
// are fully coalesced (R6 counters: 35.7 MB fetch vs 8 MB ideal, 512B lane stride).
// h (residual/decoder path) stays row-major.

#define Bsz 8
#define Lseq 2048
#define Hdim 128
#define Npol 64
#define NLAYERS 4

__device__ __forceinline__ float fast_rcp(float x) { return __builtin_amdgcn_rcpf(x); }
__device__ __forceinline__ float fast_rsq(float x) { return __builtin_amdgcn_rsqf(x); }

__device__ __forceinline__ float2 cmulf(float2 a, float2 b) {
    return make_float2(a.x * b.x - a.y * b.y, a.x * b.y + a.y * b.x);
}
__device__ __forceinline__ float2 cmulc(float2 a, float2 b) {  // a * conj(b)
    return make_float2(a.x * b.x + a.y * b.y, a.y * b.x - a.x * b.y);
}

__device__ __forceinline__ float gelu_f(float v) {
    float z = 0.7978845608028654f * (v + 0.044715f * v * v * v);
    float e = __expf(2.0f * z);
    return v - v * fast_rcp(e + 1.0f);
}

// XOR swizzle: mixes digit1 into the bank digit so strides 1/16/256 are all conflict-uniform.
__device__ __forceinline__ int sw(int i) { return (i & ~15) | ((i ^ (i >> 4)) & 15); }

static __device__ const float W16R[8] = {1.f, 0.9238795325f, 0.7071067812f, 0.3826834324f,
                                         0.f, -0.3826834324f, -0.7071067812f, -0.9238795325f};
static __device__ const float W16I[8] = {0.f, -0.3826834324f, -0.7071067812f, -0.9238795325f,
                                         -1.f, -0.9238795325f, -0.7071067812f, -0.3826834324f};
static __device__ const int BR4[16] = {0, 8, 4, 12, 2, 10, 6, 14, 1, 9, 5, 13, 3, 11, 7, 15};
static __device__ const int BR3[8] = {0, 4, 2, 6, 1, 5, 3, 7};

__device__ __forceinline__ float2 twget(const float2* __restrict__ tw, int e) {
    float2 w = tw[e & 2047];
    if (e & 2048) { w.x = -w.x; w.y = -w.y; }
    return w;
}

template <bool INV>
__device__ __forceinline__ void fft16_dif(float2 v[16]) {
#pragma unroll
    for (int mi = 0; mi < 4; mi++) {
        const int m = 8 >> mi;
#pragma unroll
        for (int g = 0; g < 16; g += 2 * m) {
#pragma unroll
            for (int j = 0; j < m; j++) {
                float wr = W16R[j << mi];
                float wi = INV ? -W16I[j << mi] : W16I[j << mi];
                float2 a = v[g + j], b = v[g + j + m];
                float dx = a.x - b.x, dy = a.y - b.y;
                v[g + j] = make_float2(a.x + b.x, a.y + b.y);
                v[g + j + m] = make_float2(dx * wr - dy * wi, dx * wi + dy * wr);
            }
        }
    }
}

template <bool INV>
__device__ __forceinline__ void fft16_dit(float2 v[16]) {
#pragma unroll
    for (int mi = 3; mi >= 0; mi--) {
        const int m = 8 >> mi;
#pragma unroll
        for (int g = 0; g < 16; g += 2 * m) {
#pragma unroll
            for (int j = 0; j < m; j++) {
                float wr = W16R[j << mi];
                float wi = INV ? -W16I[j << mi] : W16I[j << mi];
                float2 a = v[g + j], b = v[g + j + m];
                float bx = b.x * wr - b.y * wi, by = b.x * wi + b.y * wr;
                v[g + j] = make_float2(a.x + bx, a.y + by);
                v[g + j + m] = make_float2(a.x - bx, a.y - by);
            }
        }
    }
}

template <bool INV>
__device__ __forceinline__ void fft8_dif(float2 v[8]) {
#pragma unroll
    for (int mi = 0; mi < 3; mi++) {
        const int m = 4 >> mi;
#pragma unroll
        for (int g = 0; g < 8; g += 2 * m) {
#pragma unroll
            for (int j = 0; j < m; j++) {
                float wr = W16R[j << (mi + 1)];
                float wi = INV ? -W16I[j << (mi + 1)] : W16I[j << (mi + 1)];
                float2 a = v[g + j], b = v[g + j + m];
                float dx = a.x - b.x, dy = a.y - b.y;
                v[g + j] = make_float2(a.x + b.x, a.y + b.y);
                v[g + j + m] = make_float2(dx * wr - dy * wi, dx * wi + dy * wr);
            }
        }
    }
}

// Forward 4096-pt FFT in LDS, 256 threads, result in 12-bit bit-reversed positions.
// No leading barrier IF caller's fill writes exactly {t+256k, k<16} per thread.
__device__ __forceinline__ void fft4096_fwd(float2* data, const float2* __restrict__ tw, int t) {
    {
        float2 v[16];
#pragma unroll
        for (int k = 0; k < 16; k++) v[k] = data[sw(t + 256 * k)];
        fft16_dif<false>(v);
#pragma unroll
        for (int i = 1; i < 16; i++) v[i] = cmulf(v[i], twget(tw, t * BR4[i]));
#pragma unroll
        for (int i = 0; i < 16; i++) data[sw(i * 256 + t)] = v[i];
    }
    __syncthreads();
    {
        int j0 = t & 15;
        int base = (t >> 4) * 256 + j0;
        float2 v[16];
#pragma unroll
        for (int k = 0; k < 16; k++) v[k] = data[sw(base + 16 * k)];
        fft16_dif<false>(v);
#pragma unroll
        for (int i = 1; i < 16; i++) v[i] = cmulf(v[i], twget(tw, 16 * j0 * BR4[i]));
#pragma unroll
        for (int i = 0; i < 16; i++) data[sw(base + 16 * i)] = v[i];
    }
    __syncthreads();
    {
        float2 v[16];
#pragma unroll
        for (int k = 0; k < 16; k++) v[k] = data[sw(t * 16 + k)];
        fft16_dif<false>(v);
#pragma unroll
        for (int i = 0; i < 16; i++) data[sw(t * 16 + i)] = v[i];
    }
    __syncthreads();
}

// ---------------- twiddle table ----------------
__global__ __launch_bounds__(256) void twiddle_init(float2* tw) {
    int k = blockIdx.x * blockDim.x + threadIdx.x;
    if (k < 2048) {
        double a = -6.283185307179586476925286766559 * (double)k / 4096.0;
        tw[k] = make_float2((float)cos(a), (float)sin(a));
    }
}

// ---------------- encoder + fused LN: 16 rows/block; LN out -> hnT[b][h][l] ----------------
__global__ __launch_bounds__(256) void encoder_kernel(const float* __restrict__ x,
                                                      const float* __restrict__ w,
                                                      const float* __restrict__ b,
                                                      const float* __restrict__ nw,
                                                      const float* __restrict__ nb,
                                                      float* __restrict__ h,
                                                      float* __restrict__ hnT) {
    int r0 = blockIdx.x * 16;
    int t = threadIdx.x;
    __shared__ float ws[128 * 65];
    __shared__ __align__(16) float xst[64 * 20];
    __shared__ float dots[16 * 128];
    __shared__ float2 mv[16];
    for (int i = t; i < 128 * 64; i += 256) ws[(i >> 6) * 65 + (i & 63)] = w[i];
    for (int i = t; i < 16 * 64; i += 256) {
        int r = i >> 6, k = i & 63;
        xst[k * 20 + r] = x[(size_t)(r0 + r) * 64 + k];
    }
    __syncthreads();
    int o = t & 127, half = t >> 7;
    float acc[8];
    float bo = b[o];
#pragma unroll
    for (int j = 0; j < 8; j++) acc[j] = bo;
    for (int k = 0; k < 64; k++) {
        float wv = ws[o * 65 + k];
        float4 xa = *(const float4*)&xst[k * 20 + half * 8];
        float4 xb = *(const float4*)&xst[k * 20 + half * 8 + 4];
        acc[0] += wv * xa.x; acc[1] += wv * xa.y; acc[2] += wv * xa.z; acc[3] += wv * xa.w;
        acc[4] += wv * xb.x; acc[5] += wv * xb.y; acc[6] += wv * xb.z; acc[7] += wv * xb.w;
    }
#pragma unroll
    for (int j = 0; j < 8; j++) dots[(half * 8 + j) * 128 + o] = acc[j];
    __syncthreads();
    {
        int row = t >> 4, lane = t & 15;
        float s1 = 0.f, s2 = 0.f;
#pragma unroll
        for (int i = 0; i < 8; i++) {
            float v = dots[row * 128 + lane * 8 + i];
            s1 += v; s2 += v * v;
        }
#pragma unroll
        for (int m = 1; m < 16; m <<= 1) { s1 += __shfl_xor(s1, m); s2 += __shfl_xor(s2, m); }
        if (lane == 0) {
            float mu = s1 * (1.0f / 128.0f);
            float var = s2 * (1.0f / 128.0f) - mu * mu;
            mv[row] = make_float2(mu, fast_rsq(var + 1e-5f));
        }
    }
    __syncthreads();
    int c = t & 127;
    int bb = r0 >> 11, l0 = r0 & 2047;
    float nwc = nw[c], nbc = nb[c];
    float hnv[8];
#pragma unroll
    for (int j = 0; j < 8; j++) {
        int r = half * 8 + j;
        float v = dots[r * 128 + c];
        h[(size_t)(r0 + r) * Hdim + c] = v;
        float2 m = mv[r];
        hnv[j] = (v - m.x) * m.y * nwc + nbc;
    }
    float* dst = hnT + ((size_t)bb * Hdim + c) * Lseq + l0 + half * 8;
    *(float4*)dst = make_float4(hnv[0], hnv[1], hnv[2], hnv[3]);
    *(float4*)(dst + 4) = make_float4(hnv[4], hnv[5], hnv[6], hnv[7]);
}

// ---------------- DPLR generating function: 4 l's per thread, fmaf chains ----------------
__global__ __launch_bounds__(256, 4) void spectrum_kernel(const float* __restrict__ lam_re,
                                                          const float* __restrict__ lam_im,
                                                          const float* __restrict__ p_re,
                                                          const float* __restrict__ p_im,
                                                          const float* __restrict__ b_re,
                                                          const float* __restrict__ b_im,
                                                          const float* __restrict__ c_re,
                                                          const float* __restrict__ c_im,
                                                          const float* __restrict__ log_step,
                                                          float2* __restrict__ at_roots) {
    int h = blockIdx.x, layer = blockIdx.y, t = threadIdx.x;
    __shared__ __align__(16) float4 polA[Npol];  // (lam.re, lam.im, n00.re, n00.im)
    __shared__ __align__(16) float4 polB[Npol];  // (n01.re, n01.im, n10.re, n10.im)
    __shared__ float n11S[Npol];
    int baseP = (layer * Hdim + h) * Npol;
    if (t < Npol) {
        int n = t;
        float lr = lam_re[baseP + n], li = lam_im[baseP + n];
        float pr = p_re[baseP + n], pi = p_im[baseP + n];
        float br = b_re[baseP + n], bi = b_im[baseP + n];
        float cr = c_re[baseP + n], ci = c_im[baseP + n];
        polA[n] = make_float4(lr, li, cr * br + ci * bi, cr * bi - ci * br);
        polB[n] = make_float4(cr * pr + ci * pi, cr * pi - ci * pr,
                              pr * br + pi * bi, pr * bi - pi * br);
        n11S[n] = pr * pr + pi * pi;
    }
    __syncthreads();
    float step = expf(log_step[layer * Hdim + h]);
    float gs = 2.0f / step;
    int l0 = 1024 * blockIdx.z;

    float gr[4], gi[4], cr2[4], ci2[4];
#pragma unroll
    for (int j = 0; j < 4; j++) {
        int l = l0 + t + 256 * j;
        float ang = -6.283185307179586f * (float)l / (float)Lseq;
        float wr = cosf(ang), wi = sinf(ang);  // fp32 omega on purpose: keeps |g|^2 in range
        float dr = 1.0f + wr, di = wi;
        float invd2 = fast_rcp(dr * dr + di * di);
        float nr = 1.0f - wr, ni = -wi;
        gr[j] = gs * (nr * dr + ni * di) * invd2;
        gi[j] = gs * (ni * dr - nr * di) * invd2;
        cr2[j] = 2.0f * dr * invd2;
        ci2[j] = -2.0f * di * invd2;
    }
    float k00x[4] = {0, 0, 0, 0}, k00y[4] = {0, 0, 0, 0};
    float k01x[4] = {0, 0, 0, 0}, k01y[4] = {0, 0, 0, 0};
    float k10x[4] = {0, 0, 0, 0}, k10y[4] = {0, 0, 0, 0};
    float k11x[4] = {0, 0, 0, 0}, k11y[4] = {0, 0, 0, 0};
#pragma unroll 2
    for (int n = 0; n < Npol; n++) {
        float4 A = polA[n];  // b128 broadcast
        float4 B = polB[n];
        float n11 = n11S[n];
#pragma unroll
        for (int j = 0; j < 4; j++) {
            float er = gr[j] - A.x, ei = gi[j] - A.y;
            float inv2 = fast_rcp(fmaf(er, er, ei * ei));
            float ir = er * inv2;
            float mi = ei * inv2;  // = -Im(1/(g-lam))
            k00x[j] = fmaf(A.z, ir, fmaf(A.w, mi, k00x[j]));
            k00y[j] = fmaf(A.w, ir, fmaf(-A.z, mi, k00y[j]));
            k01x[j] = fmaf(B.x, ir, fmaf(B.y, mi, k01x[j]));
            k01y[j] = fmaf(B.y, ir, fmaf(-B.x, mi, k01y[j]));
            k10x[j] = fmaf(B.z, ir, fmaf(B.w, mi, k10x[j]));
            k10y[j] = fmaf(B.w, ir, fmaf(-B.z, mi, k10y[j]));
            k11x[j] = fmaf(n11, ir, k11x[j]);
            k11y[j] = fmaf(-n11, mi, k11y[j]);
        }
    }
#pragma unroll
    for (int j = 0; j < 4; j++) {
        float wr2 = 1.0f + k11x[j], wi2 = k11y[j];
        float w2inv = fast_rcp(fmaf(wr2, wr2, wi2 * wi2));
        float vr = wr2 * w2inv, vi = -wi2 * w2inv;
        float t1x = k01x[j] * k10x[j] - k01y[j] * k10y[j];
        float t1y = k01x[j] * k10y[j] + k01y[j] * k10x[j];
        float t2x = t1x * vr - t1y * vi, t2y = t1x * vi + t1y * vr;
        float ex = k00x[j] - t2x, ey = k00y[j] - t2y;
        int l = l0 + t + 256 * j;
        at_roots[((size_t)layer * Hdim + h) * Lseq + l] =
            make_float2(cr2[j] * ex - ci2[j] * ey, cr2[j] * ey + ci2[j] * ex);
    }
}

// ---------------- kernel FFT: ifft2048 -> pad -> fft4096, all layers ----------------
// Kd2 layout: [layer][hp][p] float4 = (K_{2hp}[p].re,.im, K_{2hp+1}[p].re,.im), p bit-rev.
__global__ __launch_bounds__(256) void kfft_kernel(const float2* __restrict__ at_roots,
                                                   float4* __restrict__ Kd2,
                                                   const float2* __restrict__ tw) {
    int h = blockIdx.x, layer = blockIdx.y, t = threadIdx.x;
    __shared__ float2 data[4096];
    __shared__ float ktmp[2048];
    const float2* src = at_roots + ((size_t)layer * Hdim + h) * Lseq;
#pragma unroll
    for (int k = 0; k < 8; k++) {
        int l = t + 256 * k;
        data[sw(l)] = src[l];
    }
    __syncthreads();
    // inverse 2048-pt (conjugated DIF), digits 16 x 16 x 8
    if (t < 128) {
        float2 v[16];
#pragma unroll
        for (int k = 0; k < 16; k++) v[k] = data[sw(t + 128 * k)];
        fft16_dif<true>(v);
#pragma unroll
        for (int i = 1; i < 16; i++) v[i] = cmulc(v[i], twget(tw, 2 * t * BR4[i]));
#pragma unroll
        for (int i = 0; i < 16; i++) data[sw(i * 128 + t)] = v[i];
    }
    __syncthreads();
    if (t < 128) {
        int i2 = t >> 3, j0 = t & 7;
        int base2 = i2 * 128 + j0;
        float2 v[16];
#pragma unroll
        for (int k = 0; k < 16; k++) v[k] = data[sw(base2 + 8 * k)];
        fft16_dif<true>(v);
#pragma unroll
        for (int i = 1; i < 16; i++) v[i] = cmulc(v[i], twget(tw, 32 * j0 * BR4[i]));
#pragma unroll
        for (int i = 0; i < 16; i++) data[sw(base2 + 8 * i)] = v[i];
    }
    __syncthreads();
    {
        float2 v8[8];
#pragma unroll
        for (int k = 0; k < 8; k++) v8[k] = data[sw(t * 8 + k)];
        fft8_dif<true>(v8);
        int r = BR4[t >> 4], s = BR4[t & 15];
#pragma unroll
        for (int i = 0; i < 8; i++) {
            int l = r + 16 * s + 256 * BR3[i];
            ktmp[l] = v8[i].x * (1.0f / 2048.0f);
        }
    }
    __syncthreads();
#pragma unroll
    for (int k = 0; k < 8; k++) {
        int l = t + 256 * k;
        data[sw(l)] = make_float2(ktmp[l], 0.f);
        data[sw(l + 2048)] = make_float2(0.f, 0.f);
    }
    fft4096_fwd(data, tw, t);
    float2* dst = (float2*)(Kd2 + ((size_t)layer * 64 + (h >> 1)) * 4096);
    int half = h & 1;
#pragma unroll
    for (int k = 0; k < 16; k++) {
        int p = t + 256 * k;
        dst[2 * p + half] = data[sw(p)];
    }
}

// ---------------- FFT convolution + D-skip + gelu, channel pair per block ----------------
// hnT layout: [b][h][l] — all global accesses below are lane-consecutive in l (coalesced).
__global__ __launch_bounds__(256) void conv_kernel(float* __restrict__ hnT,
                                                   const float4* __restrict__ Kd2,
                                                   const float* __restrict__ dvec,
                                                   const float2* __restrict__ tw) {
    int hp = blockIdx.x, b = blockIdx.y, h0 = hp * 2, t = threadIdx.x;
    __shared__ float2 data[4096];
    float* u0 = hnT + ((size_t)b * Hdim + h0) * Lseq;
    float* u1 = u0 + Lseq;
    float2 ureg[8];
#pragma unroll
    for (int k = 0; k < 8; k++) {
        int l = t + 256 * k;
        float2 u2 = make_float2(u0[l], u1[l]);
        ureg[k] = u2;
        data[sw(l)] = u2;
        data[sw(l + 2048)] = make_float2(0.f, 0.f);
    }
    fft4096_fwd(data, tw, t);
    const float4* Kp = Kd2 + (size_t)hp * 4096;
    const float scale = 1.0f / 4096.0f;
    for (int f = t; f <= 2048; f += 256) {
        int fm = (4096 - f) & 4095;
        int p = __brev((unsigned)f) >> 20;
        int pm = __brev((unsigned)fm) >> 20;
        float2 Zf = data[sw(p)], Zm = data[sw(pm)];
        float2 U0 = make_float2(0.5f * (Zf.x + Zm.x), 0.5f * (Zf.y - Zm.y));
        float2 Dm = make_float2(Zf.x - Zm.x, Zf.y + Zm.y);
        float2 U1 = make_float2(0.5f * Dm.y, -0.5f * Dm.x);
        float4 Ka = Kp[p];
        float2 S0 = cmulf(U0, make_float2(Ka.x, Ka.y));
        float2 S1 = cmulf(U1, make_float2(Ka.z, Ka.w));
        float2 Wf = make_float2((S0.x - S1.y) * scale, (S0.y + S1.x) * scale);
        float4 Kb = Kp[pm];
        float2 U0m = make_float2(U0.x, -U0.y);
        float2 U1m = make_float2(U1.x, -U1.y);
        float2 S0m = cmulf(U0m, make_float2(Kb.x, Kb.y));
        float2 S1m = cmulf(U1m, make_float2(Kb.z, Kb.w));
        float2 Wm = make_float2((S0m.x - S1m.y) * scale, (S0m.y + S1m.x) * scale);
        data[sw(p)] = Wf;
        if (pm != p) data[sw(pm)] = Wm;
    }
    __syncthreads();
    {
        float2 v[16];
#pragma unroll
        for (int i = 0; i < 16; i++) v[i] = data[sw(t * 16 + i)];
        fft16_dit<true>(v);
#pragma unroll
        for (int i = 0; i < 16; i++) data[sw(t * 16 + i)] = v[i];
    }
    __syncthreads();
    {
        int j0 = t & 15;
        int base2 = (t >> 4) * 256 + j0;
        float2 v[16];
        v[0] = data[sw(base2)];
#pragma unroll
        for (int i = 1; i < 16; i++)
            v[i] = cmulc(data[sw(base2 + 16 * i)], twget(tw, 16 * j0 * BR4[i]));
        fft16_dit<true>(v);
#pragma unroll
        for (int i = 0; i < 16; i++) data[sw(base2 + 16 * i)] = v[i];
    }
    __syncthreads();
    {
        float2 v[16];
        v[0] = data[sw(t)];
#pragma unroll
        for (int i = 1; i < 16; i++)
            v[i] = cmulc(data[sw(i * 256 + t)], twget(tw, t * BR4[i]));
        fft16_dit<true>(v);
        float d0 = dvec[h0], d1 = dvec[h0 + 1];
#pragma unroll
        for (int k = 0; k < 8; k++) {
            int l = t + 256 * k;
            u0[l] = gelu_f(v[k].x + ureg[k].x * d0);
            u1[l] = gelu_f(v[k].y + ureg[k].y * d1);
        }
    }
}

// ---------------- gated MLP + residual + fused next-layer LN: 32 rows/block ----------------
// y input and LN output use hnT[b][h][l]; h (residual) stays row-major.
__global__ __launch_bounds__(256) void mlp_kernel(const float* __restrict__ yT,
                                                  float* __restrict__ h,
                                                  float* __restrict__ hnT,
                                                  const float* __restrict__ w1,
                                                  const float* __restrict__ b1,
                                                  const float* __restrict__ w2,
                                                  const float* __restrict__ b2,
                                                  const float* __restrict__ nw,
                                                  const float* __restrict__ nb,
                                                  int do_ln) {
    const int ROWS = 32;
    int r0 = blockIdx.x * ROWS;
    int t = threadIdx.x;
    __shared__ __align__(16) float yst[128 * 36];  // y^T [k][r], pad 36
    __shared__ float wst[2 * 128 * 17];            // w chunk; aliased as dots later
    __shared__ float2 mv[32];
    float* dots = wst;                             // 32*132 = 4224 <= 4352 floats

    int bb = r0 >> 11, l0 = r0 & 2047;
    for (int i = t; i < 128 * ROWS; i += 256) {
        int k = i >> 5, r = i & 31;                // lanes consecutive in r -> coalesced in l
        yst[k * 36 + r] = yT[((size_t)bb * Hdim + k) * Lseq + l0 + r];
    }
    int o = t & 127, rh = t >> 7;
    float acc1[16], acc2[16];
    float bias1 = b1[o], bias2 = b2[o];
#pragma unroll
    for (int j = 0; j < 16; j++) { acc1[j] = bias1; acc2[j] = bias2; }

    float pf[16];
#pragma unroll
    for (int j = 0; j < 16; j++) {
        int e = t + 256 * j;
        int mat = e >> 11, rem = e & 2047, oo = rem >> 4, kk = rem & 15;
        pf[j] = (mat ? w2 : w1)[(size_t)oo * Hdim + kk];
    }
    for (int kc0 = 0; kc0 < 128; kc0 += 16) {
        __syncthreads();
#pragma unroll
        for (int j = 0; j < 16; j++) {
            int e = t + 256 * j;
            int mat = e >> 11, rem = e & 2047, oo = rem >> 4, kk = rem & 15;
            wst[mat * 2176 + oo * 17 + kk] = pf[j];
        }
        __syncthreads();
        if (kc0 + 16 < 128) {
#pragma unroll
            for (int j = 0; j < 16; j++) {
                int e = t + 256 * j;
                int mat = e >> 11, rem = e & 2047, oo = rem >> 4, kk = rem & 15;
                pf[j] = (mat ? w2 : w1)[(size_t)oo * Hdim + kc0 + 16 + kk];
            }
        }
#pragma unroll
        for (int k = 0; k < 16; k++) {
            float wv1 = wst[o * 17 + k];
            float wv2 = wst[2176 + o * 17 + k];
            int kk = (kc0 + k) * 36 + rh * 16;
            float4 ya = *(const float4*)&yst[kk];
            float4 yb = *(const float4*)&yst[kk + 4];
            float4 yc = *(const float4*)&yst[kk + 8];
            float4 yd = *(const float4*)&yst[kk + 12];
            acc1[0]  = fmaf(wv1, ya.x, acc1[0]);  acc2[0]  = fmaf(wv2, ya.x, acc2[0]);
            acc1[1]  = fmaf(wv1, ya.y, acc1[1]);  acc2[1]  = fmaf(wv2, ya.y, acc2[1]);
            acc1[2]  = fmaf(wv1, ya.z, acc1[2]);  acc2[2]  = fmaf(wv2, ya.z, acc2[2]);
            acc1[3]  = fmaf(wv1, ya.w, acc1[3]);  acc2[3]  = fmaf(wv2, ya.w, acc2[3]);
            acc1[4]  = fmaf(wv1, yb.x, acc1[4]);  acc2[4]  = fmaf(wv2, yb.x, acc2[4]);
            acc1[5]  = fmaf(wv1, yb.y, acc1[5]);  acc2[5]  = fmaf(wv2, yb.y, acc2[5]);
            acc1[6]  = fmaf(wv1, yb.z, acc1[6]);  acc2[6]  = fmaf(wv2, yb.z, acc2[6]);
            acc1[7]  = fmaf(wv1, yb.w, acc1[7]);  acc2[7]  = fmaf(wv2, yb.w, acc2[7]);
            acc1[8]  = fmaf(wv1, yc.x, acc1[8]);  acc2[8]  = fmaf(wv2, yc.x, acc2[8]);
            acc1[9]  = fmaf(wv1, yc.y, acc1[9]);  acc2[9]  = fmaf(wv2, yc.y, acc2[9]);
            acc1[10] = fmaf(wv1, yc.z, acc1[10]); acc2[10] = fmaf(wv2, yc.z, acc2[10]);
            acc1[11] = fmaf(wv1, yc.w, acc1[11]); acc2[11] = fmaf(wv2, yc.w, acc2[11]);
            acc1[12] = fmaf(wv1, yd.x, acc1[12]); acc2[12] = fmaf(wv2, yd.x, acc2[12]);
            acc1[13] = fmaf(wv1, yd.y, acc1[13]); acc2[13] = fmaf(wv2, yd.y, acc2[13]);
            acc1[14] = fmaf(wv1, yd.z, acc1[14]); acc2[14] = fmaf(wv2, yd.z, acc2[14]);
            acc1[15] = fmaf(wv1, yd.w, acc1[15]); acc2[15] = fmaf(wv2, yd.w, acc2[15]);
        }
    }
    __syncthreads();  // wst dead -> reuse as dots
    float hv[16];
#pragma unroll
    for (int j = 0; j < 16; j++) {
        int r = rh * 16 + j;
        float g = fast_rcp(1.0f + __expf(-acc2[j]));
        hv[j] = h[(size_t)(r0 + r) * Hdim + o] + acc1[j] * g;
        dots[r * 132 + o] = hv[j];
    }
    __syncthreads();
    if (do_ln) {
        int row = t >> 3, lane = t & 7;  // 8 lanes per row, 16 vals each
        float s1 = 0.f, s2 = 0.f;
        int base = row * 132 + lane * 16;
#pragma unroll
        for (int q = 0; q < 4; q++) {
            float4 v4 = *(const float4*)&dots[base + 4 * q];
            s1 += v4.x + v4.y + v4.z + v4.w;
            s2 += v4.x * v4.x + v4.y * v4.y + v4.z * v4.z + v4.w * v4.w;
        }
#pragma unroll
        for (int m = 1; m < 8; m <<= 1) { s1 += __shfl_xor(s1, m); s2 += __shfl_xor(s2, m); }
        if (lane == 0) {
            float mu = s1 * (1.0f / 128.0f);
            float var = s2 * (1.0f / 128.0f) - mu * mu;
            mv[row] = make_float2(mu, fast_rsq(var + 1e-5f));
        }
        __syncthreads();
        float nwc = nw[o], nbc = nb[o];
        float hnv[16];
#pragma unroll
        for (int j = 0; j < 16; j++) {
            int r = rh * 16 + j;
            h[(size_t)(r0 + r) * Hdim + o] = hv[j];
            float2 m = mv[r];
            hnv[j] = (hv[j] - m.x) * m.y * nwc + nbc;
        }
        float* dst = hnT + ((size_t)bb * Hdim + o) * Lseq + l0 + rh * 16;
        *(float4*)(dst)      = make_float4(hnv[0],  hnv[1],  hnv[2],  hnv[3]);
        *(float4*)(dst + 4)  = make_float4(hnv[4],  hnv[5],  hnv[6],  hnv[7]);
        *(float4*)(dst + 8)  = make_float4(hnv[8],  hnv[9],  hnv[10], hnv[11]);
        *(float4*)(dst + 12) = make_float4(hnv[12], hnv[13], hnv[14], hnv[15]);
    } else {
#pragma unroll
        for (int j = 0; j < 16; j++) {
            int r = rh * 16 + j;
            h[(size_t)(r0 + r) * Hdim + o] = hv[j];
        }
    }
}

// ---------------- decoder: 32 rows/block ----------------
__global__ __launch_bounds__(256) void decoder_kernel(const float* __restrict__ h,
                                                      const float* __restrict__ w,
                                                      const float* __restrict__ b,
                                                      float* __restrict__ out) {
    int r0 = blockIdx.x * 32;
    int t = threadIdx.x;
    __shared__ float ws[64 * 129];
    __shared__ __align__(16) float hst[128 * 36];
    for (int i = t; i < 64 * 128; i += 256) ws[(i >> 7) * 129 + (i & 127)] = w[i];
    for (int i = t; i < 32 * 128; i += 256) {
        int r = i >> 7, k = i & 127;
        hst[k * 36 + r] = h[(size_t)(r0 + r) * Hdim + k];
    }
    __syncthreads();
    int o = t & 63, q = t >> 6;
    float acc[8];
    float bo = b[o];
#pragma unroll
    for (int j = 0; j < 8; j++) acc[j] = bo;
    for (int k = 0; k < 128; k++) {
        float wv = ws[o * 129 + k];
        float4 ha = *(const float4*)&hst[k * 36 + q * 8];
        float4 hb = *(const float4*)&hst[k * 36 + q * 8 + 4];
        acc[0] += wv * ha.x; acc[1] += wv * ha.y; acc[2] += wv * ha.z; acc[3] += wv * ha.w;
        acc[4] += wv * hb.x; acc[5] += wv * hb.y; acc[6] += wv * hb.z; acc[7] += wv * hb.w;
    }
#pragma unroll
    for (int j = 0; j < 8; j++) out[(size_t)(r0 + q * 8 + j) * 64 + o] = acc[j];
}

extern "C" void kernel_launch(void* const* d_in, const int* in_sizes, int n_in,
                              void* d_out, int out_size, void* d_ws, size_t ws_size,
                              hipStream_t stream) {
    const float* x      = (const float*)d_in[0];
    const float* enc_w  = (const float*)d_in[2];
    const float* enc_b  = (const float*)d_in[3];
    const float* dec_w  = (const float*)d_in[4];
    const float* dec_b  = (const float*)d_in[5];
    const float* lam_re = (const float*)d_in[6];
    const float* lam_im = (const float*)d_in[7];
    const float* p_re   = (const float*)d_in[8];
    const float* p_im   = (const float*)d_in[9];
    const float* b_re   = (const float*)d_in[10];
    const float* b_im   = (const float*)d_in[11];
    const float* c_re   = (const float*)d_in[12];
    const float* c_im   = (const float*)d_in[13];
    const float* dvec   = (const float*)d_in[14];
    const float* lstep  = (const float*)d_in[15];
    const float* norm_w = (const float*)d_in[16];
    const float* norm_b = (const float*)d_in[17];
    const float* w1     = (const float*)d_in[18];
    const float* b1     = (const float*)d_in[19];
    const float* w2     = (const float*)d_in[20];
    const float* b2     = (const float*)d_in[21];
    float* out = (float*)d_out;

    char* ws = (char*)d_ws;
    float2* tw  = (float2*)ws;  ws += 2048 * sizeof(float2);
    float*  h   = (float*)ws;   ws += (size_t)Bsz * Lseq * Hdim * sizeof(float);
    float*  hnT = (float*)ws;   ws += (size_t)Bsz * Lseq * Hdim * sizeof(float);
    float2* atr = (float2*)ws;  ws += (size_t)NLAYERS * Hdim * Lseq * sizeof(float2);
    float4* Kd2 = (float4*)ws;  ws += (size_t)NLAYERS * (Hdim / 2) * 4096 * sizeof(float4);

    const int nrows = Bsz * Lseq;  // 16384

    twiddle_init<<<8, 256, 0, stream>>>(tw);
    spectrum_kernel<<<dim3(Hdim, NLAYERS, 2), 256, 0, stream>>>(
        lam_re, lam_im, p_re, p_im, b_re, b_im, c_re, c_im, lstep, atr);
    kfft_kernel<<<dim3(Hdim, NLAYERS), 256, 0, stream>>>(atr, Kd2, tw);
    encoder_kernel<<<nrows / 16, 256, 0, stream>>>(x, enc_w, enc_b, norm_w, norm_b, h, hnT);
    for (int L = 0; L < NLAYERS; L++) {
        conv_kernel<<<dim3(Hdim / 2, Bsz), 256, 0, stream>>>(
            hnT, Kd2 + (size_t)L * (Hdim / 2) * 4096, dvec + L * Hdim, tw);
        int do_ln = (L < NLAYERS - 1) ? 1 : 0;
        const float* nwn = norm_w + ((L + 1) % NLAYERS) * Hdim;
        const float* nbn = norm_b + ((L + 1) % NLAYERS) * Hdim;
        mlp_kernel<<<nrows / 32, 256, 0, stream>>>(hnT, h, hnT,
                                                   w1 + (size_t)L * Hdim * Hdim, b1 + L * Hdim,
                                                   w2 + (size_t)L * Hdim * Hdim, b2 + L * Hdim,
                                                   nwn, nbn, do_ln);
    }
    decoder_kernel<<<nrows / 32, 256, 0, stream>>>(h, dec_w, dec_b, out);
}

// Round 8
// 363.775 us; speedup vs baseline: 2.4509x; 1.0148x over previous
//
#include <hip/hip_runtime.h>
#include <hip/hip_bf16.h>

// S4 (DPLR) forward, B=8 L=2048 IN=OUT=64 H=128 N=64, 4 layers.
// R8: spectrum 8 l's/thread (full ILP, epilogue trig recompute, no spills);
// conv pointwise iterates even-p directly (bit-reversed domain) so LDS bank
// digit varies across lanes — kills the 16-way conflicts of the brev(f) loop.

#define Bsz 8
#define Lseq 2048
#define Hdim 128
#define Npol 64
#define NLAYERS 4

__device__ __forceinline__ float fast_rcp(float x) { return __builtin_amdgcn_rcpf(x); }
__device__ __forceinline__ float fast_rsq(float x) { return __builtin_amdgcn_rsqf(x); }

__device__ __forceinline__ float2 cmulf(float2 a, float2 b) {
    return make_float2(a.x * b.x - a.y * b.y, a.x * b.y + a.y * b.x);
}
__device__ __forceinline__ float2 cmulc(float2 a, float2 b) {  // a * conj(b)
    return make_float2(a.x * b.x + a.y * b.y, a.y * b.x - a.x * b.y);
}

__device__ __forceinline__ float gelu_f(float v) {
    float z = 0.7978845608028654f * (v + 0.044715f * v * v * v);
    float e = __expf(2.0f * z);
    return v - v * fast_rcp(e + 1.0f);
}

// XOR swizzle: mixes digit1 into the bank digit so strides 1/16/256 are all conflict-uniform.
__device__ __forceinline__ int sw(int i) { return (i & ~15) | ((i ^ (i >> 4)) & 15); }

static __device__ const float W16R[8] = {1.f, 0.9238795325f, 0.7071067812f, 0.3826834324f,
                                         0.f, -0.3826834324f, -0.7071067812f, -0.9238795325f};
static __device__ const float W16I[8] = {0.f, -0.3826834324f, -0.7071067812f, -0.9238795325f,
                                         -1.f, -0.9238795325f, -0.7071067812f, -0.3826834324f};
static __device__ const int BR4[16] = {0, 8, 4, 12, 2, 10, 6, 14, 1, 9, 5, 13, 3, 11, 7, 15};
static __device__ const int BR3[8] = {0, 4, 2, 6, 1, 5, 3, 7};

__device__ __forceinline__ float2 twget(const float2* __restrict__ tw, int e) {
    float2 w = tw[e & 2047];
    if (e & 2048) { w.x = -w.x; w.y = -w.y; }
    return w;
}

template <bool INV>
__device__ __forceinline__ void fft16_dif(float2 v[16]) {
#pragma unroll
    for (int mi = 0; mi < 4; mi++) {
        const int m = 8 >> mi;
#pragma unroll
        for (int g = 0; g < 16; g += 2 * m) {
#pragma unroll
            for (int j = 0; j < m; j++) {
                float wr = W16R[j << mi];
                float wi = INV ? -W16I[j << mi] : W16I[j << mi];
                float2 a = v[g + j], b = v[g + j + m];
                float dx = a.x - b.x, dy = a.y - b.y;
                v[g + j] = make_float2(a.x + b.x, a.y + b.y);
                v[g + j + m] = make_float2(dx * wr - dy * wi, dx * wi + dy * wr);
            }
        }
    }
}

template <bool INV>
__device__ __forceinline__ void fft16_dit(float2 v[16]) {
#pragma unroll
    for (int mi = 3; mi >= 0; mi--) {
        const int m = 8 >> mi;
#pragma unroll
        for (int g = 0; g < 16; g += 2 * m) {
#pragma unroll
            for (int j = 0; j < m; j++) {
                float wr = W16R[j << mi];
                float wi = INV ? -W16I[j << mi] : W16I[j << mi];
                float2 a = v[g + j], b = v[g + j + m];
                float bx = b.x * wr - b.y * wi, by = b.x * wi + b.y * wr;
                v[g + j] = make_float2(a.x + bx, a.y + by);
                v[g + j + m] = make_float2(a.x - bx, a.y - by);
            }
        }
    }
}

template <bool INV>
__device__ __forceinline__ void fft8_dif(float2 v[8]) {
#pragma unroll
    for (int mi = 0; mi < 3; mi++) {
        const int m = 4 >> mi;
#pragma unroll
        for (int g = 0; g < 8; g += 2 * m) {
#pragma unroll
            for (int j = 0; j < m; j++) {
                float wr = W16R[j << (mi + 1)];
                float wi = INV ? -W16I[j << (mi + 1)] : W16I[j << (mi + 1)];
                float2 a = v[g + j], b = v[g + j + m];
                float dx = a.x - b.x, dy = a.y - b.y;
                v[g + j] = make_float2(a.x + b.x, a.y + b.y);
                v[g + j + m] = make_float2(dx * wr - dy * wi, dx * wi + dy * wr);
            }
        }
    }
}

// Forward 4096-pt FFT in LDS, 256 threads, result in 12-bit bit-reversed positions.
// No leading barrier IF caller's fill writes exactly {t+256k, k<16} per thread.
__device__ __forceinline__ void fft4096_fwd(float2* data, const float2* __restrict__ tw, int t) {
    {
        float2 v[16];
#pragma unroll
        for (int k = 0; k < 16; k++) v[k] = data[sw(t + 256 * k)];
        fft16_dif<false>(v);
#pragma unroll
        for (int i = 1; i < 16; i++) v[i] = cmulf(v[i], twget(tw, t * BR4[i]));
#pragma unroll
        for (int i = 0; i < 16; i++) data[sw(i * 256 + t)] = v[i];
    }
    __syncthreads();
    {
        int j0 = t & 15;
        int base = (t >> 4) * 256 + j0;
        float2 v[16];
#pragma unroll
        for (int k = 0; k < 16; k++) v[k] = data[sw(base + 16 * k)];
        fft16_dif<false>(v);
#pragma unroll
        for (int i = 1; i < 16; i++) v[i] = cmulf(v[i], twget(tw, 16 * j0 * BR4[i]));
#pragma unroll
        for (int i = 0; i < 16; i++) data[sw(base + 16 * i)] = v[i];
    }
    __syncthreads();
    {
        float2 v[16];
#pragma unroll
        for (int k = 0; k < 16; k++) v[k] = data[sw(t * 16 + k)];
        fft16_dif<false>(v);
#pragma unroll
        for (int i = 0; i < 16; i++) data[sw(t * 16 + i)] = v[i];
    }
    __syncthreads();
}

// ---------------- twiddle table ----------------
__global__ __launch_bounds__(256) void twiddle_init(float2* tw) {
    int k = blockIdx.x * blockDim.x + threadIdx.x;
    if (k < 2048) {
        double a = -6.283185307179586476925286766559 * (double)k / 4096.0;
        tw[k] = make_float2((float)cos(a), (float)sin(a));
    }
}

// ---------------- encoder + fused LN: 16 rows/block; LN out -> hnT[b][h][l] ----------------
__global__ __launch_bounds__(256) void encoder_kernel(const float* __restrict__ x,
                                                      const float* __restrict__ w,
                                                      const float* __restrict__ b,
                                                      const float* __restrict__ nw,
                                                      const float* __restrict__ nb,
                                                      float* __restrict__ h,
                                                      float* __restrict__ hnT) {
    int r0 = blockIdx.x * 16;
    int t = threadIdx.x;
    __shared__ float ws[128 * 65];
    __shared__ __align__(16) float xst[64 * 20];
    __shared__ float dots[16 * 128];
    __shared__ float2 mv[16];
    for (int i = t; i < 128 * 64; i += 256) ws[(i >> 6) * 65 + (i & 63)] = w[i];
    for (int i = t; i < 16 * 64; i += 256) {
        int r = i >> 6, k = i & 63;
        xst[k * 20 + r] = x[(size_t)(r0 + r) * 64 + k];
    }
    __syncthreads();
    int o = t & 127, half = t >> 7;
    float acc[8];
    float bo = b[o];
#pragma unroll
    for (int j = 0; j < 8; j++) acc[j] = bo;
    for (int k = 0; k < 64; k++) {
        float wv = ws[o * 65 + k];
        float4 xa = *(const float4*)&xst[k * 20 + half * 8];
        float4 xb = *(const float4*)&xst[k * 20 + half * 8 + 4];
        acc[0] += wv * xa.x; acc[1] += wv * xa.y; acc[2] += wv * xa.z; acc[3] += wv * xa.w;
        acc[4] += wv * xb.x; acc[5] += wv * xb.y; acc[6] += wv * xb.z; acc[7] += wv * xb.w;
    }
#pragma unroll
    for (int j = 0; j < 8; j++) dots[(half * 8 + j) * 128 + o] = acc[j];
    __syncthreads();
    {
        int row = t >> 4, lane = t & 15;
        float s1 = 0.f, s2 = 0.f;
#pragma unroll
        for (int i = 0; i < 8; i++) {
            float v = dots[row * 128 + lane * 8 + i];
            s1 += v; s2 += v * v;
        }
#pragma unroll
        for (int m = 1; m < 16; m <<= 1) { s1 += __shfl_xor(s1, m); s2 += __shfl_xor(s2, m); }
        if (lane == 0) {
            float mu = s1 * (1.0f / 128.0f);
            float var = s2 * (1.0f / 128.0f) - mu * mu;
            mv[row] = make_float2(mu, fast_rsq(var + 1e-5f));
        }
    }
    __syncthreads();
    int c = t & 127;
    int bb = r0 >> 11, l0 = r0 & 2047;
    float nwc = nw[c], nbc = nb[c];
    float hnv[8];
#pragma unroll
    for (int j = 0; j < 8; j++) {
        int r = half * 8 + j;
        float v = dots[r * 128 + c];
        h[(size_t)(r0 + r) * Hdim + c] = v;
        float2 m = mv[r];
        hnv[j] = (v - m.x) * m.y * nwc + nbc;
    }
    float* dst = hnT + ((size_t)bb * Hdim + c) * Lseq + l0 + half * 8;
    *(float4*)dst = make_float4(hnv[0], hnv[1], hnv[2], hnv[3]);
    *(float4*)(dst + 4) = make_float4(hnv[4], hnv[5], hnv[6], hnv[7]);
}

// ---------------- DPLR generating function: 8 l's per thread, fmaf chains ----------------
__global__ __launch_bounds__(256, 2) void spectrum_kernel(const float* __restrict__ lam_re,
                                                          const float* __restrict__ lam_im,
                                                          const float* __restrict__ p_re,
                                                          const float* __restrict__ p_im,
                                                          const float* __restrict__ b_re,
                                                          const float* __restrict__ b_im,
                                                          const float* __restrict__ c_re,
                                                          const float* __restrict__ c_im,
                                                          const float* __restrict__ log_step,
                                                          float2* __restrict__ at_roots) {
    int h = blockIdx.x, layer = blockIdx.y, t = threadIdx.x;
    __shared__ __align__(16) float4 polA[Npol];  // (lam.re, lam.im, n00.re, n00.im)
    __shared__ __align__(16) float4 polB[Npol];  // (n01.re, n01.im, n10.re, n10.im)
    __shared__ float n11S[Npol];
    int baseP = (layer * Hdim + h) * Npol;
    if (t < Npol) {
        int n = t;
        float lr = lam_re[baseP + n], li = lam_im[baseP + n];
        float pr = p_re[baseP + n], pi = p_im[baseP + n];
        float br = b_re[baseP + n], bi = b_im[baseP + n];
        float cr = c_re[baseP + n], ci = c_im[baseP + n];
        polA[n] = make_float4(lr, li, cr * br + ci * bi, cr * bi - ci * br);
        polB[n] = make_float4(cr * pr + ci * pi, cr * pi - ci * pr,
                              pr * br + pi * bi, pr * bi - pi * br);
        n11S[n] = pr * pr + pi * pi;
    }
    __syncthreads();
    float step = expf(log_step[layer * Hdim + h]);
    float gs = 2.0f / step;

    float gr[8], gi[8];
#pragma unroll
    for (int j = 0; j < 8; j++) {
        int l = t + 256 * j;
        float ang = -6.283185307179586f * (float)l / (float)Lseq;
        float wr = cosf(ang), wi = sinf(ang);  // fp32 omega on purpose: keeps |g|^2 in range
        float dr = 1.0f + wr, di = wi;
        float invd2 = fast_rcp(dr * dr + di * di);
        float nr = 1.0f - wr, ni = -wi;
        gr[j] = gs * (nr * dr + ni * di) * invd2;
        gi[j] = gs * (ni * dr - nr * di) * invd2;
    }
    float k00x[8] = {0, 0, 0, 0, 0, 0, 0, 0}, k00y[8] = {0, 0, 0, 0, 0, 0, 0, 0};
    float k01x[8] = {0, 0, 0, 0, 0, 0, 0, 0}, k01y[8] = {0, 0, 0, 0, 0, 0, 0, 0};
    float k10x[8] = {0, 0, 0, 0, 0, 0, 0, 0}, k10y[8] = {0, 0, 0, 0, 0, 0, 0, 0};
    float k11x[8] = {0, 0, 0, 0, 0, 0, 0, 0}, k11y[8] = {0, 0, 0, 0, 0, 0, 0, 0};
#pragma unroll 2
    for (int n = 0; n < Npol; n++) {
        float4 A = polA[n];  // b128 broadcast
        float4 B = polB[n];
        float n11 = n11S[n];
#pragma unroll
        for (int j = 0; j < 8; j++) {
            float er = gr[j] - A.x, ei = gi[j] - A.y;
            float inv2 = fast_rcp(fmaf(er, er, ei * ei));
            float ir = er * inv2;
            float mi = ei * inv2;  // = -Im(1/(g-lam))
            k00x[j] = fmaf(A.z, ir, fmaf(A.w, mi, k00x[j]));
            k00y[j] = fmaf(A.w, ir, fmaf(-A.z, mi, k00y[j]));
            k01x[j] = fmaf(B.x, ir, fmaf(B.y, mi, k01x[j]));
            k01y[j] = fmaf(B.y, ir, fmaf(-B.x, mi, k01y[j]));
            k10x[j] = fmaf(B.z, ir, fmaf(B.w, mi, k10x[j]));
            k10y[j] = fmaf(B.w, ir, fmaf(-B.z, mi, k10y[j]));
            k11x[j] = fmaf(n11, ir, k11x[j]);
            k11y[j] = fmaf(-n11, mi, k11y[j]);
        }
    }
#pragma unroll
    for (int j = 0; j < 8; j++) {
        int l = t + 256 * j;
        float ang = -6.283185307179586f * (float)l / (float)Lseq;
        float wr = cosf(ang), wi = sinf(ang);  // recompute (saves 16 VGPRs over caching)
        float dr = 1.0f + wr, di = wi;
        float invd2 = fast_rcp(dr * dr + di * di);
        float cr2 = 2.0f * dr * invd2, ci2 = -2.0f * di * invd2;
        float wr2 = 1.0f + k11x[j], wi2 = k11y[j];
        float w2inv = fast_rcp(fmaf(wr2, wr2, wi2 * wi2));
        float vr = wr2 * w2inv, vi = -wi2 * w2inv;
        float t1x = k01x[j] * k10x[j] - k01y[j] * k10y[j];
        float t1y = k01x[j] * k10y[j] + k01y[j] * k10x[j];
        float t2x = t1x * vr - t1y * vi, t2y = t1x * vi + t1y * vr;
        float ex = k00x[j] - t2x, ey = k00y[j] - t2y;
        at_roots[((size_t)layer * Hdim + h) * Lseq + l] =
            make_float2(cr2 * ex - ci2 * ey, cr2 * ey + ci2 * ex);
    }
}

// ---------------- kernel FFT: ifft2048 -> pad -> fft4096, all layers ----------------
// Kd2 layout: [layer][hp][p] float4 = (K_{2hp}[p].re,.im, K_{2hp+1}[p].re,.im), p bit-rev.
__global__ __launch_bounds__(256) void kfft_kernel(const float2* __restrict__ at_roots,
                                                   float4* __restrict__ Kd2,
                                                   const float2* __restrict__ tw) {
    int h = blockIdx.x, layer = blockIdx.y, t = threadIdx.x;
    __shared__ float2 data[4096];
    __shared__ float ktmp[2048];
    const float2* src = at_roots + ((size_t)layer * Hdim + h) * Lseq;
#pragma unroll
    for (int k = 0; k < 8; k++) {
        int l = t + 256 * k;
        data[sw(l)] = src[l];
    }
    __syncthreads();
    // inverse 2048-pt (conjugated DIF), digits 16 x 16 x 8
    if (t < 128) {
        float2 v[16];
#pragma unroll
        for (int k = 0; k < 16; k++) v[k] = data[sw(t + 128 * k)];
        fft16_dif<true>(v);
#pragma unroll
        for (int i = 1; i < 16; i++) v[i] = cmulc(v[i], twget(tw, 2 * t * BR4[i]));
#pragma unroll
        for (int i = 0; i < 16; i++) data[sw(i * 128 + t)] = v[i];
    }
    __syncthreads();
    if (t < 128) {
        int i2 = t >> 3, j0 = t & 7;
        int base2 = i2 * 128 + j0;
        float2 v[16];
#pragma unroll
        for (int k = 0; k < 16; k++) v[k] = data[sw(base2 + 8 * k)];
        fft16_dif<true>(v);
#pragma unroll
        for (int i = 1; i < 16; i++) v[i] = cmulc(v[i], twget(tw, 32 * j0 * BR4[i]));
#pragma unroll
        for (int i = 0; i < 16; i++) data[sw(base2 + 8 * i)] = v[i];
    }
    __syncthreads();
    {
        float2 v8[8];
#pragma unroll
        for (int k = 0; k < 8; k++) v8[k] = data[sw(t * 8 + k)];
        fft8_dif<true>(v8);
        int r = BR4[t >> 4], s = BR4[t & 15];
#pragma unroll
        for (int i = 0; i < 8; i++) {
            int l = r + 16 * s + 256 * BR3[i];
            ktmp[l] = v8[i].x * (1.0f / 2048.0f);
        }
    }
    __syncthreads();
#pragma unroll
    for (int k = 0; k < 8; k++) {
        int l = t + 256 * k;
        data[sw(l)] = make_float2(ktmp[l], 0.f);
        data[sw(l + 2048)] = make_float2(0.f, 0.f);
    }
    fft4096_fwd(data, tw, t);
    float2* dst = (float2*)(Kd2 + ((size_t)layer * 64 + (h >> 1)) * 4096);
    int half = h & 1;
#pragma unroll
    for (int k = 0; k < 16; k++) {
        int p = t + 256 * k;
        dst[2 * p + half] = data[sw(p)];
    }
}

// ---------------- FFT convolution + D-skip + gelu, channel pair per block ----------------
// hnT layout: [b][h][l]. Pointwise iterates EVEN p (bit-reversed domain) so the
// lane-varying bits land in p's low bits -> conflict-optimal LDS access.
__global__ __launch_bounds__(256) void conv_kernel(float* __restrict__ hnT,
                                                   const float4* __restrict__ Kd2,
                                                   const float* __restrict__ dvec,
                                                   const float2* __restrict__ tw) {
    int hp = blockIdx.x, b = blockIdx.y, h0 = hp * 2, t = threadIdx.x;
    __shared__ float2 data[4096];
    float* u0 = hnT + ((size_t)b * Hdim + h0) * Lseq;
    float* u1 = u0 + Lseq;
    float2 ureg[8];
#pragma unroll
    for (int k = 0; k < 8; k++) {
        int l = t + 256 * k;
        float2 u2 = make_float2(u0[l], u1[l]);
        ureg[k] = u2;
        data[sw(l)] = u2;
        data[sw(l + 2048)] = make_float2(0.f, 0.f);
    }
    fft4096_fwd(data, tw, t);
    const float4* Kp = Kd2 + (size_t)hp * 4096;
    const float scale = 1.0f / 4096.0f;
#pragma unroll
    for (int k = 0; k < 8; k++) {
        int p = 2 * (t + 256 * k);                // even p <-> f in [0, 2048)
        int f = __brev((unsigned)p) >> 20;
        int fm = (4096 - f) & 4095;
        int pm = __brev((unsigned)fm) >> 20;      // odd (or 0 when f==0)
        float2 Zf = data[sw(p)], Zm = data[sw(pm)];
        float2 U0 = make_float2(0.5f * (Zf.x + Zm.x), 0.5f * (Zf.y - Zm.y));
        float2 Dm = make_float2(Zf.x - Zm.x, Zf.y + Zm.y);
        float2 U1 = make_float2(0.5f * Dm.y, -0.5f * Dm.x);
        float4 Ka = Kp[p];
        float2 S0 = cmulf(U0, make_float2(Ka.x, Ka.y));
        float2 S1 = cmulf(U1, make_float2(Ka.z, Ka.w));
        float2 Wf = make_float2((S0.x - S1.y) * scale, (S0.y + S1.x) * scale);
        float4 Kb = Kp[pm];
        float2 U0m = make_float2(U0.x, -U0.y);
        float2 U1m = make_float2(U1.x, -U1.y);
        float2 S0m = cmulf(U0m, make_float2(Kb.x, Kb.y));
        float2 S1m = cmulf(U1m, make_float2(Kb.z, Kb.w));
        float2 Wm = make_float2((S0m.x - S1m.y) * scale, (S0m.y + S1m.x) * scale);
        data[sw(p)] = Wf;
        if (pm != p) data[sw(pm)] = Wm;
    }
    if (t == 0) {  // f = 2048 self-pair: p = pm = brev(2048) = 1
        float2 Zf = data[sw(1)];
        float2 U0 = make_float2(Zf.x, 0.f);
        float2 U1 = make_float2(Zf.y, 0.f);
        float4 Ka = Kp[1];
        float2 S0 = cmulf(U0, make_float2(Ka.x, Ka.y));
        float2 S1 = cmulf(U1, make_float2(Ka.z, Ka.w));
        data[sw(1)] = make_float2((S0.x - S1.y) * scale, (S0.y + S1.x) * scale);
    }
    __syncthreads();
    {
        float2 v[16];
#pragma unroll
        for (int i = 0; i < 16; i++) v[i] = data[sw(t * 16 + i)];
        fft16_dit<true>(v);
#pragma unroll
        for (int i = 0; i < 16; i++) data[sw(t * 16 + i)] = v[i];
    }
    __syncthreads();
    {
        int j0 = t & 15;
        int base2 = (t >> 4) * 256 + j0;
        float2 v[16];
        v[0] = data[sw(base2)];
#pragma unroll
        for (int i = 1; i < 16; i++)
            v[i] = cmulc(data[sw(base2 + 16 * i)], twget(tw, 16 * j0 * BR4[i]));
        fft16_dit<true>(v);
#pragma unroll
        for (int i = 0; i < 16; i++) data[sw(base2 + 16 * i)] = v[i];
    }
    __syncthreads();
    {
        float2 v[16];
        v[0] = data[sw(t)];
#pragma unroll
        for (int i = 1; i < 16; i++)
            v[i] = cmulc(data[sw(i * 256 + t)], twget(tw, t * BR4[i]));
        fft16_dit<true>(v);
        float d0 = dvec[h0], d1 = dvec[h0 + 1];
#pragma unroll
        for (int k = 0; k < 8; k++) {
            int l = t + 256 * k;
            u0[l] = gelu_f(v[k].x + ureg[k].x * d0);
            u1[l] = gelu_f(v[k].y + ureg[k].y * d1);
        }
    }
}

// ---------------- gated MLP + residual + fused next-layer LN: 32 rows/block ----------------
__global__ __launch_bounds__(256) void mlp_kernel(const float* __restrict__ yT,
                                                  float* __restrict__ h,
                                                  float* __restrict__ hnT,
                                                  const float* __restrict__ w1,
                                                  const float* __restrict__ b1,
                                                  const float* __restrict__ w2,
                                                  const float* __restrict__ b2,
                                                  const float* __restrict__ nw,
                                                  const float* __restrict__ nb,
                                                  int do_ln) {
    const int ROWS = 32;
    int r0 = blockIdx.x * ROWS;
    int t = threadIdx.x;
    __shared__ __align__(16) float yst[128 * 36];  // y^T [k][r], pad 36
    __shared__ float wst[2 * 128 * 17];            // w chunk; aliased as dots later
    __shared__ float2 mv[32];
    float* dots = wst;                             // 32*132 = 4224 <= 4352 floats

    int bb = r0 >> 11, l0 = r0 & 2047;
    for (int i = t; i < 128 * ROWS; i += 256) {
        int k = i >> 5, r = i & 31;                // lanes consecutive in r -> coalesced in l
        yst[k * 36 + r] = yT[((size_t)bb * Hdim + k) * Lseq + l0 + r];
    }
    int o = t & 127, rh = t >> 7;
    float acc1[16], acc2[16];
    float bias1 = b1[o], bias2 = b2[o];
#pragma unroll
    for (int j = 0; j < 16; j++) { acc1[j] = bias1; acc2[j] = bias2; }

    float pf[16];
#pragma unroll
    for (int j = 0; j < 16; j++) {
        int e = t + 256 * j;
        int mat = e >> 11, rem = e & 2047, oo = rem >> 4, kk = rem & 15;
        pf[j] = (mat ? w2 : w1)[(size_t)oo * Hdim + kk];
    }
    for (int kc0 = 0; kc0 < 128; kc0 += 16) {
        __syncthreads();
#pragma unroll
        for (int j = 0; j < 16; j++) {
            int e = t + 256 * j;
            int mat = e >> 11, rem = e & 2047, oo = rem >> 4, kk = rem & 15;
            wst[mat * 2176 + oo * 17 + kk] = pf[j];
        }
        __syncthreads();
        if (kc0 + 16 < 128) {
#pragma unroll
            for (int j = 0; j < 16; j++) {
                int e = t + 256 * j;
                int mat = e >> 11, rem = e & 2047, oo = rem >> 4, kk = rem & 15;
                pf[j] = (mat ? w2 : w1)[(size_t)oo * Hdim + kc0 + 16 + kk];
            }
        }
#pragma unroll
        for (int k = 0; k < 16; k++) {
            float wv1 = wst[o * 17 + k];
            float wv2 = wst[2176 + o * 17 + k];
            int kk = (kc0 + k) * 36 + rh * 16;
            float4 ya = *(const float4*)&yst[kk];
            float4 yb = *(const float4*)&yst[kk + 4];
            float4 yc = *(const float4*)&yst[kk + 8];
            float4 yd = *(const float4*)&yst[kk + 12];
            acc1[0]  = fmaf(wv1, ya.x, acc1[0]);  acc2[0]  = fmaf(wv2, ya.x, acc2[0]);
            acc1[1]  = fmaf(wv1, ya.y, acc1[1]);  acc2[1]  = fmaf(wv2, ya.y, acc2[1]);
            acc1[2]  = fmaf(wv1, ya.z, acc1[2]);  acc2[2]  = fmaf(wv2, ya.z, acc2[2]);
            acc1[3]  = fmaf(wv1, ya.w, acc1[3]);  acc2[3]  = fmaf(wv2, ya.w, acc2[3]);
            acc1[4]  = fmaf(wv1, yb.x, acc1[4]);  acc2[4]  = fmaf(wv2, yb.x, acc2[4]);
            acc1[5]  = fmaf(wv1, yb.y, acc1[5]);  acc2[5]  = fmaf(wv2, yb.y, acc2[5]);
            acc1[6]  = fmaf(wv1, yb.z, acc1[6]);  acc2[6]  = fmaf(wv2, yb.z, acc2[6]);
            acc1[7]  = fmaf(wv1, yb.w, acc1[7]);  acc2[7]  = fmaf(wv2, yb.w, acc2[7]);
            acc1[8]  = fmaf(wv1, yc.x, acc1[8]);  acc2[8]  = fmaf(wv2, yc.x, acc2[8]);
            acc1[9]  = fmaf(wv1, yc.y, acc1[9]);  acc2[9]  = fmaf(wv2, yc.y, acc2[9]);
            acc1[10] = fmaf(wv1, yc.z, acc1[10]); acc2[10] = fmaf(wv2, yc.z, acc2[10]);
            acc1[11] = fmaf(wv1, yc.w, acc1[11]); acc2[11] = fmaf(wv2, yc.w, acc2[11]);
            acc1[12] = fmaf(wv1, yd.x, acc1[12]); acc2[12] = fmaf(wv2, yd.x, acc2[12]);
            acc1[13] = fmaf(wv1, yd.y, acc1[13]); acc2[13] = fmaf(wv2, yd.y, acc2[13]);
            acc1[14] = fmaf(wv1, yd.z, acc1[14]); acc2[14] = fmaf(wv2, yd.z, acc2[14]);
            acc1[15] = fmaf(wv1, yd.w, acc1[15]); acc2[15] = fmaf(wv2, yd.w, acc2[15]);
        }
    }
    __syncthreads();  // wst dead -> reuse as dots
    float hv[16];
#pragma unroll
    for (int j = 0; j < 16; j++) {
        int r = rh * 16 + j;
        float g = fast_rcp(1.0f + __expf(-acc2[j]));
        hv[j] = h[(size_t)(r0 + r) * Hdim + o] + acc1[j] * g;
        dots[r * 132 + o] = hv[j];
    }
    __syncthreads();
    if (do_ln) {
        int row = t >> 3, lane = t & 7;  // 8 lanes per row, 16 vals each
        float s1 = 0.f, s2 = 0.f;
        int base = row * 132 + lane * 16;
#pragma unroll
        for (int q = 0; q < 4; q++) {
            float4 v4 = *(const float4*)&dots[base + 4 * q];
            s1 += v4.x + v4.y + v4.z + v4.w;
            s2 += v4.x * v4.x + v4.y * v4.y + v4.z * v4.z + v4.w * v4.w;
        }
#pragma unroll
        for (int m = 1; m < 8; m <<= 1) { s1 += __shfl_xor(s1, m); s2 += __shfl_xor(s2, m); }
        if (lane == 0) {
            float mu = s1 * (1.0f / 128.0f);
            float var = s2 * (1.0f / 128.0f) - mu * mu;
            mv[row] = make_float2(mu, fast_rsq(var + 1e-5f));
        }
        __syncthreads();
        float nwc = nw[o], nbc = nb[o];
        float hnv[16];
#pragma unroll
        for (int j = 0; j < 16; j++) {
            int r = rh * 16 + j;
            h[(size_t)(r0 + r) * Hdim + o] = hv[j];
            float2 m = mv[r];
            hnv[j] = (hv[j] - m.x) * m.y * nwc + nbc;
        }
        float* dst = hnT + ((size_t)bb * Hdim + o) * Lseq + l0 + rh * 16;
        *(float4*)(dst)      = make_float4(hnv[0],  hnv[1],  hnv[2],  hnv[3]);
        *(float4*)(dst + 4)  = make_float4(hnv[4],  hnv[5],  hnv[6],  hnv[7]);
        *(float4*)(dst + 8)  = make_float4(hnv[8],  hnv[9],  hnv[10], hnv[11]);
        *(float4*)(dst + 12) = make_float4(hnv[12], hnv[13], hnv[14], hnv[15]);
    } else {
#pragma unroll
        for (int j = 0; j < 16; j++) {
            int r = rh * 16 + j;
            h[(size_t)(r0 + r) * Hdim + o] = hv[j];
        }
    }
}

// ---------------- decoder: 32 rows/block ----------------
__global__ __launch_bounds__(256) void decoder_kernel(const float* __restrict__ h,
                                                      const float* __restrict__ w,
                                                      const float* __restrict__ b,
                                                      float* __restrict__ out) {
    int r0 = blockIdx.x * 32;
    int t = threadIdx.x;
    __shared__ float ws[64 * 129];
    __shared__ __align__(16) float hst[128 * 36];
    for (int i = t; i < 64 * 128; i += 256) ws[(i >> 7) * 129 + (i & 127)] = w[i];
    for (int i = t; i < 32 * 128; i += 256) {
        int r = i >> 7, k = i & 127;
        hst[k * 36 + r] = h[(size_t)(r0 + r) * Hdim + k];
    }
    __syncthreads();
    int o = t & 63, q = t >> 6;
    float acc[8];
    float bo = b[o];
#pragma unroll
    for (int j = 0; j < 8; j++) acc[j] = bo;
    for (int k = 0; k < 128; k++) {
        float wv = ws[o * 129 + k];
        float4 ha = *(const float4*)&hst[k * 36 + q * 8];
        float4 hb = *(const float4*)&hst[k * 36 + q * 8 + 4];
        acc[0] += wv * ha.x; acc[1] += wv * ha.y; acc[2] += wv * ha.z; acc[3] += wv * ha.w;
        acc[4] += wv * hb.x; acc[5] += wv * hb.y; acc[6] += wv * hb.z; acc[7] += wv * hb.w;
    }
#pragma unroll
    for (int j = 0; j < 8; j++) out[(size_t)(r0 + q * 8 + j) * 64 + o] = acc[j];
}

extern "C" void kernel_launch(void* const* d_in, const int* in_sizes, int n_in,
                              void* d_out, int out_size, void* d_ws, size_t ws_size,
                              hipStream_t stream) {
    const float* x      = (const float*)d_in[0];
    const float* enc_w  = (const float*)d_in[2];
    const float* enc_b  = (const float*)d_in[3];
    const float* dec_w  = (const float*)d_in[4];
    const float* dec_b  = (const float*)d_in[5];
    const float* lam_re = (const float*)d_in[6];
    const float* lam_im = (const float*)d_in[7];
    const float* p_re   = (const float*)d_in[8];
    const float* p_im   = (const float*)d_in[9];
    const float* b_re   = (const float*)d_in[10];
    const float* b_im   = (const float*)d_in[11];
    const float* c_re   = (const float*)d_in[12];
    const float* c_im   = (const float*)d_in[13];
    const float* dvec   = (const float*)d_in[14];
    const float* lstep  = (const float*)d_in[15];
    const float* norm_w = (const float*)d_in[16];
    const float* norm_b = (const float*)d_in[17];
    const float* w1     = (const float*)d_in[18];
    const float* b1     = (const float*)d_in[19];
    const float* w2     = (const float*)d_in[20];
    const float* b2     = (const float*)d_in[21];
    float* out = (float*)d_out;

    char* ws = (char*)d_ws;
    float2* tw  = (float2*)ws;  ws += 2048 * sizeof(float2);
    float*  h   = (float*)ws;   ws += (size_t)Bsz * Lseq * Hdim * sizeof(float);
    float*  hnT = (float*)ws;   ws += (size_t)Bsz * Lseq * Hdim * sizeof(float);
    float2* atr = (float2*)ws;  ws += (size_t)NLAYERS * Hdim * Lseq * sizeof(float2);
    float4* Kd2 = (float4*)ws;  ws += (size_t)NLAYERS * (Hdim / 2) * 4096 * sizeof(float4);

    const int nrows = Bsz * Lseq;  // 16384

    twiddle_init<<<8, 256, 0, stream>>>(tw);
    spectrum_kernel<<<dim3(Hdim, NLAYERS), 256, 0, stream>>>(
        lam_re, lam_im, p_re, p_im, b_re, b_im, c_re, c_im, lstep, atr);
    kfft_kernel<<<dim3(Hdim, NLAYERS), 256, 0, stream>>>(atr, Kd2, tw);
    encoder_kernel<<<nrows / 16, 256, 0, stream>>>(x, enc_w, enc_b, norm_w, norm_b, h, hnT);
    for (int L = 0; L < NLAYERS; L++) {
        conv_kernel<<<dim3(Hdim / 2, Bsz), 256, 0, stream>>>(
            hnT, Kd2 + (size_t)L * (Hdim / 2) * 4096, dvec + L * Hdim, tw);
        int do_ln = (L < NLAYERS - 1) ? 1 : 0;
        const float* nwn = norm_w + ((L + 1) % NLAYERS) * Hdim;
        const float* nbn = norm_b + ((L + 1) % NLAYERS) * Hdim;
        mlp_kernel<<<nrows / 32, 256, 0, stream>>>(hnT, h, hnT,
                                                   w1 + (size_t)L * Hdim * Hdim, b1 + L * Hdim,
                                                   w2 + (size_t)L * Hdim * Hdim, b2 + L * Hdim,
                                                   nwn, nbn, do_ln);
    }
    decoder_kernel<<<nrows / 32, 256, 0, stream>>>(h, dec_w, dec_b, out);
}

// Round 9
// 363.596 us; speedup vs baseline: 2.4521x; 1.0005x over previous
//
#include <hip/hip_runtime.h>
#include <hip/hip_bf16.h>

// S4 (DPLR) forward, B=8 L=2048 IN=OUT=64 H=128 N=64, 4 layers.
// R9: spectrum back to high block count (2048 blocks, 2 l/thread) with the lean
// float4/fmaf inner loop. Evidence: VALUBusy tracks block count monotonically
// (R4 2048blk=80%, R5 1024=62%, R8 512=57%) — latency-bound, needs waves.

#define Bsz 8
#define Lseq 2048
#define Hdim 128
#define Npol 64
#define NLAYERS 4

__device__ __forceinline__ float fast_rcp(float x) { return __builtin_amdgcn_rcpf(x); }
__device__ __forceinline__ float fast_rsq(float x) { return __builtin_amdgcn_rsqf(x); }

__device__ __forceinline__ float2 cmulf(float2 a, float2 b) {
    return make_float2(a.x * b.x - a.y * b.y, a.x * b.y + a.y * b.x);
}
__device__ __forceinline__ float2 cmulc(float2 a, float2 b) {  // a * conj(b)
    return make_float2(a.x * b.x + a.y * b.y, a.y * b.x - a.x * b.y);
}

__device__ __forceinline__ float gelu_f(float v) {
    float z = 0.7978845608028654f * (v + 0.044715f * v * v * v);
    float e = __expf(2.0f * z);
    return v - v * fast_rcp(e + 1.0f);
}

// XOR swizzle: mixes digit1 into the bank digit so strides 1/16/256 are all conflict-uniform.
__device__ __forceinline__ int sw(int i) { return (i & ~15) | ((i ^ (i >> 4)) & 15); }

static __device__ const float W16R[8] = {1.f, 0.9238795325f, 0.7071067812f, 0.3826834324f,
                                         0.f, -0.3826834324f, -0.7071067812f, -0.9238795325f};
static __device__ const float W16I[8] = {0.f, -0.3826834324f, -0.7071067812f, -0.9238795325f,
                                         -1.f, -0.9238795325f, -0.7071067812f, -0.3826834324f};
static __device__ const int BR4[16] = {0, 8, 4, 12, 2, 10, 6, 14, 1, 9, 5, 13, 3, 11, 7, 15};
static __device__ const int BR3[8] = {0, 4, 2, 6, 1, 5, 3, 7};

__device__ __forceinline__ float2 twget(const float2* __restrict__ tw, int e) {
    float2 w = tw[e & 2047];
    if (e & 2048) { w.x = -w.x; w.y = -w.y; }
    return w;
}

template <bool INV>
__device__ __forceinline__ void fft16_dif(float2 v[16]) {
#pragma unroll
    for (int mi = 0; mi < 4; mi++) {
        const int m = 8 >> mi;
#pragma unroll
        for (int g = 0; g < 16; g += 2 * m) {
#pragma unroll
            for (int j = 0; j < m; j++) {
                float wr = W16R[j << mi];
                float wi = INV ? -W16I[j << mi] : W16I[j << mi];
                float2 a = v[g + j], b = v[g + j + m];
                float dx = a.x - b.x, dy = a.y - b.y;
                v[g + j] = make_float2(a.x + b.x, a.y + b.y);
                v[g + j + m] = make_float2(dx * wr - dy * wi, dx * wi + dy * wr);
            }
        }
    }
}

template <bool INV>
__device__ __forceinline__ void fft16_dit(float2 v[16]) {
#pragma unroll
    for (int mi = 3; mi >= 0; mi--) {
        const int m = 8 >> mi;
#pragma unroll
        for (int g = 0; g < 16; g += 2 * m) {
#pragma unroll
            for (int j = 0; j < m; j++) {
                float wr = W16R[j << mi];
                float wi = INV ? -W16I[j << mi] : W16I[j << mi];
                float2 a = v[g + j], b = v[g + j + m];
                float bx = b.x * wr - b.y * wi, by = b.x * wi + b.y * wr;
                v[g + j] = make_float2(a.x + bx, a.y + by);
                v[g + j + m] = make_float2(a.x - bx, a.y - by);
            }
        }
    }
}

template <bool INV>
__device__ __forceinline__ void fft8_dif(float2 v[8]) {
#pragma unroll
    for (int mi = 0; mi < 3; mi++) {
        const int m = 4 >> mi;
#pragma unroll
        for (int g = 0; g < 8; g += 2 * m) {
#pragma unroll
            for (int j = 0; j < m; j++) {
                float wr = W16R[j << (mi + 1)];
                float wi = INV ? -W16I[j << (mi + 1)] : W16I[j << (mi + 1)];
                float2 a = v[g + j], b = v[g + j + m];
                float dx = a.x - b.x, dy = a.y - b.y;
                v[g + j] = make_float2(a.x + b.x, a.y + b.y);
                v[g + j + m] = make_float2(dx * wr - dy * wi, dx * wi + dy * wr);
            }
        }
    }
}

// Forward 4096-pt FFT in LDS, 256 threads, result in 12-bit bit-reversed positions.
// No leading barrier IF caller's fill writes exactly {t+256k, k<16} per thread.
__device__ __forceinline__ void fft4096_fwd(float2* data, const float2* __restrict__ tw, int t) {
    {
        float2 v[16];
#pragma unroll
        for (int k = 0; k < 16; k++) v[k] = data[sw(t + 256 * k)];
        fft16_dif<false>(v);
#pragma unroll
        for (int i = 1; i < 16; i++) v[i] = cmulf(v[i], twget(tw, t * BR4[i]));
#pragma unroll
        for (int i = 0; i < 16; i++) data[sw(i * 256 + t)] = v[i];
    }
    __syncthreads();
    {
        int j0 = t & 15;
        int base = (t >> 4) * 256 + j0;
        float2 v[16];
#pragma unroll
        for (int k = 0; k < 16; k++) v[k] = data[sw(base + 16 * k)];
        fft16_dif<false>(v);
#pragma unroll
        for (int i = 1; i < 16; i++) v[i] = cmulf(v[i], twget(tw, 16 * j0 * BR4[i]));
#pragma unroll
        for (int i = 0; i < 16; i++) data[sw(base + 16 * i)] = v[i];
    }
    __syncthreads();
    {
        float2 v[16];
#pragma unroll
        for (int k = 0; k < 16; k++) v[k] = data[sw(t * 16 + k)];
        fft16_dif<false>(v);
#pragma unroll
        for (int i = 0; i < 16; i++) data[sw(t * 16 + i)] = v[i];
    }
    __syncthreads();
}

// ---------------- twiddle table ----------------
__global__ __launch_bounds__(256) void twiddle_init(float2* tw) {
    int k = blockIdx.x * blockDim.x + threadIdx.x;
    if (k < 2048) {
        double a = -6.283185307179586476925286766559 * (double)k / 4096.0;
        tw[k] = make_float2((float)cos(a), (float)sin(a));
    }
}

// ---------------- encoder + fused LN: 16 rows/block; LN out -> hnT[b][h][l] ----------------
__global__ __launch_bounds__(256) void encoder_kernel(const float* __restrict__ x,
                                                      const float* __restrict__ w,
                                                      const float* __restrict__ b,
                                                      const float* __restrict__ nw,
                                                      const float* __restrict__ nb,
                                                      float* __restrict__ h,
                                                      float* __restrict__ hnT) {
    int r0 = blockIdx.x * 16;
    int t = threadIdx.x;
    __shared__ float ws[128 * 65];
    __shared__ __align__(16) float xst[64 * 20];
    __shared__ float dots[16 * 128];
    __shared__ float2 mv[16];
    for (int i = t; i < 128 * 64; i += 256) ws[(i >> 6) * 65 + (i & 63)] = w[i];
    for (int i = t; i < 16 * 64; i += 256) {
        int r = i >> 6, k = i & 63;
        xst[k * 20 + r] = x[(size_t)(r0 + r) * 64 + k];
    }
    __syncthreads();
    int o = t & 127, half = t >> 7;
    float acc[8];
    float bo = b[o];
#pragma unroll
    for (int j = 0; j < 8; j++) acc[j] = bo;
    for (int k = 0; k < 64; k++) {
        float wv = ws[o * 65 + k];
        float4 xa = *(const float4*)&xst[k * 20 + half * 8];
        float4 xb = *(const float4*)&xst[k * 20 + half * 8 + 4];
        acc[0] += wv * xa.x; acc[1] += wv * xa.y; acc[2] += wv * xa.z; acc[3] += wv * xa.w;
        acc[4] += wv * xb.x; acc[5] += wv * xb.y; acc[6] += wv * xb.z; acc[7] += wv * xb.w;
    }
#pragma unroll
    for (int j = 0; j < 8; j++) dots[(half * 8 + j) * 128 + o] = acc[j];
    __syncthreads();
    {
        int row = t >> 4, lane = t & 15;
        float s1 = 0.f, s2 = 0.f;
#pragma unroll
        for (int i = 0; i < 8; i++) {
            float v = dots[row * 128 + lane * 8 + i];
            s1 += v; s2 += v * v;
        }
#pragma unroll
        for (int m = 1; m < 16; m <<= 1) { s1 += __shfl_xor(s1, m); s2 += __shfl_xor(s2, m); }
        if (lane == 0) {
            float mu = s1 * (1.0f / 128.0f);
            float var = s2 * (1.0f / 128.0f) - mu * mu;
            mv[row] = make_float2(mu, fast_rsq(var + 1e-5f));
        }
    }
    __syncthreads();
    int c = t & 127;
    int bb = r0 >> 11, l0 = r0 & 2047;
    float nwc = nw[c], nbc = nb[c];
    float hnv[8];
#pragma unroll
    for (int j = 0; j < 8; j++) {
        int r = half * 8 + j;
        float v = dots[r * 128 + c];
        h[(size_t)(r0 + r) * Hdim + c] = v;
        float2 m = mv[r];
        hnv[j] = (v - m.x) * m.y * nwc + nbc;
    }
    float* dst = hnT + ((size_t)bb * Hdim + c) * Lseq + l0 + half * 8;
    *(float4*)dst = make_float4(hnv[0], hnv[1], hnv[2], hnv[3]);
    *(float4*)(dst + 4) = make_float4(hnv[4], hnv[5], hnv[6], hnv[7]);
}

// ---------------- DPLR generating function: 2 l's per thread, 2048 blocks ----------------
__global__ __launch_bounds__(256, 4) void spectrum_kernel(const float* __restrict__ lam_re,
                                                          const float* __restrict__ lam_im,
                                                          const float* __restrict__ p_re,
                                                          const float* __restrict__ p_im,
                                                          const float* __restrict__ b_re,
                                                          const float* __restrict__ b_im,
                                                          const float* __restrict__ c_re,
                                                          const float* __restrict__ c_im,
                                                          const float* __restrict__ log_step,
                                                          float2* __restrict__ at_roots) {
    int h = blockIdx.x, layer = blockIdx.y, t = threadIdx.x;
    __shared__ __align__(16) float4 polA[Npol];  // (lam.re, lam.im, n00.re, n00.im)
    __shared__ __align__(16) float4 polB[Npol];  // (n01.re, n01.im, n10.re, n10.im)
    __shared__ float n11S[Npol];
    int baseP = (layer * Hdim + h) * Npol;
    if (t < Npol) {
        int n = t;
        float lr = lam_re[baseP + n], li = lam_im[baseP + n];
        float pr = p_re[baseP + n], pi = p_im[baseP + n];
        float br = b_re[baseP + n], bi = b_im[baseP + n];
        float cr = c_re[baseP + n], ci = c_im[baseP + n];
        polA[n] = make_float4(lr, li, cr * br + ci * bi, cr * bi - ci * br);
        polB[n] = make_float4(cr * pr + ci * pi, cr * pi - ci * pr,
                              pr * br + pi * bi, pr * bi - pi * br);
        n11S[n] = pr * pr + pi * pi;
    }
    __syncthreads();
    float step = expf(log_step[layer * Hdim + h]);
    float gs = 2.0f / step;
    int l0 = 512 * blockIdx.z;

    float gr[2], gi[2];
#pragma unroll
    for (int j = 0; j < 2; j++) {
        int l = l0 + t + 256 * j;
        float ang = -6.283185307179586f * (float)l / (float)Lseq;
        float wr = cosf(ang), wi = sinf(ang);  // fp32 omega on purpose: keeps |g|^2 in range
        float dr = 1.0f + wr, di = wi;
        float invd2 = fast_rcp(dr * dr + di * di);
        float nr = 1.0f - wr, ni = -wi;
        gr[j] = gs * (nr * dr + ni * di) * invd2;
        gi[j] = gs * (ni * dr - nr * di) * invd2;
    }
    float k00x[2] = {0, 0}, k00y[2] = {0, 0};
    float k01x[2] = {0, 0}, k01y[2] = {0, 0};
    float k10x[2] = {0, 0}, k10y[2] = {0, 0};
    float k11x[2] = {0, 0}, k11y[2] = {0, 0};
#pragma unroll 4
    for (int n = 0; n < Npol; n++) {
        float4 A = polA[n];  // b128 broadcast
        float4 B = polB[n];
        float n11 = n11S[n];
#pragma unroll
        for (int j = 0; j < 2; j++) {
            float er = gr[j] - A.x, ei = gi[j] - A.y;
            float inv2 = fast_rcp(fmaf(er, er, ei * ei));
            float ir = er * inv2;
            float mi = ei * inv2;  // = -Im(1/(g-lam))
            k00x[j] = fmaf(A.z, ir, fmaf(A.w, mi, k00x[j]));
            k00y[j] = fmaf(A.w, ir, fmaf(-A.z, mi, k00y[j]));
            k01x[j] = fmaf(B.x, ir, fmaf(B.y, mi, k01x[j]));
            k01y[j] = fmaf(B.y, ir, fmaf(-B.x, mi, k01y[j]));
            k10x[j] = fmaf(B.z, ir, fmaf(B.w, mi, k10x[j]));
            k10y[j] = fmaf(B.w, ir, fmaf(-B.z, mi, k10y[j]));
            k11x[j] = fmaf(n11, ir, k11x[j]);
            k11y[j] = fmaf(-n11, mi, k11y[j]);
        }
    }
#pragma unroll
    for (int j = 0; j < 2; j++) {
        int l = l0 + t + 256 * j;
        float ang = -6.283185307179586f * (float)l / (float)Lseq;
        float wr = cosf(ang), wi = sinf(ang);
        float dr = 1.0f + wr, di = wi;
        float invd2 = fast_rcp(dr * dr + di * di);
        float cr2 = 2.0f * dr * invd2, ci2 = -2.0f * di * invd2;
        float wr2 = 1.0f + k11x[j], wi2 = k11y[j];
        float w2inv = fast_rcp(fmaf(wr2, wr2, wi2 * wi2));
        float vr = wr2 * w2inv, vi = -wi2 * w2inv;
        float t1x = k01x[j] * k10x[j] - k01y[j] * k10y[j];
        float t1y = k01x[j] * k10y[j] + k01y[j] * k10x[j];
        float t2x = t1x * vr - t1y * vi, t2y = t1x * vi + t1y * vr;
        float ex = k00x[j] - t2x, ey = k00y[j] - t2y;
        at_roots[((size_t)layer * Hdim + h) * Lseq + l] =
            make_float2(cr2 * ex - ci2 * ey, cr2 * ey + ci2 * ex);
    }
}

// ---------------- kernel FFT: ifft2048 -> pad -> fft4096, all layers ----------------
// Kd2 layout: [layer][hp][p] float4 = (K_{2hp}[p].re,.im, K_{2hp+1}[p].re,.im), p bit-rev.
__global__ __launch_bounds__(256) void kfft_kernel(const float2* __restrict__ at_roots,
                                                   float4* __restrict__ Kd2,
                                                   const float2* __restrict__ tw) {
    int h = blockIdx.x, layer = blockIdx.y, t = threadIdx.x;
    __shared__ float2 data[4096];
    __shared__ float ktmp[2048];
    const float2* src = at_roots + ((size_t)layer * Hdim + h) * Lseq;
#pragma unroll
    for (int k = 0; k < 8; k++) {
        int l = t + 256 * k;
        data[sw(l)] = src[l];
    }
    __syncthreads();
    // inverse 2048-pt (conjugated DIF), digits 16 x 16 x 8
    if (t < 128) {
        float2 v[16];
#pragma unroll
        for (int k = 0; k < 16; k++) v[k] = data[sw(t + 128 * k)];
        fft16_dif<true>(v);
#pragma unroll
        for (int i = 1; i < 16; i++) v[i] = cmulc(v[i], twget(tw, 2 * t * BR4[i]));
#pragma unroll
        for (int i = 0; i < 16; i++) data[sw(i * 128 + t)] = v[i];
    }
    __syncthreads();
    if (t < 128) {
        int i2 = t >> 3, j0 = t & 7;
        int base2 = i2 * 128 + j0;
        float2 v[16];
#pragma unroll
        for (int k = 0; k < 16; k++) v[k] = data[sw(base2 + 8 * k)];
        fft16_dif<true>(v);
#pragma unroll
        for (int i = 1; i < 16; i++) v[i] = cmulc(v[i], twget(tw, 32 * j0 * BR4[i]));
#pragma unroll
        for (int i = 0; i < 16; i++) data[sw(base2 + 8 * i)] = v[i];
    }
    __syncthreads();
    {
        float2 v8[8];
#pragma unroll
        for (int k = 0; k < 8; k++) v8[k] = data[sw(t * 8 + k)];
        fft8_dif<true>(v8);
        int r = BR4[t >> 4], s = BR4[t & 15];
#pragma unroll
        for (int i = 0; i < 8; i++) {
            int l = r + 16 * s + 256 * BR3[i];
            ktmp[l] = v8[i].x * (1.0f / 2048.0f);
        }
    }
    __syncthreads();
#pragma unroll
    for (int k = 0; k < 8; k++) {
        int l = t + 256 * k;
        data[sw(l)] = make_float2(ktmp[l], 0.f);
        data[sw(l + 2048)] = make_float2(0.f, 0.f);
    }
    fft4096_fwd(data, tw, t);
    float2* dst = (float2*)(Kd2 + ((size_t)layer * 64 + (h >> 1)) * 4096);
    int half = h & 1;
#pragma unroll
    for (int k = 0; k < 16; k++) {
        int p = t + 256 * k;
        dst[2 * p + half] = data[sw(p)];
    }
}

// ---------------- FFT convolution + D-skip + gelu, channel pair per block ----------------
// hnT layout: [b][h][l]. Pointwise iterates EVEN p (bit-reversed domain) so the
// lane-varying bits land in p's low bits -> conflict-optimal LDS access.
__global__ __launch_bounds__(256) void conv_kernel(float* __restrict__ hnT,
                                                   const float4* __restrict__ Kd2,
                                                   const float* __restrict__ dvec,
                                                   const float2* __restrict__ tw) {
    int hp = blockIdx.x, b = blockIdx.y, h0 = hp * 2, t = threadIdx.x;
    __shared__ float2 data[4096];
    float* u0 = hnT + ((size_t)b * Hdim + h0) * Lseq;
    float* u1 = u0 + Lseq;
    float2 ureg[8];
#pragma unroll
    for (int k = 0; k < 8; k++) {
        int l = t + 256 * k;
        float2 u2 = make_float2(u0[l], u1[l]);
        ureg[k] = u2;
        data[sw(l)] = u2;
        data[sw(l + 2048)] = make_float2(0.f, 0.f);
    }
    fft4096_fwd(data, tw, t);
    const float4* Kp = Kd2 + (size_t)hp * 4096;
    const float scale = 1.0f / 4096.0f;
#pragma unroll
    for (int k = 0; k < 8; k++) {
        int p = 2 * (t + 256 * k);                // even p <-> f in [0, 2048)
        int f = __brev((unsigned)p) >> 20;
        int fm = (4096 - f) & 4095;
        int pm = __brev((unsigned)fm) >> 20;      // odd (or 0 when f==0)
        float2 Zf = data[sw(p)], Zm = data[sw(pm)];
        float2 U0 = make_float2(0.5f * (Zf.x + Zm.x), 0.5f * (Zf.y - Zm.y));
        float2 Dm = make_float2(Zf.x - Zm.x, Zf.y + Zm.y);
        float2 U1 = make_float2(0.5f * Dm.y, -0.5f * Dm.x);
        float4 Ka = Kp[p];
        float2 S0 = cmulf(U0, make_float2(Ka.x, Ka.y));
        float2 S1 = cmulf(U1, make_float2(Ka.z, Ka.w));
        float2 Wf = make_float2((S0.x - S1.y) * scale, (S0.y + S1.x) * scale);
        float4 Kb = Kp[pm];
        float2 U0m = make_float2(U0.x, -U0.y);
        float2 U1m = make_float2(U1.x, -U1.y);
        float2 S0m = cmulf(U0m, make_float2(Kb.x, Kb.y));
        float2 S1m = cmulf(U1m, make_float2(Kb.z, Kb.w));
        float2 Wm = make_float2((S0m.x - S1m.y) * scale, (S0m.y + S1m.x) * scale);
        data[sw(p)] = Wf;
        if (pm != p) data[sw(pm)] = Wm;
    }
    if (t == 0) {  // f = 2048 self-pair: p = pm = brev(2048) = 1
        float2 Zf = data[sw(1)];
        float2 U0 = make_float2(Zf.x, 0.f);
        float2 U1 = make_float2(Zf.y, 0.f);
        float4 Ka = Kp[1];
        float2 S0 = cmulf(U0, make_float2(Ka.x, Ka.y));
        float2 S1 = cmulf(U1, make_float2(Ka.z, Ka.w));
        data[sw(1)] = make_float2((S0.x - S1.y) * scale, (S0.y + S1.x) * scale);
    }
    __syncthreads();
    {
        float2 v[16];
#pragma unroll
        for (int i = 0; i < 16; i++) v[i] = data[sw(t * 16 + i)];
        fft16_dit<true>(v);
#pragma unroll
        for (int i = 0; i < 16; i++) data[sw(t * 16 + i)] = v[i];
    }
    __syncthreads();
    {
        int j0 = t & 15;
        int base2 = (t >> 4) * 256 + j0;
        float2 v[16];
        v[0] = data[sw(base2)];
#pragma unroll
        for (int i = 1; i < 16; i++)
            v[i] = cmulc(data[sw(base2 + 16 * i)], twget(tw, 16 * j0 * BR4[i]));
        fft16_dit<true>(v);
#pragma unroll
        for (int i = 0; i < 16; i++) data[sw(base2 + 16 * i)] = v[i];
    }
    __syncthreads();
    {
        float2 v[16];
        v[0] = data[sw(t)];
#pragma unroll
        for (int i = 1; i < 16; i++)
            v[i] = cmulc(data[sw(i * 256 + t)], twget(tw, t * BR4[i]));
        fft16_dit<true>(v);
        float d0 = dvec[h0], d1 = dvec[h0 + 1];
#pragma unroll
        for (int k = 0; k < 8; k++) {
            int l = t + 256 * k;
            u0[l] = gelu_f(v[k].x + ureg[k].x * d0);
            u1[l] = gelu_f(v[k].y + ureg[k].y * d1);
        }
    }
}

// ---------------- gated MLP + residual + fused next-layer LN: 32 rows/block ----------------
__global__ __launch_bounds__(256) void mlp_kernel(const float* __restrict__ yT,
                                                  float* __restrict__ h,
                                                  float* __restrict__ hnT,
                                                  const float* __restrict__ w1,
                                                  const float* __restrict__ b1,
                                                  const float* __restrict__ w2,
                                                  const float* __restrict__ b2,
                                                  const float* __restrict__ nw,
                                                  const float* __restrict__ nb,
                                                  int do_ln) {
    const int ROWS = 32;
    int r0 = blockIdx.x * ROWS;
    int t = threadIdx.x;
    __shared__ __align__(16) float yst[128 * 36];  // y^T [k][r], pad 36
    __shared__ float wst[2 * 128 * 17];            // w chunk; aliased as dots later
    __shared__ float2 mv[32];
    float* dots = wst;                             // 32*132 = 4224 <= 4352 floats

    int bb = r0 >> 11, l0 = r0 & 2047;
    for (int i = t; i < 128 * ROWS; i += 256) {
        int k = i >> 5, r = i & 31;                // lanes consecutive in r -> coalesced in l
        yst[k * 36 + r] = yT[((size_t)bb * Hdim + k) * Lseq + l0 + r];
    }
    int o = t & 127, rh = t >> 7;
    float acc1[16], acc2[16];
    float bias1 = b1[o], bias2 = b2[o];
#pragma unroll
    for (int j = 0; j < 16; j++) { acc1[j] = bias1; acc2[j] = bias2; }

    float pf[16];
#pragma unroll
    for (int j = 0; j < 16; j++) {
        int e = t + 256 * j;
        int mat = e >> 11, rem = e & 2047, oo = rem >> 4, kk = rem & 15;
        pf[j] = (mat ? w2 : w1)[(size_t)oo * Hdim + kk];
    }
    for (int kc0 = 0; kc0 < 128; kc0 += 16) {
        __syncthreads();
#pragma unroll
        for (int j = 0; j < 16; j++) {
            int e = t + 256 * j;
            int mat = e >> 11, rem = e & 2047, oo = rem >> 4, kk = rem & 15;
            wst[mat * 2176 + oo * 17 + kk] = pf[j];
        }
        __syncthreads();
        if (kc0 + 16 < 128) {
#pragma unroll
            for (int j = 0; j < 16; j++) {
                int e = t + 256 * j;
                int mat = e >> 11, rem = e & 2047, oo = rem >> 4, kk = rem & 15;
                pf[j] = (mat ? w2 : w1)[(size_t)oo * Hdim + kc0 + 16 + kk];
            }
        }
#pragma unroll
        for (int k = 0; k < 16; k++) {
            float wv1 = wst[o * 17 + k];
            float wv2 = wst[2176 + o * 17 + k];
            int kk = (kc0 + k) * 36 + rh * 16;
            float4 ya = *(const float4*)&yst[kk];
            float4 yb = *(const float4*)&yst[kk + 4];
            float4 yc = *(const float4*)&yst[kk + 8];
            float4 yd = *(const float4*)&yst[kk + 12];
            acc1[0]  = fmaf(wv1, ya.x, acc1[0]);  acc2[0]  = fmaf(wv2, ya.x, acc2[0]);
            acc1[1]  = fmaf(wv1, ya.y, acc1[1]);  acc2[1]  = fmaf(wv2, ya.y, acc2[1]);
            acc1[2]  = fmaf(wv1, ya.z, acc1[2]);  acc2[2]  = fmaf(wv2, ya.z, acc2[2]);
            acc1[3]  = fmaf(wv1, ya.w, acc1[3]);  acc2[3]  = fmaf(wv2, ya.w, acc2[3]);
            acc1[4]  = fmaf(wv1, yb.x, acc1[4]);  acc2[4]  = fmaf(wv2, yb.x, acc2[4]);
            acc1[5]  = fmaf(wv1, yb.y, acc1[5]);  acc2[5]  = fmaf(wv2, yb.y, acc2[5]);
            acc1[6]  = fmaf(wv1, yb.z, acc1[6]);  acc2[6]  = fmaf(wv2, yb.z, acc2[6]);
            acc1[7]  = fmaf(wv1, yb.w, acc1[7]);  acc2[7]  = fmaf(wv2, yb.w, acc2[7]);
            acc1[8]  = fmaf(wv1, yc.x, acc1[8]);  acc2[8]  = fmaf(wv2, yc.x, acc2[8]);
            acc1[9]  = fmaf(wv1, yc.y, acc1[9]);  acc2[9]  = fmaf(wv2, yc.y, acc2[9]);
            acc1[10] = fmaf(wv1, yc.z, acc1[10]); acc2[10] = fmaf(wv2, yc.z, acc2[10]);
            acc1[11] = fmaf(wv1, yc.w, acc1[11]); acc2[11] = fmaf(wv2, yc.w, acc2[11]);
            acc1[12] = fmaf(wv1, yd.x, acc1[12]); acc2[12] = fmaf(wv2, yd.x, acc2[12]);
            acc1[13] = fmaf(wv1, yd.y, acc1[13]); acc2[13] = fmaf(wv2, yd.y, acc2[13]);
            acc1[14] = fmaf(wv1, yd.z, acc1[14]); acc2[14] = fmaf(wv2, yd.z, acc2[14]);
            acc1[15] = fmaf(wv1, yd.w, acc1[15]); acc2[15] = fmaf(wv2, yd.w, acc2[15]);
        }
    }
    __syncthreads();  // wst dead -> reuse as dots
    float hv[16];
#pragma unroll
    for (int j = 0; j < 16; j++) {
        int r = rh * 16 + j;
        float g = fast_rcp(1.0f + __expf(-acc2[j]));
        hv[j] = h[(size_t)(r0 + r) * Hdim + o] + acc1[j] * g;
        dots[r * 132 + o] = hv[j];
    }
    __syncthreads();
    if (do_ln) {
        int row = t >> 3, lane = t & 7;  // 8 lanes per row, 16 vals each
        float s1 = 0.f, s2 = 0.f;
        int base = row * 132 + lane * 16;
#pragma unroll
        for (int q = 0; q < 4; q++) {
            float4 v4 = *(const float4*)&dots[base + 4 * q];
            s1 += v4.x + v4.y + v4.z + v4.w;
            s2 += v4.x * v4.x + v4.y * v4.y + v4.z * v4.z + v4.w * v4.w;
        }
#pragma unroll
        for (int m = 1; m < 8; m <<= 1) { s1 += __shfl_xor(s1, m); s2 += __shfl_xor(s2, m); }
        if (lane == 0) {
            float mu = s1 * (1.0f / 128.0f);
            float var = s2 * (1.0f / 128.0f) - mu * mu;
            mv[row] = make_float2(mu, fast_rsq(var + 1e-5f));
        }
        __syncthreads();
        float nwc = nw[o], nbc = nb[o];
        float hnv[16];
#pragma unroll
        for (int j = 0; j < 16; j++) {
            int r = rh * 16 + j;
            h[(size_t)(r0 + r) * Hdim + o] = hv[j];
            float2 m = mv[r];
            hnv[j] = (hv[j] - m.x) * m.y * nwc + nbc;
        }
        float* dst = hnT + ((size_t)bb * Hdim + o) * Lseq + l0 + rh * 16;
        *(float4*)(dst)      = make_float4(hnv[0],  hnv[1],  hnv[2],  hnv[3]);
        *(float4*)(dst + 4)  = make_float4(hnv[4],  hnv[5],  hnv[6],  hnv[7]);
        *(float4*)(dst + 8)  = make_float4(hnv[8],  hnv[9],  hnv[10], hnv[11]);
        *(float4*)(dst + 12) = make_float4(hnv[12], hnv[13], hnv[14], hnv[15]);
    } else {
#pragma unroll
        for (int j = 0; j < 16; j++) {
            int r = rh * 16 + j;
            h[(size_t)(r0 + r) * Hdim + o] = hv[j];
        }
    }
}

// ---------------- decoder: 32 rows/block ----------------
__global__ __launch_bounds__(256) void decoder_kernel(const float* __restrict__ h,
                                                      const float* __restrict__ w,
                                                      const float* __restrict__ b,
                                                      float* __restrict__ out) {
    int r0 = blockIdx.x * 32;
    int t = threadIdx.x;
    __shared__ float ws[64 * 129];
    __shared__ __align__(16) float hst[128 * 36];
    for (int i = t; i < 64 * 128; i += 256) ws[(i >> 7) * 129 + (i & 127)] = w[i];
    for (int i = t; i < 32 * 128; i += 256) {
        int r = i >> 7, k = i & 127;
        hst[k * 36 + r] = h[(size_t)(r0 + r) * Hdim + k];
    }
    __syncthreads();
    int o = t & 63, q = t >> 6;
    float acc[8];
    float bo = b[o];
#pragma unroll
    for (int j = 0; j < 8; j++) acc[j] = bo;
    for (int k = 0; k < 128; k++) {
        float wv = ws[o * 129 + k];
        float4 ha = *(const float4*)&hst[k * 36 + q * 8];
        float4 hb = *(const float4*)&hst[k * 36 + q * 8 + 4];
        acc[0] += wv * ha.x; acc[1] += wv * ha.y; acc[2] += wv * ha.z; acc[3] += wv * ha.w;
        acc[4] += wv * hb.x; acc[5] += wv * hb.y; acc[6] += wv * hb.z; acc[7] += wv * hb.w;
    }
#pragma unroll
    for (int j = 0; j < 8; j++) out[(size_t)(r0 + q * 8 + j) * 64 + o] = acc[j];
}

extern "C" void kernel_launch(void* const* d_in, const int* in_sizes, int n_in,
                              void* d_out, int out_size, void* d_ws, size_t ws_size,
                              hipStream_t stream) {
    const float* x      = (const float*)d_in[0];
    const float* enc_w  = (const float*)d_in[2];
    const float* enc_b  = (const float*)d_in[3];
    const float* dec_w  = (const float*)d_in[4];
    const float* dec_b  = (const float*)d_in[5];
    const float* lam_re = (const float*)d_in[6];
    const float* lam_im = (const float*)d_in[7];
    const float* p_re   = (const float*)d_in[8];
    const float* p_im   = (const float*)d_in[9];
    const float* b_re   = (const float*)d_in[10];
    const float* b_im   = (const float*)d_in[11];
    const float* c_re   = (const float*)d_in[12];
    const float* c_im   = (const float*)d_in[13];
    const float* dvec   = (const float*)d_in[14];
    const float* lstep  = (const float*)d_in[15];
    const float* norm_w = (const float*)d_in[16];
    const float* norm_b = (const float*)d_in[17];
    const float* w1     = (const float*)d_in[18];
    const float* b1     = (const float*)d_in[19];
    const float* w2     = (const float*)d_in[20];
    const float* b2     = (const float*)d_in[21];
    float* out = (float*)d_out;

    char* ws = (char*)d_ws;
    float2* tw  = (float2*)ws;  ws += 2048 * sizeof(float2);
    float*  h   = (float*)ws;   ws += (size_t)Bsz * Lseq * Hdim * sizeof(float);
    float*  hnT = (float*)ws;   ws += (size_t)Bsz * Lseq * Hdim * sizeof(float);
    float2* atr = (float2*)ws;  ws += (size_t)NLAYERS * Hdim * Lseq * sizeof(float2);
    float4* Kd2 = (float4*)ws;  ws += (size_t)NLAYERS * (Hdim / 2) * 4096 * sizeof(float4);

    const int nrows = Bsz * Lseq;  // 16384

    twiddle_init<<<8, 256, 0, stream>>>(tw);
    spectrum_kernel<<<dim3(Hdim, NLAYERS, 4), 256, 0, stream>>>(
        lam_re, lam_im, p_re, p_im, b_re, b_im, c_re, c_im, lstep, atr);
    kfft_kernel<<<dim3(Hdim, NLAYERS), 256, 0, stream>>>(atr, Kd2, tw);
    encoder_kernel<<<nrows / 16, 256, 0, stream>>>(x, enc_w, enc_b, norm_w, norm_b, h, hnT);
    for (int L = 0; L < NLAYERS; L++) {
        conv_kernel<<<dim3(Hdim / 2, Bsz), 256, 0, stream>>>(
            hnT, Kd2 + (size_t)L * (Hdim / 2) * 4096, dvec + L * Hdim, tw);
        int do_ln = (L < NLAYERS - 1) ? 1 : 0;
        const float* nwn = norm_w + ((L + 1) % NLAYERS) * Hdim;
        const float* nbn = norm_b + ((L + 1) % NLAYERS) * Hdim;
        mlp_kernel<<<nrows / 32, 256, 0, stream>>>(hnT, h, hnT,
                                                   w1 + (size_t)L * Hdim * Hdim, b1 + L * Hdim,
                                                   w2 + (size_t)L * Hdim * Hdim, b2 + L * Hdim,
                                                   nwn, nbn, do_ln);
    }
    decoder_kernel<<<nrows / 32, 256, 0, stream>>>(h, dec_w, dec_b, out);
}